// Round 7
// baseline (1145.423 us; speedup 1.0000x reference)
//
#include <hip/hip_runtime.h>
#include <math.h>

#define BB 4
#define LL 4096
#define DD 1024
#define HH 4
#define DKk 256
#define DVv 256
#define HIDD 512
#define NC 128   // number of 32-chunks in L
#define NSEG 64  // EMA segments
#define SEG 64   // EMA segment length

typedef unsigned short ushort_t;
typedef __attribute__((ext_vector_type(8))) short short8;
typedef __attribute__((ext_vector_type(4))) float floatx4;

__device__ __forceinline__ float sigm(float x) { return 1.f / (1.f + __expf(-x)); }

__device__ __forceinline__ float bf2f(ushort_t u) {
  union { unsigned int i; float f; } c; c.i = ((unsigned int)u) << 16; return c.f;
}
__device__ __forceinline__ ushort_t f2bf(float f) {
  union { float f; unsigned int i; } c; c.f = f;
  unsigned int lsb = (c.i >> 16) & 1u;
  return (ushort_t)((c.i + 0x7fffu + lsb) >> 16);
}
__device__ __forceinline__ void unpack2(unsigned int u, float& a, float& b) {
  union { unsigned int i; float f; } c0, c1;
  c0.i = u << 16; c1.i = u & 0xffff0000u; a = c0.f; b = c1.f;
}
__device__ __forceinline__ unsigned int pack2(float a, float b) {
  return (unsigned int)f2bf(a) | ((unsigned int)f2bf(b) << 16);
}
__device__ __forceinline__ void unpack8(const uint4 v, float* o) {
  unpack2(v.x, o[0], o[1]); unpack2(v.y, o[2], o[3]);
  unpack2(v.z, o[4], o[5]); unpack2(v.w, o[6], o[7]);
}
__device__ __forceinline__ float ubits(unsigned u) {
  union { unsigned i; float f; } c; c.i = u; return c.f;
}
// exact truncate-split of two floats into packed bf16 hi and bf16 lo words
__device__ __forceinline__ void split2t(float a, float b, unsigned& hi, unsigned& lo) {
  union { float f; unsigned u; } ca, cb; ca.f = a; cb.f = b;
  const unsigned ha = ca.u & 0xffff0000u, hb = cb.u & 0xffff0000u;
  hi = (ha >> 16) | hb;
  union { float f; unsigned u; } la, lb;
  la.f = a - ubits(ha); lb.f = b - ubits(hb);
  lo = (la.u >> 16) | (lb.u & 0xffff0000u);
}
__device__ __forceinline__ void gload16(const ushort_t* g, ushort_t* l) {
  __builtin_amdgcn_global_load_lds(
      (const __attribute__((address_space(1))) void*)g,
      (__attribute__((address_space(3))) void*)l, 16, 0, 0);
}

// ---- f32 -> bf16 convert (8 elems/thread) ----------------------------------
__global__ __launch_bounds__(256) void cvt_bf16_kernel(const float* __restrict__ in,
    ushort_t* __restrict__ outp, int n8)
{
  const int i = blockIdx.x * 256 + threadIdx.x;
  if (i >= n8) return;
  const float4 a = ((const float4*)in)[2*i];
  const float4 b = ((const float4*)in)[2*i + 1];
  uint4 p;
  p.x = pack2(a.x, a.y); p.y = pack2(a.z, a.w);
  p.z = pack2(b.x, b.y); p.w = pack2(b.z, b.w);
  ((uint4*)outp)[i] = p;
}

// ---- MFMA GEMM, bf16 A and W, global_load_lds staging ----------------------
// C(M,N) = A(M,K) @ W(N,K)^T.  ACT==1: +bias then SiLU. BF16OUT: bf16 else f32.
template<int ACT, int BF16OUT>
__global__ __launch_bounds__(256) void gemm_bf16(const ushort_t* __restrict__ A,
    const ushort_t* __restrict__ W, const float* __restrict__ bias,
    void* __restrict__ Cv, int M, int N, int K)
{
  __shared__ ushort_t As[128*32];
  __shared__ ushort_t Ws[128*32];
  const int tid = threadIdx.x;
  const int bm = blockIdx.y * 128, bn = blockIdx.x * 128;
  const int lane = tid & 63, wave = tid >> 6;
  const int wm = (wave >> 1) * 64, wn = (wave & 1) * 64;
  const int fr = lane & 15, fq = lane >> 4;
  // staging: wave w covers rows w*16..w*16+16 of each 64-row half; lane*16B linear LDS
  const int srow = wave * 16 + (lane >> 2);
  const int scol = (lane & 3) * 8;
  const ushort_t* Ap = A + (size_t)(bm + srow) * K + scol;
  const ushort_t* Wp = W + (size_t)(bn + srow) * K + scol;
  ushort_t* AsD = &As[wave * 512];
  ushort_t* WsD = &Ws[wave * 512];
  floatx4 acc[4][4];
#pragma unroll
  for (int i = 0; i < 4; ++i)
#pragma unroll
    for (int j = 0; j < 4; ++j) acc[i][j] = (floatx4){0.f, 0.f, 0.f, 0.f};

  for (int k0 = 0; k0 < K; k0 += 32) {
    __syncthreads();                       // prev tile reads done
    gload16(Ap + k0, AsD);
    gload16(Ap + (size_t)64 * K + k0, AsD + 64*32);
    gload16(Wp + k0, WsD);
    gload16(Wp + (size_t)64 * K + k0, WsD + 64*32);
    __syncthreads();                       // staging complete (vmcnt drained)
    short8 af[4], bf_[4];
#pragma unroll
    for (int mt = 0; mt < 4; ++mt)
      af[mt] = *(const short8*)&As[(wm + mt*16 + fr)*32 + fq*8];
#pragma unroll
    for (int nt = 0; nt < 4; ++nt)
      bf_[nt] = *(const short8*)&Ws[(wn + nt*16 + fr)*32 + fq*8];
#pragma unroll
    for (int mt = 0; mt < 4; ++mt)
#pragma unroll
      for (int nt = 0; nt < 4; ++nt)
        acc[mt][nt] = __builtin_amdgcn_mfma_f32_16x16x32_bf16(af[mt], bf_[nt], acc[mt][nt], 0, 0, 0);
  }
#pragma unroll
  for (int mt = 0; mt < 4; ++mt) {
#pragma unroll
    for (int reg = 0; reg < 4; ++reg) {
      const int row = bm + wm + mt*16 + fq*4 + reg;
#pragma unroll
      for (int nt = 0; nt < 4; ++nt) {
        const int col = bn + wn + nt*16 + fr;
        float v = acc[mt][nt][reg];
        if (ACT == 1) { v += bias[col]; v = v * sigm(v); }
        if (BF16OUT) ((ushort_t*)Cv)[(size_t)row * N + col] = f2bf(v);
        else         ((float*)Cv)[(size_t)row * N + col] = v;
      }
    }
  }
}

// ---- depthwise causal conv(k=4)+SiLU, vectorized 8/thread ------------------
__global__ __launch_bounds__(256) void conv_silu_kernel(const ushort_t* __restrict__ xin,
    const float* __restrict__ wc, ushort_t* __restrict__ outp)
{
  const size_t i8 = (size_t)blockIdx.x * 256 + threadIdx.x;  // over B*L*D/8
  const int d8 = (int)((i8 & 127) << 3);
  const int l  = (int)((i8 >> 7) & (LL - 1));
  const int b  = (int)(i8 >> 19);
  const ushort_t* xp = xin + i8 * 8;
  const uint4 z4 = (uint4){0u,0u,0u,0u};
  const uint4 v0 = *(const uint4*)xp;
  const uint4 v1 = (l >= 1) ? *(const uint4*)(xp - DD)   : z4;
  const uint4 v2 = (l >= 2) ? *(const uint4*)(xp - 2*DD) : z4;
  const uint4 v3 = (l >= 3) ? *(const uint4*)(xp - 3*DD) : z4;
  float x0[8], x1[8], x2[8], x3[8];
  unpack8(v0, x0); unpack8(v1, x1); unpack8(v2, x2); unpack8(v3, x3);
  unsigned pk[4];
#pragma unroll
  for (int p = 0; p < 4; ++p) {
    float o2[2];
#pragma unroll
    for (int q = 0; q < 2; ++q) {
      const int j = p*2 + q;
      const float4 w = *(const float4*)(wc + (d8 + j) * 4);
      float acc = w.w * x0[j];
      acc = fmaf(w.z, x1[j], acc);
      acc = fmaf(w.y, x2[j], acc);
      acc = fmaf(w.x, x3[j], acc);
      o2[q] = acc * sigm(acc);
    }
    pk[p] = pack2(o2[0], o2[1]);
  }
  const int h = d8 >> 8, dk = d8 & 255;
  *(uint4*)(outp + (((size_t)(b*HH + h))*LL + l)*DKk + dk) = *(uint4*)pk;
}

// ---- beta / g_s / g_l: 12 length-1024 dots per (b,l), x fp32 ---------------
__global__ __launch_bounds__(256) void small_proj_kernel(const float* __restrict__ x,
   const float* __restrict__ Wb, const float* __restrict__ Wds, const float* __restrict__ bds,
   const float* __restrict__ Wdl, const float* __restrict__ bdl,
   float* __restrict__ beta, float* __restrict__ gs, float* __restrict__ gl)
{
  const int bl = blockIdx.x;
  const int t = threadIdx.x, wave = t >> 6, lane = t & 63;
  __shared__ float res[12];
  const float* xr = x + (size_t)bl * DD + lane * 16;
  const float4 x0 = *(const float4*)(xr);
  const float4 x1 = *(const float4*)(xr + 4);
  const float4 x2 = *(const float4*)(xr + 8);
  const float4 x3 = *(const float4*)(xr + 12);
  for (int rr = 0; rr < 3; ++rr) {
    const int r = wave * 3 + rr;
    const int mat = r >> 2, h = r & 3;
    const float* Wr = (mat == 0 ? Wb : (mat == 1 ? Wds : Wdl)) + (size_t)h * DD + lane * 16;
    const float4 w0 = *(const float4*)(Wr);
    const float4 w1 = *(const float4*)(Wr + 4);
    const float4 w2 = *(const float4*)(Wr + 8);
    const float4 w3 = *(const float4*)(Wr + 12);
    float p = x0.x*w0.x + x0.y*w0.y + x0.z*w0.z + x0.w*w0.w
            + x1.x*w1.x + x1.y*w1.y + x1.z*w1.z + x1.w*w1.w
            + x2.x*w2.x + x2.y*w2.y + x2.z*w2.z + x2.w*w2.w
            + x3.x*w3.x + x3.y*w3.y + x3.z*w3.z + x3.w*w3.w;
#pragma unroll
    for (int o = 1; o < 64; o <<= 1) p += __shfl_xor(p, o);
    if (lane == 0) res[r] = p;
  }
  __syncthreads();
  if (t < 12) {
    const int mat = t >> 2, h = t & 3;
    float v = res[t];
    if (mat == 1) v += bds[h];
    if (mat == 2) v += bdl[h];
    v = sigm(v);
    const int b = bl >> 12, l = bl & (LL - 1);
    const size_t o = ((size_t)(b*HH + h))*LL + l;
    (mat == 0 ? beta : (mat == 1 ? gs : gl))[o] = v;
  }
}

// ---- hierarchical gate: z bf16, 24 length-512 dots + 2-way softmaxes -------
__global__ __launch_bounds__(256) void gate_kernel(const ushort_t* __restrict__ z,
  const float* __restrict__ Wc, const float* __restrict__ bc,
  const float* __restrict__ Wl, const float* __restrict__ bl_,
  const float* __restrict__ Wg, const float* __restrict__ bg,
  const float* __restrict__ ltc, const float* __restrict__ ltf,
  float* __restrict__ wgt)
{
  const int bl = blockIdx.x;
  const int t = threadIdx.x, wave = t >> 6, lane = t & 63;
  __shared__ float res[24];
  const uint4 zv = *(const uint4*)(z + (size_t)bl * HIDD + lane * 8);
  float zf[8]; unpack8(zv, zf);
  for (int rr = 0; rr < 6; ++rr) {
    const int r = wave * 6 + rr;
    const int mat = r >> 3, qi = r & 7;
    const float* Wr = (mat == 0 ? Wc : (mat == 1 ? Wl : Wg)) + (size_t)qi * HIDD + lane * 8;
    const float4 w0 = *(const float4*)(Wr);
    const float4 w1 = *(const float4*)(Wr + 4);
    float p = zf[0]*w0.x + zf[1]*w0.y + zf[2]*w0.z + zf[3]*w0.w
            + zf[4]*w1.x + zf[5]*w1.y + zf[6]*w1.z + zf[7]*w1.w;
#pragma unroll
    for (int o = 1; o < 64; o <<= 1) p += __shfl_xor(p, o);
    if (lane == 0) {
      const float* br = (mat == 0 ? bc : (mat == 1 ? bl_ : bg));
      res[r] = p + br[qi];
    }
  }
  __syncthreads();
  if (t < 4) {
    const float tc = logf(1.f + __expf(ltc[t])) + 1e-4f;
    const float tf = logf(1.f + __expf(ltf[t])) + 1e-4f;
    const float pg0 = sigm((res[2*t]     - res[2*t+1])     / tc);
    const float q0  = sigm((res[8+2*t]   - res[8+2*t+1])   / tf);
    const float r0  = sigm((res[16+2*t]  - res[16+2*t+1])  / tf);
    float* o = wgt + ((size_t)bl * HH + t) * 4;
    o[0] = pg0 * q0;         o[1] = pg0 * (1.f - q0);
    o[2] = (1.f - pg0) * r0; o[3] = (1.f - pg0) * (1.f - r0);
  }
}

// ---- chunk-local prep: l2norm, MFMA attn(hi/lo)+Lm, triangular solves ------
#define QS 264
__global__ __launch_bounds__(256) void prep_kernel(ushort_t* __restrict__ q,
    ushort_t* __restrict__ k, const ushort_t* __restrict__ v,
    const float* __restrict__ beta,
    ushort_t* __restrict__ u, ushort_t* __restrict__ w,
    ushort_t* __restrict__ ah, ushort_t* __restrict__ al)
{
  __shared__ ushort_t qb[32*QS];
  __shared__ ushort_t kb[32*QS];
  __shared__ float Lm[32*32];
  __shared__ float betas[32];
  const int bid = blockIdx.x;
  const int ci = bid & (NC - 1);
  const int bh = bid >> 7;
  const int t = threadIdx.x;
  const size_t base = ((size_t)bh * LL + ci*32) * DKk;
  if (t < 32) betas[t] = beta[(size_t)bh * LL + ci*32 + t];
  for (int i4 = t; i4 < 1024; i4 += 256) {
    const int r = i4 >> 5, e = (i4 & 31) * 8;
    *(uint4*)&qb[r*QS + e] = *(const uint4*)(q + base + r*256 + e);
    *(uint4*)&kb[r*QS + e] = *(const uint4*)(k + base + r*256 + e);
  }
  __syncthreads();
  {
    const int r = t >> 3, g = t & 7;
    float sq = 0.f, sk = 0.f;
    for (int e = g*32; e < g*32 + 32; ++e) {
      const float a = bf2f(qb[r*QS + e]); sq = fmaf(a, a, sq);
      const float c = bf2f(kb[r*QS + e]); sk = fmaf(c, c, sk);
    }
#pragma unroll
    for (int o = 1; o < 8; o <<= 1) { sq += __shfl_xor(sq, o); sk += __shfl_xor(sk, o); }
    const float rq = rsqrtf(sq + 1e-6f), rk = rsqrtf(sk + 1e-6f);
    for (int e = g*32; e < g*32 + 32; ++e) {
      qb[r*QS + e] = f2bf(bf2f(qb[r*QS + e]) * rq);
      kb[r*QS + e] = f2bf(bf2f(kb[r*QS + e]) * rk);
    }
  }
  __syncthreads();
  // write back normalized q (row-major, used as MFMA A-frags in scan)
  for (int i4 = t; i4 < 1024; i4 += 256) {
    const int r = i4 >> 5, e = (i4 & 31) * 8;
    *(uint4*)(q + base + r*256 + e) = *(const uint4*)&qb[r*QS + e];
  }
  // write kT (dk-major: [dk][cr]) into the k slab; thread t = dk
  {
    unsigned int pk[16];
#pragma unroll
    for (int j = 0; j < 16; ++j)
      pk[j] = (unsigned int)kb[(2*j)*QS + t] | ((unsigned int)kb[(2*j+1)*QS + t] << 16);
    uint4* kd = (uint4*)(k + base + (size_t)t*32);
#pragma unroll
    for (int j = 0; j < 4; ++j) kd[j] = ((const uint4*)pk)[j];
  }
  // attn = q@k^T (tril), Lm = beta_i * (k@k^T) (strict tril) -- via MFMA.
  // 4 waves x one 16x16 (i,j)-tile x 8 ksteps x 2 products.
  {
    const int lane = t & 63, wv4 = t >> 6;
    const int fr = lane & 15, fq = lane >> 4;
    const int it = wv4 >> 1, jt = wv4 & 1;
    floatx4 dq = (floatx4){0.f,0.f,0.f,0.f};
    floatx4 dk2 = (floatx4){0.f,0.f,0.f,0.f};
#pragma unroll
    for (int ks = 0; ks < 8; ++ks) {
      const short8 bfk = *(const short8*)&kb[(jt*16+fr)*QS + ks*32 + fq*8];
      const short8 afq = *(const short8*)&qb[(it*16+fr)*QS + ks*32 + fq*8];
      const short8 afk = *(const short8*)&kb[(it*16+fr)*QS + ks*32 + fq*8];
      dq  = __builtin_amdgcn_mfma_f32_16x16x32_bf16(afq, bfk, dq, 0,0,0);
      dk2 = __builtin_amdgcn_mfma_f32_16x16x32_bf16(afk, bfk, dk2, 0,0,0);
    }
#pragma unroll
    for (int reg = 0; reg < 4; ++reg) {
      const int i = it*16 + fq*4 + reg;
      const int j = jt*16 + fr;
      const float av = (j <= i) ? dq[reg] : 0.f;
      const ushort_t hh = f2bf(av);
      const size_t aoff = ((size_t)bh*NC + ci)*1024 + (size_t)i*32 + j;
      ah[aoff] = hh;
      al[aoff] = f2bf(av - bf2f(hh));
      Lm[i*32 + j] = (j < i) ? betas[i] * dk2[reg] : 0.f;
    }
  }
  __syncthreads();
  {
    float cu[32], cw[32];
#pragma unroll
    for (int r = 0; r < 32; ++r) {
      cu[r] = bf2f(v[base + r*256 + t]) * betas[r];
      cw[r] = bf2f(kb[r*QS + t]) * betas[r];
    }
#pragma unroll
    for (int i = 1; i < 32; ++i) {
      float au = cu[i], aw = cw[i];
#pragma unroll
      for (int j = 0; j < i; ++j) {
        const float lm = Lm[i*32 + j];
        au = fmaf(-lm, cu[j], au);
        aw = fmaf(-lm, cw[j], aw);
      }
      cu[i] = au; cw[i] = aw;
    }
    // uT (dv-major: [dv][cr]); thread t = dv -> 64B contiguous
    {
      unsigned int pu[16];
#pragma unroll
      for (int j = 0; j < 16; ++j) pu[j] = pack2(cu[2*j], cu[2*j+1]);
      uint4* ud = (uint4*)(u + base + (size_t)t*32);
#pragma unroll
      for (int j = 0; j < 4; ++j) ud[j] = ((const uint4*)pu)[j];
    }
#pragma unroll
    for (int r = 0; r < 32; ++r) w[base + r*256 + t] = f2bf(cw[r]);
  }
}

// ---- MFMA sequential chunk scan: 512 blocks x 4 specialized waves ----------
// Task = (bh, vs) with dv-slice 8 -> 512 blocks = 2 blocks/CU = 2 waves/SIMD
// from INDEPENDENT blocks (their stalls interleave). MFMA cols 8-15 carry a
// duplicated-u recurrence (bounded, discarded). Waves 0,1: accA = -u+w@S ->
// uhat hi/lo. Waves 2,3: accB = q@Sh; +attn@uhat, store o (fr<8 only).
// All waves: own 64-dk slice of S, S += kT@uhat, mirror to LDS. 2 bars/chunk.
#define S16(dv,kk) (((dv)<<8) + ((kk) ^ (((dv)&7)<<3)))
#define U16(dv,cr) (((dv)<<5) + ((cr) ^ (((dv)&3)<<3)))

__global__ __launch_bounds__(256, 2) void scan_kernel(
    const ushort_t* __restrict__ qn, const ushort_t* __restrict__ kt,
    const ushort_t* __restrict__ ut, const ushort_t* __restrict__ w,
    const ushort_t* __restrict__ ah, const ushort_t* __restrict__ al,
    float* __restrict__ dout)
{
  __shared__ ushort_t STh[16*256];   // 8 KB [dv][dk] hi, swizzled
  __shared__ ushort_t STl[16*256];   // 8 KB lo
  __shared__ ushort_t Uh[16*32];     // 1 KB [dv][cr] hi, swizzled
  __shared__ ushort_t Ul[16*32];     // 1 KB lo
  const int bid = blockIdx.x;
  const int bh = bid & 15, vs = bid >> 4;  // vs 0..31; bid%8==bh%8 -> XCD pin
  const int b = bh >> 2, h = bh & 3;
  const int t = threadIdx.x, lane = t & 63, wv = t >> 6;
  const int fr = lane & 15, fq = lane >> 4;
  const int mt = wv & 1;
  const bool isW = (wv < 2);

  for (int i = t; i < 512; i += 256) {
    ((uint4*)STh)[i] = (uint4){0u,0u,0u,0u};
    ((uint4*)STl)[i] = (uint4){0u,0u,0u,0u};
  }

  const size_t bhL = (size_t)bh * LL;
  const ushort_t* wqB = (isW ? w : qn) + bhL * DKk;  // phaseA A-operand source
  const ushort_t* kB  = kt + bhL * DKk;
  const ushort_t* uB  = ut + bhL * DVv;
  const ushort_t* ahB = ah + (size_t)bh * NC * 1024;
  const ushort_t* alB = al + (size_t)bh * NC * 1024;
  float* oB = dout + (size_t)b * LL * DD + h * DVv + vs * 8 + fr;

  floatx4 Sacc[4];   // dk slice [wv*64, wv*64+64) x dv(16, 8 useful)
#pragma unroll
  for (int i = 0; i < 4; ++i) Sacc[i] = (floatx4){0.f,0.f,0.f,0.f};

  short8 aw[8]; uint2 uu;
  auto loadA = [&](int ci) {
    const ushort_t* ap = wqB + (size_t)(ci*32 + mt*16 + fr) * DKk + fq*8;
#pragma unroll
    for (int ks = 0; ks < 8; ++ks) aw[ks] = *(const short8*)(ap + ks*32);
    if (isW)
      uu = *(const uint2*)(uB + (size_t)ci*8192 + (size_t)(vs*8 + (fr & 7))*32 + mt*16 + fq*4);
  };

  loadA(0);
  __syncthreads();   // ST zero-init visible

  for (int ci = 0; ci < NC; ++ci) {
    // current-chunk late-phase operands: issue now, consumed after BAR1
    short8 kf[4];
    {
      const ushort_t* kp = kB + (size_t)ci*8192 + (size_t)(wv*64 + fr)*32 + fq*8;
#pragma unroll
      for (int m = 0; m < 4; ++m) kf[m] = *(const short8*)(kp + m*512);
    }
    short8 afh, afl;
    if (!isW) {
      afh = *(const short8*)(ahB + (size_t)ci*1024 + (mt*16+fr)*32 + fq*8);
      afl = *(const short8*)(alB + (size_t)ci*1024 + (mt*16+fr)*32 + fq*8);
    }
    // phaseA
    floatx4 acc0, acc1;
    if (isW) {
      float u0,u1,u2,u3; unpack2(uu.x,u0,u1); unpack2(uu.y,u2,u3);
      acc0 = (floatx4){-u0,-u1,-u2,-u3};
      acc1 = (floatx4){0.f,0.f,0.f,0.f};
#pragma unroll
      for (int ks = 0; ks < 8; ++ks) {
        const short8 sh = *(const short8*)&STh[S16(fr, ks*32 + fq*8)];
        const short8 sl = *(const short8*)&STl[S16(fr, ks*32 + fq*8)];
        acc0 = __builtin_amdgcn_mfma_f32_16x16x32_bf16(aw[ks], sh, acc0, 0,0,0);
        acc1 = __builtin_amdgcn_mfma_f32_16x16x32_bf16(aw[ks], sl, acc1, 0,0,0);
      }
      const float v0 = -(acc0[0]+acc1[0]), v1 = -(acc0[1]+acc1[1]);
      const float v2 = -(acc0[2]+acc1[2]), v3 = -(acc0[3]+acc1[3]);
      unsigned ph0, pl0, ph1, pl1;
      split2t(v0, v1, ph0, pl0); split2t(v2, v3, ph1, pl1);
      *(uint2*)&Uh[U16(fr, mt*16 + fq*4)] = (uint2){ph0, ph1};
      *(uint2*)&Ul[U16(fr, mt*16 + fq*4)] = (uint2){pl0, pl1};
    } else {
      acc0 = (floatx4){0.f,0.f,0.f,0.f};
#pragma unroll
      for (int ks = 0; ks < 8; ++ks) {
        const short8 sh = *(const short8*)&STh[S16(fr, ks*32 + fq*8)];
        acc0 = __builtin_amdgcn_mfma_f32_16x16x32_bf16(aw[ks], sh, acc0, 0,0,0);
      }
    }
    __syncthreads();   // BAR1: uhat ready; all ST reads of this chunk done
    if (ci + 1 < NC) loadA(ci + 1);   // prefetch next phaseA operands
    const short8 uhh = *(const short8*)&Uh[U16(fr, fq*8)];
    const short8 uhl = *(const short8*)&Ul[U16(fr, fq*8)];
    if (!isW) {
      // o = q@Sh + attn@uhat; f32 stores (8 consecutive dv, fr<8 lanes)
      acc0 = __builtin_amdgcn_mfma_f32_16x16x32_bf16(afh, uhh, acc0, 0,0,0);
      acc0 = __builtin_amdgcn_mfma_f32_16x16x32_bf16(afh, uhl, acc0, 0,0,0);
      acc0 = __builtin_amdgcn_mfma_f32_16x16x32_bf16(afl, uhh, acc0, 0,0,0);
      if (fr < 8) {
        float* op = oB + (size_t)(ci*32 + mt*16 + fq*4) * DD;
#pragma unroll
        for (int r = 0; r < 4; ++r) op[(size_t)r * DD] = acc0[r];
      }
    }
    // S += kT @ (uhat_hi + uhat_lo): wave's own 4 dk tiles
#pragma unroll
    for (int m = 0; m < 4; ++m) {
      Sacc[m] = __builtin_amdgcn_mfma_f32_16x16x32_bf16(kf[m], uhh, Sacc[m], 0,0,0);
      Sacc[m] = __builtin_amdgcn_mfma_f32_16x16x32_bf16(kf[m], uhl, Sacc[m], 0,0,0);
    }
    // mirror S slice -> shared LDS image (hi/lo) for next chunk
#pragma unroll
    for (int m = 0; m < 4; ++m) {
      unsigned ph0, pl0, ph1, pl1;
      split2t(Sacc[m][0], Sacc[m][1], ph0, pl0);
      split2t(Sacc[m][2], Sacc[m][3], ph1, pl1);
      const int dk0 = wv*64 + m*16 + fq*4;
      *(uint2*)&STh[S16(fr, dk0)] = (uint2){ph0, ph1};
      *(uint2*)&STl[S16(fr, dk0)] = (uint2){pl0, pl1};
    }
    __syncthreads();   // BAR2: ST ready; Uh readers done
  }
}

// ---- EMA pass 1: per-segment local scan ------------------------------------
__global__ __launch_bounds__(256) void ema_local_kernel(const ushort_t* __restrict__ v,
  const float* __restrict__ gs, const float* __restrict__ gl,
  ushort_t* __restrict__ es, ushort_t* __restrict__ el,
  float* __restrict__ Bs, float* __restrict__ Bl,
  float* __restrict__ As, float* __restrict__ Al,
  float* __restrict__ PfS, float* __restrict__ PfL)
{
  const int bid = blockIdx.x;
  const int seg = bid & (NSEG - 1), bh = bid >> 6;
  const int b = bh >> 2, h = bh & 3;
  const int dv = threadIdx.x;
  const int l0 = seg * SEG;
  const ushort_t* vp = v + ((size_t)bh*LL + l0) * DVv + dv;
  const float* gsp = gs + (size_t)bh*LL + l0;
  const float* glp = gl + (size_t)bh*LL + l0;
  ushort_t* esp = es + ((size_t)b*LL + l0)*DD + h*DVv + dv;
  ushort_t* elp = el + ((size_t)b*LL + l0)*DD + h*DVv + dv;
  float* pfs = PfS + (size_t)bh*LL + l0;
  float* pfl = PfL + (size_t)bh*LL + l0;
  float s1 = 0.f, s2 = 0.f, p1 = 1.f, p2 = 1.f;
  for (int j = 0; j < SEG; ++j) {
    const float vv = bf2f(vp[(size_t)j * DVv]);
    const float a = gsp[j], g2 = glp[j];
    s1 = fmaf(a,  s1, (1.f - a)  * vv);
    s2 = fmaf(g2, s2, (1.f - g2) * vv);
    p1 *= a; p2 *= g2;
    esp[(size_t)j * DD] = f2bf(s1);
    elp[(size_t)j * DD] = f2bf(s2);
    if (dv == 0) { pfs[j] = p1; pfl[j] = p2; }
  }
  const size_t o = (((size_t)bh*NSEG + seg) << 8) + dv;
  Bs[o] = s1; Bl[o] = s2;
  if (dv == 0) { As[bh*NSEG + seg] = p1; Al[bh*NSEG + seg] = p2; }
}

// ---- EMA pass 2: cross-segment carry (carry INTO each segment) -------------
__global__ __launch_bounds__(256) void ema_carry_kernel(
  const float* __restrict__ Bs, const float* __restrict__ Bl,
  const float* __restrict__ As, const float* __restrict__ Al,
  float* __restrict__ Cs, float* __restrict__ Cl)
{
  const int bh = blockIdx.x;
  const int dv = threadIdx.x;
  __shared__ float Ash[NSEG], Alh[NSEG];
  if (dv < NSEG) { Ash[dv] = As[bh*NSEG + dv]; Alh[dv] = Al[bh*NSEG + dv]; }
  __syncthreads();
  float c1 = 0.f, c2 = 0.f;
  for (int s = 0; s < NSEG; ++s) {
    const size_t o = (((size_t)bh*NSEG + s) << 8) + dv;
    Cs[o] = c1; Cl[o] = c2;
    c1 = fmaf(Ash[s], c1, Bs[o]);
    c2 = fmaf(Alh[s], c2, Bl[o]);
  }
}

// ---- combine + per-head RMSNorm; fuses EMA segment-carry correction --------
__global__ __launch_bounds__(64) void combine_kernel(const ushort_t* __restrict__ v,
  const ushort_t* __restrict__ es, const ushort_t* __restrict__ el,
  const float* __restrict__ dov, const float* __restrict__ wgt,
  const float* __restrict__ onw,
  const float* __restrict__ Cs, const float* __restrict__ Cl,
  const float* __restrict__ PfS, const float* __restrict__ PfL,
  ushort_t* __restrict__ outp)
{
  const int bid = blockIdx.x;
  const int h = bid & 3;
  const size_t bl = (size_t)(bid >> 2);
  const int lane = threadIdx.x;
  const size_t b = bl >> 12;
  const size_t l = bl & (LL - 1);
  const int bh = (int)(b * HH) + h;
  const int seg = (int)(l >> 6);
  const size_t vidx = (((b*HH + h) * (size_t)LL) + l) * DVv + lane*4;
  const size_t didx = bl * DD + h*DVv + lane*4;
  const uint2 vu = *(const uint2*)(v + vidx);
  const uint2 eu = *(const uint2*)(es + didx);
  const uint2 gu = *(const uint2*)(el + didx);
  const float4 d4 = *(const float4*)(dov + didx);
  const float pS = PfS[(size_t)bh*LL + l];
  const float pL = PfL[(size_t)bh*LL + l];
  const float4 cs4 = *(const float4*)(Cs + (((size_t)bh*NSEG + seg) << 8) + lane*4);
  const float4 cl4 = *(const float4*)(Cl + (((size_t)bh*NSEG + seg) << 8) + lane*4);
  float vf[4], ef[4], gf[4];
  unpack2(vu.x, vf[0], vf[1]); unpack2(vu.y, vf[2], vf[3]);
  unpack2(eu.x, ef[0], ef[1]); unpack2(eu.y, ef[2], ef[3]);
  unpack2(gu.x, gf[0], gf[1]); unpack2(gu.y, gf[2], gf[3]);
  ef[0] = fmaf(pS, cs4.x, ef[0]); ef[1] = fmaf(pS, cs4.y, ef[1]);
  ef[2] = fmaf(pS, cs4.z, ef[2]); ef[3] = fmaf(pS, cs4.w, ef[3]);
  gf[0] = fmaf(pL, cl4.x, gf[0]); gf[1] = fmaf(pL, cl4.y, gf[1]);
  gf[2] = fmaf(pL, cl4.z, gf[2]); gf[3] = fmaf(pL, cl4.w, gf[3]);
  const float* wp = wgt + (size_t)bid * 4;
  const float w0 = wp[0], w1 = wp[1], w2 = wp[2], w3 = wp[3];
  float o[4];
  const float df[4] = {d4.x, d4.y, d4.z, d4.w};
  float ss = 0.f;
#pragma unroll
  for (int i = 0; i < 4; ++i) {
    o[i] = w0*vf[i] + w1*ef[i] + w2*df[i] + w3*gf[i];
    ss = fmaf(o[i], o[i], ss);
  }
#pragma unroll
  for (int off = 1; off < 64; off <<= 1) ss += __shfl_xor(ss, off);
  const float sc = rsqrtf(ss * (1.f / DVv) + 1e-5f);
  const float4 nw = *(const float4*)(onw + lane*4);
  uint2 pk;
  pk.x = pack2(o[0]*sc*nw.x, o[1]*sc*nw.y);
  pk.y = pack2(o[2]*sc*nw.z, o[3]*sc*nw.w);
  *(uint2*)(outp + didx) = pk;
}

extern "C" void kernel_launch(void* const* d_in, const int* in_sizes, int n_in,
                              void* d_out, int out_size, void* d_ws, size_t ws_size,
                              hipStream_t stream)
{
  const float* x    = (const float*)d_in[0];
  const float* Wq   = (const float*)d_in[1];
  const float* Wk   = (const float*)d_in[2];
  const float* Wv   = (const float*)d_in[3];
  const float* cqw  = (const float*)d_in[4];
  const float* ckw  = (const float*)d_in[5];
  const float* cvw  = (const float*)d_in[6];
  const float* Wb   = (const float*)d_in[7];
  const float* Wds  = (const float*)d_in[8];
  const float* bds  = (const float*)d_in[9];
  const float* Wdl  = (const float*)d_in[10];
  const float* bdl  = (const float*)d_in[11];
  const float* Wtr  = (const float*)d_in[12];
  const float* btr  = (const float*)d_in[13];
  const float* Wc   = (const float*)d_in[14];
  const float* bc   = (const float*)d_in[15];
  const float* Wl   = (const float*)d_in[16];
  const float* blc  = (const float*)d_in[17];
  const float* Wg   = (const float*)d_in[18];
  const float* bg   = (const float*)d_in[19];
  const float* ltc  = (const float*)d_in[20];
  const float* ltf  = (const float*)d_in[21];
  const float* onw  = (const float*)d_in[22];
  const float* Wo   = (const float*)d_in[23];
  float* outp = (float*)d_out;

  const size_t BLD = (size_t)BB * LL * DD;
  unsigned char* w8 = (unsigned char*)d_ws;
  const size_t SL = BLD * 2;                        // 32 MB bf16 slab
  ushort_t* SA = (ushort_t*)(w8 + 0*SL);   // qraw -> kn -> kT -> opre
  ushort_t* SB = (ushort_t*)(w8 + 1*SL);   // kraw -> vv
  ushort_t* SC = (ushort_t*)(w8 + 2*SL);   // vraw -> uT
  ushort_t* SD = (ushort_t*)(w8 + 3*SL);   // xb -> qn -> el(local)
  ushort_t* SE = (ushort_t*)(w8 + 4*SL);   // w  -> es(local)
  ushort_t* zb   = (ushort_t*)(w8 + 5*SL);
  ushort_t* attn_hi = (ushort_t*)(w8 + 5*SL + BLD);
  ushort_t* attn_lo = attn_hi + (size_t)BB*HH*NC*1024;
  float*    beta = (float*)(attn_hi + 2*(size_t)BB*HH*NC*1024);
  float*    gs   = beta + (size_t)BB*HH*LL;
  float*    gl   = gs   + (size_t)BB*HH*LL;
  float*    wgt  = gl   + (size_t)BB*HH*LL;
  float*    Bs   = wgt  + (size_t)BB*LL*HH*4;
  float*    Bl   = Bs   + (size_t)BB*HH*NSEG*256;
  float*    Cs   = Bl   + (size_t)BB*HH*NSEG*256;
  float*    Cl   = Cs   + (size_t)BB*HH*NSEG*256;
  float*    As   = Cl   + (size_t)BB*HH*NSEG*256;
  float*    Al   = As   + (size_t)BB*HH*NSEG;
  float*    PfS  = Al   + (size_t)BB*HH*NSEG;
  float*    PfL  = PfS  + (size_t)BB*HH*LL;
  ushort_t* Wqb  = (ushort_t*)(PfL + (size_t)BB*HH*LL);
  ushort_t* Wkb  = Wqb + (size_t)DD*DD;
  ushort_t* Wvb  = Wkb + (size_t)DD*DD;
  ushort_t* Wob  = Wvb + (size_t)DD*DD;
  ushort_t* Wtrb = Wob + (size_t)DD*DD;
  ushort_t* xb   = SD;                     // bf16 x, consumed by the 4 x-GEMMs
  float*    dov  = outp;

  const int MBL = BB * LL;  // 16384
  dim3 blk256(256);

  cvt_bf16_kernel<<<dim3((unsigned)(BLD/8/256)), blk256, 0, stream>>>(x, xb, (int)(BLD/8));
  cvt_bf16_kernel<<<dim3(DD*DD/8/256), blk256, 0, stream>>>(Wq, Wqb, DD*DD/8);
  cvt_bf16_kernel<<<dim3(DD*DD/8/256), blk256, 0, stream>>>(Wk, Wkb, DD*DD/8);
  cvt_bf16_kernel<<<dim3(DD*DD/8/256), blk256, 0, stream>>>(Wv, Wvb, DD*DD/8);
  cvt_bf16_kernel<<<dim3(DD*DD/8/256), blk256, 0, stream>>>(Wo, Wob, DD*DD/8);
  cvt_bf16_kernel<<<dim3(HIDD*DD/8/256), blk256, 0, stream>>>(Wtr, Wtrb, HIDD*DD/8);

  gemm_bf16<0,1><<<dim3(DD/128, MBL/128), blk256, 0, stream>>>(xb, Wqb, nullptr, SA, MBL, DD, DD);
  gemm_bf16<0,1><<<dim3(DD/128, MBL/128), blk256, 0, stream>>>(xb, Wkb, nullptr, SB, MBL, DD, DD);
  gemm_bf16<0,1><<<dim3(DD/128, MBL/128), blk256, 0, stream>>>(xb, Wvb, nullptr, SC, MBL, DD, DD);
  gemm_bf16<1,1><<<dim3(HIDD/128, MBL/128), blk256, 0, stream>>>(xb, Wtrb, btr, zb, MBL, HIDD, DD);
  small_proj_kernel<<<dim3(MBL), blk256, 0, stream>>>(x, Wb, Wds, bds, Wdl, bdl, beta, gs, gl);
  gate_kernel<<<dim3(MBL), blk256, 0, stream>>>(zb, Wc, bc, Wl, blc, Wg, bg, ltc, ltf, wgt);
  conv_silu_kernel<<<dim3((unsigned)(BLD/8/256)), blk256, 0, stream>>>(SA, cqw, SD);  // qn=SD
  conv_silu_kernel<<<dim3((unsigned)(BLD/8/256)), blk256, 0, stream>>>(SB, ckw, SA);  // kn=SA
  conv_silu_kernel<<<dim3((unsigned)(BLD/8/256)), blk256, 0, stream>>>(SC, cvw, SB);  // vv=SB
  prep_kernel<<<dim3(BB*HH*NC), blk256, 0, stream>>>(SD, SA, SB, beta, SC, SE, attn_hi, attn_lo); // uT=SC w=SE kT=SA
  scan_kernel<<<dim3(512), blk256, 0, stream>>>(SD, SA, SC, SE, attn_hi, attn_lo, dov);
  ema_local_kernel<<<dim3(BB*HH*NSEG), blk256, 0, stream>>>(SB, gs, gl, SE, SD, Bs, Bl, As, Al, PfS, PfL); // es=SE el=SD
  ema_carry_kernel<<<dim3(BB*HH), blk256, 0, stream>>>(Bs, Bl, As, Al, Cs, Cl);
  combine_kernel<<<dim3(MBL*HH), dim3(64), 0, stream>>>(SB, SE, SD, dov, wgt, onw, Cs, Cl, PfS, PfL, SA); // opre=SA
  gemm_bf16<0,0><<<dim3(DD/128, MBL/128), blk256, 0, stream>>>(SA, Wob, nullptr, outp, MBL, DD, DD);
}

// Round 8
// 1045.996 us; speedup vs baseline: 1.0951x; 1.0951x over previous
//
#include <hip/hip_runtime.h>
#include <math.h>

#define BB 4
#define LL 4096
#define DD 1024
#define HH 4
#define DKk 256
#define DVv 256
#define HIDD 512
#define NC 128   // number of 32-chunks in L
#define NSEG 64  // EMA segments
#define SEG 64   // EMA segment length

typedef unsigned short ushort_t;
typedef __attribute__((ext_vector_type(8))) short short8;
typedef __attribute__((ext_vector_type(4))) float floatx4;

__device__ __forceinline__ float sigm(float x) { return 1.f / (1.f + __expf(-x)); }

__device__ __forceinline__ float bf2f(ushort_t u) {
  union { unsigned int i; float f; } c; c.i = ((unsigned int)u) << 16; return c.f;
}
__device__ __forceinline__ ushort_t f2bf(float f) {
  union { float f; unsigned int i; } c; c.f = f;
  unsigned int lsb = (c.i >> 16) & 1u;
  return (ushort_t)((c.i + 0x7fffu + lsb) >> 16);
}
__device__ __forceinline__ void unpack2(unsigned int u, float& a, float& b) {
  union { unsigned int i; float f; } c0, c1;
  c0.i = u << 16; c1.i = u & 0xffff0000u; a = c0.f; b = c1.f;
}
__device__ __forceinline__ unsigned int pack2(float a, float b) {
  return (unsigned int)f2bf(a) | ((unsigned int)f2bf(b) << 16);
}
__device__ __forceinline__ void unpack8(const uint4 v, float* o) {
  unpack2(v.x, o[0], o[1]); unpack2(v.y, o[2], o[3]);
  unpack2(v.z, o[4], o[5]); unpack2(v.w, o[6], o[7]);
}
__device__ __forceinline__ float ubits(unsigned u) {
  union { unsigned i; float f; } c; c.i = u; return c.f;
}
// exact truncate-split of two floats into packed bf16 hi and bf16 lo words
__device__ __forceinline__ void split2t(float a, float b, unsigned& hi, unsigned& lo) {
  union { float f; unsigned u; } ca, cb; ca.f = a; cb.f = b;
  const unsigned ha = ca.u & 0xffff0000u, hb = cb.u & 0xffff0000u;
  hi = (ha >> 16) | hb;
  union { float f; unsigned u; } la, lb;
  la.f = a - ubits(ha); lb.f = b - ubits(hb);
  lo = (la.u >> 16) | (lb.u & 0xffff0000u);
}
__device__ __forceinline__ void gload16(const ushort_t* g, ushort_t* l) {
  __builtin_amdgcn_global_load_lds(
      (const __attribute__((address_space(1))) void*)g,
      (__attribute__((address_space(3))) void*)l, 16, 0, 0);
}

// ---- fused f32 -> bf16 converts (x + 5 weight matrices), 8 elems/thread ----
__global__ __launch_bounds__(256) void cvt_all_kernel(
    const float* __restrict__ x,  const float* __restrict__ Wq,
    const float* __restrict__ Wk, const float* __restrict__ Wv,
    const float* __restrict__ Wo, const float* __restrict__ Wtr,
    ushort_t* __restrict__ xb,  ushort_t* __restrict__ Wqb,
    ushort_t* __restrict__ Wkb, ushort_t* __restrict__ Wvb,
    ushort_t* __restrict__ Wob, ushort_t* __restrict__ Wtrb)
{
  const int NX = (int)((size_t)BB*LL*DD/8), NW = DD*DD/8, NT = HIDD*DD/8;
  int i = blockIdx.x * 256 + threadIdx.x;
  const float* src; ushort_t* dst;
  if (i < NX) { src = x; dst = xb; }
  else {
    i -= NX;
    if (i < NW) { src = Wq; dst = Wqb; }
    else { i -= NW;
      if (i < NW) { src = Wk; dst = Wkb; }
      else { i -= NW;
        if (i < NW) { src = Wv; dst = Wvb; }
        else { i -= NW;
          if (i < NW) { src = Wo; dst = Wob; }
          else { i -= NW; if (i >= NT) return; src = Wtr; dst = Wtrb; }
        }
      }
    }
  }
  const float4 a = ((const float4*)src)[2*i];
  const float4 b = ((const float4*)src)[2*i + 1];
  uint4 p;
  p.x = pack2(a.x, a.y); p.y = pack2(a.z, a.w);
  p.z = pack2(b.x, b.y); p.w = pack2(b.z, b.w);
  ((uint4*)dst)[i] = p;
}

// ---- MFMA GEMM, bf16 A and W, global_load_lds staging ----------------------
// C(M,N) = A(M,K) @ W(N,K)^T.  ACT==1: +bias then SiLU. BF16OUT: bf16 else f32.
template<int ACT, int BF16OUT>
__global__ __launch_bounds__(256) void gemm_bf16(const ushort_t* __restrict__ A,
    const ushort_t* __restrict__ W, const float* __restrict__ bias,
    void* __restrict__ Cv, int M, int N, int K)
{
  __shared__ ushort_t As[128*32];
  __shared__ ushort_t Ws[128*32];
  const int tid = threadIdx.x;
  const int bm = blockIdx.y * 128, bn = blockIdx.x * 128;
  const int lane = tid & 63, wave = tid >> 6;
  const int wm = (wave >> 1) * 64, wn = (wave & 1) * 64;
  const int fr = lane & 15, fq = lane >> 4;
  // staging: wave w covers rows w*16..w*16+16 of each 64-row half; lane*16B linear LDS
  const int srow = wave * 16 + (lane >> 2);
  const int scol = (lane & 3) * 8;
  const ushort_t* Ap = A + (size_t)(bm + srow) * K + scol;
  const ushort_t* Wp = W + (size_t)(bn + srow) * K + scol;
  ushort_t* AsD = &As[wave * 512];
  ushort_t* WsD = &Ws[wave * 512];
  floatx4 acc[4][4];
#pragma unroll
  for (int i = 0; i < 4; ++i)
#pragma unroll
    for (int j = 0; j < 4; ++j) acc[i][j] = (floatx4){0.f, 0.f, 0.f, 0.f};

  for (int k0 = 0; k0 < K; k0 += 32) {
    __syncthreads();                       // prev tile reads done
    gload16(Ap + k0, AsD);
    gload16(Ap + (size_t)64 * K + k0, AsD + 64*32);
    gload16(Wp + k0, WsD);
    gload16(Wp + (size_t)64 * K + k0, WsD + 64*32);
    __syncthreads();                       // staging complete (vmcnt drained)
    short8 af[4], bf_[4];
#pragma unroll
    for (int mt = 0; mt < 4; ++mt)
      af[mt] = *(const short8*)&As[(wm + mt*16 + fr)*32 + fq*8];
#pragma unroll
    for (int nt = 0; nt < 4; ++nt)
      bf_[nt] = *(const short8*)&Ws[(wn + nt*16 + fr)*32 + fq*8];
#pragma unroll
    for (int mt = 0; mt < 4; ++mt)
#pragma unroll
      for (int nt = 0; nt < 4; ++nt)
        acc[mt][nt] = __builtin_amdgcn_mfma_f32_16x16x32_bf16(af[mt], bf_[nt], acc[mt][nt], 0, 0, 0);
  }
#pragma unroll
  for (int mt = 0; mt < 4; ++mt) {
#pragma unroll
    for (int reg = 0; reg < 4; ++reg) {
      const int row = bm + wm + mt*16 + fq*4 + reg;
#pragma unroll
      for (int nt = 0; nt < 4; ++nt) {
        const int col = bn + wn + nt*16 + fr;
        float v = acc[mt][nt][reg];
        if (ACT == 1) { v += bias[col]; v = v * sigm(v); }
        if (BF16OUT) ((ushort_t*)Cv)[(size_t)row * N + col] = f2bf(v);
        else         ((float*)Cv)[(size_t)row * N + col] = v;
      }
    }
  }
}

// ---- depthwise causal conv(k=4)+SiLU, vectorized 8/thread ------------------
__global__ __launch_bounds__(256) void conv_silu_kernel(const ushort_t* __restrict__ xin,
    const float* __restrict__ wc, ushort_t* __restrict__ outp)
{
  const size_t i8 = (size_t)blockIdx.x * 256 + threadIdx.x;  // over B*L*D/8
  const int d8 = (int)((i8 & 127) << 3);
  const int l  = (int)((i8 >> 7) & (LL - 1));
  const int b  = (int)(i8 >> 19);
  const ushort_t* xp = xin + i8 * 8;
  const uint4 z4 = (uint4){0u,0u,0u,0u};
  const uint4 v0 = *(const uint4*)xp;
  const uint4 v1 = (l >= 1) ? *(const uint4*)(xp - DD)   : z4;
  const uint4 v2 = (l >= 2) ? *(const uint4*)(xp - 2*DD) : z4;
  const uint4 v3 = (l >= 3) ? *(const uint4*)(xp - 3*DD) : z4;
  float x0[8], x1[8], x2[8], x3[8];
  unpack8(v0, x0); unpack8(v1, x1); unpack8(v2, x2); unpack8(v3, x3);
  unsigned pk[4];
#pragma unroll
  for (int p = 0; p < 4; ++p) {
    float o2[2];
#pragma unroll
    for (int q = 0; q < 2; ++q) {
      const int j = p*2 + q;
      const float4 w = *(const float4*)(wc + (d8 + j) * 4);
      float acc = w.w * x0[j];
      acc = fmaf(w.z, x1[j], acc);
      acc = fmaf(w.y, x2[j], acc);
      acc = fmaf(w.x, x3[j], acc);
      o2[q] = acc * sigm(acc);
    }
    pk[p] = pack2(o2[0], o2[1]);
  }
  const int h = d8 >> 8, dk = d8 & 255;
  *(uint4*)(outp + (((size_t)(b*HH + h))*LL + l)*DKk + dk) = *(uint4*)pk;
}

// ---- beta / g_s / g_l: 12 length-1024 dots per (b,l), x fp32 ---------------
__global__ __launch_bounds__(256) void small_proj_kernel(const float* __restrict__ x,
   const float* __restrict__ Wb, const float* __restrict__ Wds, const float* __restrict__ bds,
   const float* __restrict__ Wdl, const float* __restrict__ bdl,
   float* __restrict__ beta, float* __restrict__ gs, float* __restrict__ gl)
{
  const int bl = blockIdx.x;
  const int t = threadIdx.x, wave = t >> 6, lane = t & 63;
  __shared__ float res[12];
  const float* xr = x + (size_t)bl * DD + lane * 16;
  const float4 x0 = *(const float4*)(xr);
  const float4 x1 = *(const float4*)(xr + 4);
  const float4 x2 = *(const float4*)(xr + 8);
  const float4 x3 = *(const float4*)(xr + 12);
  for (int rr = 0; rr < 3; ++rr) {
    const int r = wave * 3 + rr;
    const int mat = r >> 2, h = r & 3;
    const float* Wr = (mat == 0 ? Wb : (mat == 1 ? Wds : Wdl)) + (size_t)h * DD + lane * 16;
    const float4 w0 = *(const float4*)(Wr);
    const float4 w1 = *(const float4*)(Wr + 4);
    const float4 w2 = *(const float4*)(Wr + 8);
    const float4 w3 = *(const float4*)(Wr + 12);
    float p = x0.x*w0.x + x0.y*w0.y + x0.z*w0.z + x0.w*w0.w
            + x1.x*w1.x + x1.y*w1.y + x1.z*w1.z + x1.w*w1.w
            + x2.x*w2.x + x2.y*w2.y + x2.z*w2.z + x2.w*w2.w
            + x3.x*w3.x + x3.y*w3.y + x3.z*w3.z + x3.w*w3.w;
#pragma unroll
    for (int o = 1; o < 64; o <<= 1) p += __shfl_xor(p, o);
    if (lane == 0) res[r] = p;
  }
  __syncthreads();
  if (t < 12) {
    const int mat = t >> 2, h = t & 3;
    float v = res[t];
    if (mat == 1) v += bds[h];
    if (mat == 2) v += bdl[h];
    v = sigm(v);
    const int b = bl >> 12, l = bl & (LL - 1);
    const size_t o = ((size_t)(b*HH + h))*LL + l;
    (mat == 0 ? beta : (mat == 1 ? gs : gl))[o] = v;
  }
}

// ---- chunk-local prep: vectorized l2norm, MFMA attn(hi/lo)+Lm, solves ------
#define QS 264
__global__ __launch_bounds__(256) void prep_kernel(ushort_t* __restrict__ q,
    ushort_t* __restrict__ k, const ushort_t* __restrict__ v,
    const float* __restrict__ beta,
    ushort_t* __restrict__ u, ushort_t* __restrict__ w,
    ushort_t* __restrict__ ah, ushort_t* __restrict__ al)
{
  __shared__ ushort_t qb[32*QS];
  __shared__ ushort_t kb[32*QS];
  __shared__ float Lm[32*32];
  __shared__ float betas[32];
  const int bid = blockIdx.x;
  const int ci = bid & (NC - 1);
  const int bh = bid >> 7;
  const int t = threadIdx.x;
  const size_t base = ((size_t)bh * LL + ci*32) * DKk;
  if (t < 32) betas[t] = beta[(size_t)bh * LL + ci*32 + t];
  for (int i4 = t; i4 < 1024; i4 += 256) {
    const int r = i4 >> 5, e = (i4 & 31) * 8;
    *(uint4*)&qb[r*QS + e] = *(const uint4*)(q + base + r*256 + e);
    *(uint4*)&kb[r*QS + e] = *(const uint4*)(k + base + r*256 + e);
  }
  __syncthreads();
  // l2norm: vectorized -- 8 uint4 reads, values kept in regs, 8 uint4 writes
  {
    const int r = t >> 3, g = t & 7;
    const int e0 = g * 32;
    float qf[32], kf[32];
#pragma unroll
    for (int j = 0; j < 4; ++j) {
      const uint4 qv = *(const uint4*)&qb[r*QS + e0 + j*8];
      const uint4 kv = *(const uint4*)&kb[r*QS + e0 + j*8];
      unpack8(qv, qf + j*8); unpack8(kv, kf + j*8);
    }
    float sq = 0.f, sk = 0.f;
#pragma unroll
    for (int j = 0; j < 32; ++j) {
      sq = fmaf(qf[j], qf[j], sq);
      sk = fmaf(kf[j], kf[j], sk);
    }
#pragma unroll
    for (int o = 1; o < 8; o <<= 1) { sq += __shfl_xor(sq, o); sk += __shfl_xor(sk, o); }
    const float rq = rsqrtf(sq + 1e-6f), rk = rsqrtf(sk + 1e-6f);
#pragma unroll
    for (int j = 0; j < 4; ++j) {
      uint4 qo, ko;
      qo.x = pack2(qf[j*8+0]*rq, qf[j*8+1]*rq);
      qo.y = pack2(qf[j*8+2]*rq, qf[j*8+3]*rq);
      qo.z = pack2(qf[j*8+4]*rq, qf[j*8+5]*rq);
      qo.w = pack2(qf[j*8+6]*rq, qf[j*8+7]*rq);
      ko.x = pack2(kf[j*8+0]*rk, kf[j*8+1]*rk);
      ko.y = pack2(kf[j*8+2]*rk, kf[j*8+3]*rk);
      ko.z = pack2(kf[j*8+4]*rk, kf[j*8+5]*rk);
      ko.w = pack2(kf[j*8+6]*rk, kf[j*8+7]*rk);
      *(uint4*)&qb[r*QS + e0 + j*8] = qo;
      *(uint4*)&kb[r*QS + e0 + j*8] = ko;
    }
  }
  __syncthreads();
  // write back normalized q (row-major, used as MFMA A-frags in scan)
  for (int i4 = t; i4 < 1024; i4 += 256) {
    const int r = i4 >> 5, e = (i4 & 31) * 8;
    *(uint4*)(q + base + r*256 + e) = *(const uint4*)&qb[r*QS + e];
  }
  // write kT (dk-major: [dk][cr]) into the k slab; thread t = dk
  {
    unsigned int pk[16];
#pragma unroll
    for (int j = 0; j < 16; ++j)
      pk[j] = (unsigned int)kb[(2*j)*QS + t] | ((unsigned int)kb[(2*j+1)*QS + t] << 16);
    uint4* kd = (uint4*)(k + base + (size_t)t*32);
#pragma unroll
    for (int j = 0; j < 4; ++j) kd[j] = ((const uint4*)pk)[j];
  }
  // attn = q@k^T (tril), Lm = beta_i * (k@k^T) (strict tril) -- via MFMA.
  {
    const int lane = t & 63, wv4 = t >> 6;
    const int fr = lane & 15, fq = lane >> 4;
    const int it = wv4 >> 1, jt = wv4 & 1;
    floatx4 dq = (floatx4){0.f,0.f,0.f,0.f};
    floatx4 dk2 = (floatx4){0.f,0.f,0.f,0.f};
#pragma unroll
    for (int ks = 0; ks < 8; ++ks) {
      const short8 bfk = *(const short8*)&kb[(jt*16+fr)*QS + ks*32 + fq*8];
      const short8 afq = *(const short8*)&qb[(it*16+fr)*QS + ks*32 + fq*8];
      const short8 afk = *(const short8*)&kb[(it*16+fr)*QS + ks*32 + fq*8];
      dq  = __builtin_amdgcn_mfma_f32_16x16x32_bf16(afq, bfk, dq, 0,0,0);
      dk2 = __builtin_amdgcn_mfma_f32_16x16x32_bf16(afk, bfk, dk2, 0,0,0);
    }
#pragma unroll
    for (int reg = 0; reg < 4; ++reg) {
      const int i = it*16 + fq*4 + reg;
      const int j = jt*16 + fr;
      const float av = (j <= i) ? dq[reg] : 0.f;
      const ushort_t hh = f2bf(av);
      const size_t aoff = ((size_t)bh*NC + ci)*1024 + (size_t)i*32 + j;
      ah[aoff] = hh;
      al[aoff] = f2bf(av - bf2f(hh));
      Lm[i*32 + j] = (j < i) ? betas[i] * dk2[reg] : 0.f;
    }
  }
  __syncthreads();
  {
    float cu[32], cw[32];
#pragma unroll
    for (int r = 0; r < 32; ++r) {
      cu[r] = bf2f(v[base + r*256 + t]) * betas[r];
      cw[r] = bf2f(kb[r*QS + t]) * betas[r];
    }
#pragma unroll
    for (int i = 1; i < 32; ++i) {
      float au = cu[i], aw = cw[i];
#pragma unroll
      for (int j = 0; j < i; ++j) {
        const float lm = Lm[i*32 + j];
        au = fmaf(-lm, cu[j], au);
        aw = fmaf(-lm, cw[j], aw);
      }
      cu[i] = au; cw[i] = aw;
    }
    // uT (dv-major: [dv][cr]); thread t = dv -> 64B contiguous
    {
      unsigned int pu[16];
#pragma unroll
      for (int j = 0; j < 16; ++j) pu[j] = pack2(cu[2*j], cu[2*j+1]);
      uint4* ud = (uint4*)(u + base + (size_t)t*32);
#pragma unroll
      for (int j = 0; j < 4; ++j) ud[j] = ((const uint4*)pu)[j];
    }
#pragma unroll
    for (int r = 0; r < 32; ++r) w[base + r*256 + t] = f2bf(cw[r]);
  }
}

// ---- fused: MFMA scan (blocks 0..255, r6 structure) + gate (blocks 256+) ---
// scan: task = (bh, vs16). 4 specialized waves, 2 barriers/chunk, S hi/lo in
// LDS, per-wave 64-dk slice of S in f32 accumulators. gate blocks fill the
// idle SIMDs during the scan window (gate output consumed only after scan).
#define S16(dv,kk) (((dv)<<8) + ((kk) ^ (((dv)&7)<<3)))
#define U16(dv,cr) (((dv)<<5) + ((cr) ^ (((dv)&3)<<3)))

__global__ __launch_bounds__(256, 1) void scan_gate_kernel(
    const ushort_t* __restrict__ qn, const ushort_t* __restrict__ kt,
    const ushort_t* __restrict__ ut, const ushort_t* __restrict__ w,
    const ushort_t* __restrict__ ah, const ushort_t* __restrict__ al,
    float* __restrict__ dout,
    const ushort_t* __restrict__ z,
    const float* __restrict__ Wc, const float* __restrict__ bc,
    const float* __restrict__ Wl, const float* __restrict__ bl_,
    const float* __restrict__ Wg, const float* __restrict__ bg,
    const float* __restrict__ ltc, const float* __restrict__ ltf,
    float* __restrict__ wgt)
{
  __shared__ ushort_t STh[16*256];   // 8 KB [dv][dk] hi, swizzled
  __shared__ ushort_t STl[16*256];   // 8 KB lo
  __shared__ ushort_t Uh[16*32];     // 1 KB [dv][cr] hi, swizzled
  __shared__ ushort_t Ul[16*32];     // 1 KB lo
  const int bid = blockIdx.x;
  const int t = threadIdx.x;

  if (bid >= 256) {
    // ---------------- gate branch ----------------
    const int bl = bid - 256;
    const int wave = t >> 6, lane = t & 63;
    float* res = (float*)STh;   // 96 B carved from scan scratch
    const uint4 zv = *(const uint4*)(z + (size_t)bl * HIDD + lane * 8);
    float zf[8]; unpack8(zv, zf);
    for (int rr = 0; rr < 6; ++rr) {
      const int r = wave * 6 + rr;
      const int mat = r >> 3, qi = r & 7;
      const float* Wr = (mat == 0 ? Wc : (mat == 1 ? Wl : Wg)) + (size_t)qi * HIDD + lane * 8;
      const float4 w0 = *(const float4*)(Wr);
      const float4 w1 = *(const float4*)(Wr + 4);
      float p = zf[0]*w0.x + zf[1]*w0.y + zf[2]*w0.z + zf[3]*w0.w
              + zf[4]*w1.x + zf[5]*w1.y + zf[6]*w1.z + zf[7]*w1.w;
#pragma unroll
      for (int o = 1; o < 64; o <<= 1) p += __shfl_xor(p, o);
      if (lane == 0) {
        const float* br = (mat == 0 ? bc : (mat == 1 ? bl_ : bg));
        res[r] = p + br[qi];
      }
    }
    __syncthreads();
    if (t < 4) {
      const float tc = logf(1.f + __expf(ltc[t])) + 1e-4f;
      const float tf = logf(1.f + __expf(ltf[t])) + 1e-4f;
      const float pg0 = sigm((res[2*t]     - res[2*t+1])     / tc);
      const float q0  = sigm((res[8+2*t]   - res[8+2*t+1])   / tf);
      const float r0  = sigm((res[16+2*t]  - res[16+2*t+1])  / tf);
      float* o = wgt + ((size_t)bl * HH + t) * 4;
      o[0] = pg0 * q0;         o[1] = pg0 * (1.f - q0);
      o[2] = (1.f - pg0) * r0; o[3] = (1.f - pg0) * (1.f - r0);
    }
    return;
  }

  // ---------------- scan branch (r6 structure, dv-slice 16) ----------------
  const int bh = bid & 15, vs = bid >> 4;  // bid%8==bh%8 -> bh pinned to XCD
  const int b = bh >> 2, h = bh & 3;
  const int lane = t & 63, wv = t >> 6;
  const int fr = lane & 15, fq = lane >> 4;
  const int mt = wv & 1;
  const bool isW = (wv < 2);

  for (int i = t; i < 512; i += 256) {
    ((uint4*)STh)[i] = (uint4){0u,0u,0u,0u};
    ((uint4*)STl)[i] = (uint4){0u,0u,0u,0u};
  }

  const size_t bhL = (size_t)bh * LL;
  const ushort_t* wqB = (isW ? w : qn) + bhL * DKk;  // phaseA A-operand source
  const ushort_t* kB  = kt + bhL * DKk;
  const ushort_t* uB  = ut + bhL * DVv;
  const ushort_t* ahB = ah + (size_t)bh * NC * 1024;
  const ushort_t* alB = al + (size_t)bh * NC * 1024;
  float* oB = dout + (size_t)b * LL * DD + h * DVv + vs * 16 + fr;

  floatx4 Sacc[4];   // dk slice [wv*64, wv*64+64) x dv16
#pragma unroll
  for (int i = 0; i < 4; ++i) Sacc[i] = (floatx4){0.f,0.f,0.f,0.f};

  short8 aw[8]; uint2 uu;
  auto loadA = [&](int ci) {
    const ushort_t* ap = wqB + (size_t)(ci*32 + mt*16 + fr) * DKk + fq*8;
#pragma unroll
    for (int ks = 0; ks < 8; ++ks) aw[ks] = *(const short8*)(ap + ks*32);
    if (isW)
      uu = *(const uint2*)(uB + (size_t)ci*8192 + (size_t)(vs*16 + fr)*32 + mt*16 + fq*4);
  };

  loadA(0);
  __syncthreads();   // ST zero-init visible

  for (int ci = 0; ci < NC; ++ci) {
    // current-chunk late-phase operands: issue now, consumed after BAR1
    short8 kf[4];
    {
      const ushort_t* kp = kB + (size_t)ci*8192 + (size_t)(wv*64 + fr)*32 + fq*8;
#pragma unroll
      for (int m = 0; m < 4; ++m) kf[m] = *(const short8*)(kp + m*512);
    }
    short8 afh, afl;
    if (!isW) {
      afh = *(const short8*)(ahB + (size_t)ci*1024 + (mt*16+fr)*32 + fq*8);
      afl = *(const short8*)(alB + (size_t)ci*1024 + (mt*16+fr)*32 + fq*8);
    }
    // phaseA
    floatx4 acc0, acc1;
    if (isW) {
      float u0,u1,u2,u3; unpack2(uu.x,u0,u1); unpack2(uu.y,u2,u3);
      acc0 = (floatx4){-u0,-u1,-u2,-u3};
      acc1 = (floatx4){0.f,0.f,0.f,0.f};
#pragma unroll
      for (int ks = 0; ks < 8; ++ks) {
        const short8 sh = *(const short8*)&STh[S16(fr, ks*32 + fq*8)];
        const short8 sl = *(const short8*)&STl[S16(fr, ks*32 + fq*8)];
        acc0 = __builtin_amdgcn_mfma_f32_16x16x32_bf16(aw[ks], sh, acc0, 0,0,0);
        acc1 = __builtin_amdgcn_mfma_f32_16x16x32_bf16(aw[ks], sl, acc1, 0,0,0);
      }
      const float v0 = -(acc0[0]+acc1[0]), v1 = -(acc0[1]+acc1[1]);
      const float v2 = -(acc0[2]+acc1[2]), v3 = -(acc0[3]+acc1[3]);
      unsigned ph0, pl0, ph1, pl1;
      split2t(v0, v1, ph0, pl0); split2t(v2, v3, ph1, pl1);
      *(uint2*)&Uh[U16(fr, mt*16 + fq*4)] = (uint2){ph0, ph1};
      *(uint2*)&Ul[U16(fr, mt*16 + fq*4)] = (uint2){pl0, pl1};
    } else {
      acc0 = (floatx4){0.f,0.f,0.f,0.f};
#pragma unroll
      for (int ks = 0; ks < 8; ++ks) {
        const short8 sh = *(const short8*)&STh[S16(fr, ks*32 + fq*8)];
        acc0 = __builtin_amdgcn_mfma_f32_16x16x32_bf16(aw[ks], sh, acc0, 0,0,0);
      }
    }
    __syncthreads();   // BAR1: uhat ready; all ST reads of this chunk done
    if (ci + 1 < NC) loadA(ci + 1);   // prefetch next phaseA operands
    const short8 uhh = *(const short8*)&Uh[U16(fr, fq*8)];
    const short8 uhl = *(const short8*)&Ul[U16(fr, fq*8)];
    if (!isW) {
      // o = q@Sh + attn@uhat; coalesced f32 stores (16 consecutive dv)
      acc0 = __builtin_amdgcn_mfma_f32_16x16x32_bf16(afh, uhh, acc0, 0,0,0);
      acc0 = __builtin_amdgcn_mfma_f32_16x16x32_bf16(afh, uhl, acc0, 0,0,0);
      acc0 = __builtin_amdgcn_mfma_f32_16x16x32_bf16(afl, uhh, acc0, 0,0,0);
      float* op = oB + (size_t)(ci*32 + mt*16 + fq*4) * DD;
#pragma unroll
      for (int r = 0; r < 4; ++r) op[(size_t)r * DD] = acc0[r];
    }
    // S += kT @ (uhat_hi + uhat_lo): wave's own 4 dk tiles
#pragma unroll
    for (int m = 0; m < 4; ++m) {
      Sacc[m] = __builtin_amdgcn_mfma_f32_16x16x32_bf16(kf[m], uhh, Sacc[m], 0,0,0);
      Sacc[m] = __builtin_amdgcn_mfma_f32_16x16x32_bf16(kf[m], uhl, Sacc[m], 0,0,0);
    }
    // mirror S slice -> shared LDS image (hi/lo) for next chunk
#pragma unroll
    for (int m = 0; m < 4; ++m) {
      unsigned ph0, pl0, ph1, pl1;
      split2t(Sacc[m][0], Sacc[m][1], ph0, pl0);
      split2t(Sacc[m][2], Sacc[m][3], ph1, pl1);
      const int dk0 = wv*64 + m*16 + fq*4;
      *(uint2*)&STh[S16(fr, dk0)] = (uint2){ph0, ph1};
      *(uint2*)&STl[S16(fr, dk0)] = (uint2){pl0, pl1};
    }
    __syncthreads();   // BAR2: ST ready; Uh readers done
  }
}

// ---- EMA pass 1: per-segment local scan ------------------------------------
__global__ __launch_bounds__(256) void ema_local_kernel(const ushort_t* __restrict__ v,
  const float* __restrict__ gs, const float* __restrict__ gl,
  ushort_t* __restrict__ es, ushort_t* __restrict__ el,
  float* __restrict__ Bs, float* __restrict__ Bl,
  float* __restrict__ As, float* __restrict__ Al,
  float* __restrict__ PfS, float* __restrict__ PfL)
{
  const int bid = blockIdx.x;
  const int seg = bid & (NSEG - 1), bh = bid >> 6;
  const int b = bh >> 2, h = bh & 3;
  const int dv = threadIdx.x;
  const int l0 = seg * SEG;
  const ushort_t* vp = v + ((size_t)bh*LL + l0) * DVv + dv;
  const float* gsp = gs + (size_t)bh*LL + l0;
  const float* glp = gl + (size_t)bh*LL + l0;
  ushort_t* esp = es + ((size_t)b*LL + l0)*DD + h*DVv + dv;
  ushort_t* elp = el + ((size_t)b*LL + l0)*DD + h*DVv + dv;
  float* pfs = PfS + (size_t)bh*LL + l0;
  float* pfl = PfL + (size_t)bh*LL + l0;
  float s1 = 0.f, s2 = 0.f, p1 = 1.f, p2 = 1.f;
  for (int j = 0; j < SEG; ++j) {
    const float vv = bf2f(vp[(size_t)j * DVv]);
    const float a = gsp[j], g2 = glp[j];
    s1 = fmaf(a,  s1, (1.f - a)  * vv);
    s2 = fmaf(g2, s2, (1.f - g2) * vv);
    p1 *= a; p2 *= g2;
    esp[(size_t)j * DD] = f2bf(s1);
    elp[(size_t)j * DD] = f2bf(s2);
    if (dv == 0) { pfs[j] = p1; pfl[j] = p2; }
  }
  const size_t o = (((size_t)bh*NSEG + seg) << 8) + dv;
  Bs[o] = s1; Bl[o] = s2;
  if (dv == 0) { As[bh*NSEG + seg] = p1; Al[bh*NSEG + seg] = p2; }
}

// ---- EMA pass 2: cross-segment carry (carry INTO each segment) -------------
__global__ __launch_bounds__(256) void ema_carry_kernel(
  const float* __restrict__ Bs, const float* __restrict__ Bl,
  const float* __restrict__ As, const float* __restrict__ Al,
  float* __restrict__ Cs, float* __restrict__ Cl)
{
  const int bh = blockIdx.x;
  const int dv = threadIdx.x;
  __shared__ float Ash[NSEG], Alh[NSEG];
  if (dv < NSEG) { Ash[dv] = As[bh*NSEG + dv]; Alh[dv] = Al[bh*NSEG + dv]; }
  __syncthreads();
  float c1 = 0.f, c2 = 0.f;
  for (int s = 0; s < NSEG; ++s) {
    const size_t o = (((size_t)bh*NSEG + s) << 8) + dv;
    Cs[o] = c1; Cl[o] = c2;
    c1 = fmaf(Ash[s], c1, Bs[o]);
    c2 = fmaf(Alh[s], c2, Bl[o]);
  }
}

// ---- combine + per-head RMSNorm; fuses EMA segment-carry correction --------
__global__ __launch_bounds__(64) void combine_kernel(const ushort_t* __restrict__ v,
  const ushort_t* __restrict__ es, const ushort_t* __restrict__ el,
  const float* __restrict__ dov, const float* __restrict__ wgt,
  const float* __restrict__ onw,
  const float* __restrict__ Cs, const float* __restrict__ Cl,
  const float* __restrict__ PfS, const float* __restrict__ PfL,
  ushort_t* __restrict__ outp)
{
  const int bid = blockIdx.x;
  const int h = bid & 3;
  const size_t bl = (size_t)(bid >> 2);
  const int lane = threadIdx.x;
  const size_t b = bl >> 12;
  const size_t l = bl & (LL - 1);
  const int bh = (int)(b * HH) + h;
  const int seg = (int)(l >> 6);
  const size_t vidx = (((b*HH + h) * (size_t)LL) + l) * DVv + lane*4;
  const size_t didx = bl * DD + h*DVv + lane*4;
  const uint2 vu = *(const uint2*)(v + vidx);
  const uint2 eu = *(const uint2*)(es + didx);
  const uint2 gu = *(const uint2*)(el + didx);
  const float4 d4 = *(const float4*)(dov + didx);
  const float pS = PfS[(size_t)bh*LL + l];
  const float pL = PfL[(size_t)bh*LL + l];
  const float4 cs4 = *(const float4*)(Cs + (((size_t)bh*NSEG + seg) << 8) + lane*4);
  const float4 cl4 = *(const float4*)(Cl + (((size_t)bh*NSEG + seg) << 8) + lane*4);
  float vf[4], ef[4], gf[4];
  unpack2(vu.x, vf[0], vf[1]); unpack2(vu.y, vf[2], vf[3]);
  unpack2(eu.x, ef[0], ef[1]); unpack2(eu.y, ef[2], ef[3]);
  unpack2(gu.x, gf[0], gf[1]); unpack2(gu.y, gf[2], gf[3]);
  ef[0] = fmaf(pS, cs4.x, ef[0]); ef[1] = fmaf(pS, cs4.y, ef[1]);
  ef[2] = fmaf(pS, cs4.z, ef[2]); ef[3] = fmaf(pS, cs4.w, ef[3]);
  gf[0] = fmaf(pL, cl4.x, gf[0]); gf[1] = fmaf(pL, cl4.y, gf[1]);
  gf[2] = fmaf(pL, cl4.z, gf[2]); gf[3] = fmaf(pL, cl4.w, gf[3]);
  const float* wp = wgt + (size_t)bid * 4;
  const float w0 = wp[0], w1 = wp[1], w2 = wp[2], w3 = wp[3];
  float o[4];
  const float df[4] = {d4.x, d4.y, d4.z, d4.w};
  float ss = 0.f;
#pragma unroll
  for (int i = 0; i < 4; ++i) {
    o[i] = w0*vf[i] + w1*ef[i] + w2*df[i] + w3*gf[i];
    ss = fmaf(o[i], o[i], ss);
  }
#pragma unroll
  for (int off = 1; off < 64; off <<= 1) ss += __shfl_xor(ss, off);
  const float sc = rsqrtf(ss * (1.f / DVv) + 1e-5f);
  const float4 nw = *(const float4*)(onw + lane*4);
  uint2 pk;
  pk.x = pack2(o[0]*sc*nw.x, o[1]*sc*nw.y);
  pk.y = pack2(o[2]*sc*nw.z, o[3]*sc*nw.w);
  *(uint2*)(outp + didx) = pk;
}

extern "C" void kernel_launch(void* const* d_in, const int* in_sizes, int n_in,
                              void* d_out, int out_size, void* d_ws, size_t ws_size,
                              hipStream_t stream)
{
  const float* x    = (const float*)d_in[0];
  const float* Wq   = (const float*)d_in[1];
  const float* Wk   = (const float*)d_in[2];
  const float* Wv   = (const float*)d_in[3];
  const float* cqw  = (const float*)d_in[4];
  const float* ckw  = (const float*)d_in[5];
  const float* cvw  = (const float*)d_in[6];
  const float* Wb   = (const float*)d_in[7];
  const float* Wds  = (const float*)d_in[8];
  const float* bds  = (const float*)d_in[9];
  const float* Wdl  = (const float*)d_in[10];
  const float* bdl  = (const float*)d_in[11];
  const float* Wtr  = (const float*)d_in[12];
  const float* btr  = (const float*)d_in[13];
  const float* Wc   = (const float*)d_in[14];
  const float* bc   = (const float*)d_in[15];
  const float* Wl   = (const float*)d_in[16];
  const float* blc  = (const float*)d_in[17];
  const float* Wg   = (const float*)d_in[18];
  const float* bg   = (const float*)d_in[19];
  const float* ltc  = (const float*)d_in[20];
  const float* ltf  = (const float*)d_in[21];
  const float* onw  = (const float*)d_in[22];
  const float* Wo   = (const float*)d_in[23];
  float* outp = (float*)d_out;

  const size_t BLD = (size_t)BB * LL * DD;
  unsigned char* w8 = (unsigned char*)d_ws;
  const size_t SL = BLD * 2;                        // 32 MB bf16 slab
  ushort_t* SA = (ushort_t*)(w8 + 0*SL);   // qraw -> kn -> kT -> opre
  ushort_t* SB = (ushort_t*)(w8 + 1*SL);   // kraw -> vv
  ushort_t* SC = (ushort_t*)(w8 + 2*SL);   // vraw -> uT
  ushort_t* SD = (ushort_t*)(w8 + 3*SL);   // xb -> qn -> el(local)
  ushort_t* SE = (ushort_t*)(w8 + 4*SL);   // w  -> es(local)
  ushort_t* zb   = (ushort_t*)(w8 + 5*SL);
  ushort_t* attn_hi = (ushort_t*)(w8 + 5*SL + BLD);
  ushort_t* attn_lo = attn_hi + (size_t)BB*HH*NC*1024;
  float*    beta = (float*)(attn_hi + 2*(size_t)BB*HH*NC*1024);
  float*    gs   = beta + (size_t)BB*HH*LL;
  float*    gl   = gs   + (size_t)BB*HH*LL;
  float*    wgt  = gl   + (size_t)BB*HH*LL;
  float*    Bs   = wgt  + (size_t)BB*LL*HH*4;
  float*    Bl   = Bs   + (size_t)BB*HH*NSEG*256;
  float*    Cs   = Bl   + (size_t)BB*HH*NSEG*256;
  float*    Cl   = Cs   + (size_t)BB*HH*NSEG*256;
  float*    As   = Cl   + (size_t)BB*HH*NSEG*256;
  float*    Al   = As   + (size_t)BB*HH*NSEG;
  float*    PfS  = Al   + (size_t)BB*HH*NSEG;
  float*    PfL  = PfS  + (size_t)BB*HH*LL;
  ushort_t* Wqb  = (ushort_t*)(PfL + (size_t)BB*HH*LL);
  ushort_t* Wkb  = Wqb + (size_t)DD*DD;
  ushort_t* Wvb  = Wkb + (size_t)DD*DD;
  ushort_t* Wob  = Wvb + (size_t)DD*DD;
  ushort_t* Wtrb = Wob + (size_t)DD*DD;
  ushort_t* xb   = SD;                     // bf16 x, consumed by the 4 x-GEMMs
  float*    dov  = outp;

  const int MBL = BB * LL;  // 16384
  dim3 blk256(256);

  {
    const int NTOT = (int)(BLD/8) + 4*(DD*DD/8) + HIDD*DD/8;
    cvt_all_kernel<<<dim3((NTOT + 255)/256), blk256, 0, stream>>>(
        x, Wq, Wk, Wv, Wo, Wtr, xb, Wqb, Wkb, Wvb, Wob, Wtrb);
  }

  gemm_bf16<0,1><<<dim3(DD/128, MBL/128), blk256, 0, stream>>>(xb, Wqb, nullptr, SA, MBL, DD, DD);
  gemm_bf16<0,1><<<dim3(DD/128, MBL/128), blk256, 0, stream>>>(xb, Wkb, nullptr, SB, MBL, DD, DD);
  gemm_bf16<0,1><<<dim3(DD/128, MBL/128), blk256, 0, stream>>>(xb, Wvb, nullptr, SC, MBL, DD, DD);
  gemm_bf16<1,1><<<dim3(HIDD/128, MBL/128), blk256, 0, stream>>>(xb, Wtrb, btr, zb, MBL, HIDD, DD);
  small_proj_kernel<<<dim3(MBL), blk256, 0, stream>>>(x, Wb, Wds, bds, Wdl, bdl, beta, gs, gl);
  conv_silu_kernel<<<dim3((unsigned)(BLD/8/256)), blk256, 0, stream>>>(SA, cqw, SD);  // qn=SD
  conv_silu_kernel<<<dim3((unsigned)(BLD/8/256)), blk256, 0, stream>>>(SB, ckw, SA);  // kn=SA
  conv_silu_kernel<<<dim3((unsigned)(BLD/8/256)), blk256, 0, stream>>>(SC, cvw, SB);  // vv=SB
  prep_kernel<<<dim3(BB*HH*NC), blk256, 0, stream>>>(SD, SA, SB, beta, SC, SE, attn_hi, attn_lo); // uT=SC w=SE kT=SA
  scan_gate_kernel<<<dim3(256 + MBL), blk256, 0, stream>>>(
      SD, SA, SC, SE, attn_hi, attn_lo, dov,
      zb, Wc, bc, Wl, blc, Wg, bg, ltc, ltf, wgt);
  ema_local_kernel<<<dim3(BB*HH*NSEG), blk256, 0, stream>>>(SB, gs, gl, SE, SD, Bs, Bl, As, Al, PfS, PfL); // es=SE el=SD
  ema_carry_kernel<<<dim3(BB*HH), blk256, 0, stream>>>(Bs, Bl, As, Al, Cs, Cl);
  combine_kernel<<<dim3(MBL*HH), dim3(64), 0, stream>>>(SB, SE, SD, dov, wgt, onw, Cs, Cl, PfS, PfL, SA); // opre=SA
  gemm_bf16<0,0><<<dim3(DD/128, MBL/128), blk256, 0, stream>>>(SA, Wob, nullptr, outp, MBL, DD, DD);
}

// Round 9
// 1033.853 us; speedup vs baseline: 1.1079x; 1.0117x over previous
//
#include <hip/hip_runtime.h>
#include <math.h>

#define BB 4
#define LL 4096
#define DD 1024
#define HH 4
#define DKk 256
#define DVv 256
#define HIDD 512
#define NC 128   // number of 32-chunks in L
#define NSEG 64  // EMA segments
#define SEG 64   // EMA segment length

typedef unsigned short ushort_t;
typedef __attribute__((ext_vector_type(8))) short short8;
typedef __attribute__((ext_vector_type(4))) float floatx4;

__device__ __forceinline__ float sigm(float x) { return 1.f / (1.f + __expf(-x)); }

__device__ __forceinline__ float bf2f(ushort_t u) {
  union { unsigned int i; float f; } c; c.i = ((unsigned int)u) << 16; return c.f;
}
__device__ __forceinline__ ushort_t f2bf(float f) {
  union { float f; unsigned int i; } c; c.f = f;
  unsigned int lsb = (c.i >> 16) & 1u;
  return (ushort_t)((c.i + 0x7fffu + lsb) >> 16);
}
__device__ __forceinline__ void unpack2(unsigned int u, float& a, float& b) {
  union { unsigned int i; float f; } c0, c1;
  c0.i = u << 16; c1.i = u & 0xffff0000u; a = c0.f; b = c1.f;
}
__device__ __forceinline__ unsigned int pack2(float a, float b) {
  return (unsigned int)f2bf(a) | ((unsigned int)f2bf(b) << 16);
}
__device__ __forceinline__ void unpack8(const uint4 v, float* o) {
  unpack2(v.x, o[0], o[1]); unpack2(v.y, o[2], o[3]);
  unpack2(v.z, o[4], o[5]); unpack2(v.w, o[6], o[7]);
}
__device__ __forceinline__ float ubits(unsigned u) {
  union { unsigned i; float f; } c; c.i = u; return c.f;
}
// exact truncate-split of two floats into packed bf16 hi and bf16 lo words
__device__ __forceinline__ void split2t(float a, float b, unsigned& hi, unsigned& lo) {
  union { float f; unsigned u; } ca, cb; ca.f = a; cb.f = b;
  const unsigned ha = ca.u & 0xffff0000u, hb = cb.u & 0xffff0000u;
  hi = (ha >> 16) | hb;
  union { float f; unsigned u; } la, lb;
  la.f = a - ubits(ha); lb.f = b - ubits(hb);
  lo = (la.u >> 16) | (lb.u & 0xffff0000u);
}
__device__ __forceinline__ void gload16(const ushort_t* g, ushort_t* l) {
  __builtin_amdgcn_global_load_lds(
      (const __attribute__((address_space(1))) void*)g,
      (__attribute__((address_space(3))) void*)l, 16, 0, 0);
}

// ---- fused f32 -> bf16 converts (x + 5 weight matrices), 8 elems/thread ----
__global__ __launch_bounds__(256) void cvt_all_kernel(
    const float* __restrict__ x,  const float* __restrict__ Wq,
    const float* __restrict__ Wk, const float* __restrict__ Wv,
    const float* __restrict__ Wo, const float* __restrict__ Wtr,
    ushort_t* __restrict__ xb,  ushort_t* __restrict__ Wqb,
    ushort_t* __restrict__ Wkb, ushort_t* __restrict__ Wvb,
    ushort_t* __restrict__ Wob, ushort_t* __restrict__ Wtrb)
{
  const int NX = (int)((size_t)BB*LL*DD/8), NW = DD*DD/8, NT = HIDD*DD/8;
  int i = blockIdx.x * 256 + threadIdx.x;
  const float* src; ushort_t* dst;
  if (i < NX) { src = x; dst = xb; }
  else {
    i -= NX;
    if (i < NW) { src = Wq; dst = Wqb; }
    else { i -= NW;
      if (i < NW) { src = Wk; dst = Wkb; }
      else { i -= NW;
        if (i < NW) { src = Wv; dst = Wvb; }
        else { i -= NW;
          if (i < NW) { src = Wo; dst = Wob; }
          else { i -= NW; if (i >= NT) return; src = Wtr; dst = Wtrb; }
        }
      }
    }
  }
  const float4 a = ((const float4*)src)[2*i];
  const float4 b = ((const float4*)src)[2*i + 1];
  uint4 p;
  p.x = pack2(a.x, a.y); p.y = pack2(a.z, a.w);
  p.z = pack2(b.x, b.y); p.w = pack2(b.z, b.w);
  ((uint4*)dst)[i] = p;
}

// ---- MFMA GEMM, bf16 A and W, global_load_lds staging ----------------------
// C(M,N) = A(M,K) @ W(N,K)^T.  ACT==1: +bias then SiLU. BF16OUT: bf16 else f32.
template<int ACT, int BF16OUT>
__global__ __launch_bounds__(256) void gemm_bf16(const ushort_t* __restrict__ A,
    const ushort_t* __restrict__ W, const float* __restrict__ bias,
    void* __restrict__ Cv, int M, int N, int K)
{
  __shared__ ushort_t As[128*32];
  __shared__ ushort_t Ws[128*32];
  const int tid = threadIdx.x;
  const int bm = blockIdx.y * 128, bn = blockIdx.x * 128;
  const int lane = tid & 63, wave = tid >> 6;
  const int wm = (wave >> 1) * 64, wn = (wave & 1) * 64;
  const int fr = lane & 15, fq = lane >> 4;
  // staging: wave w covers rows w*16..w*16+16 of each 64-row half; lane*16B linear LDS
  const int srow = wave * 16 + (lane >> 2);
  const int scol = (lane & 3) * 8;
  const ushort_t* Ap = A + (size_t)(bm + srow) * K + scol;
  const ushort_t* Wp = W + (size_t)(bn + srow) * K + scol;
  ushort_t* AsD = &As[wave * 512];
  ushort_t* WsD = &Ws[wave * 512];
  floatx4 acc[4][4];
#pragma unroll
  for (int i = 0; i < 4; ++i)
#pragma unroll
    for (int j = 0; j < 4; ++j) acc[i][j] = (floatx4){0.f, 0.f, 0.f, 0.f};

  for (int k0 = 0; k0 < K; k0 += 32) {
    __syncthreads();                       // prev tile reads done
    gload16(Ap + k0, AsD);
    gload16(Ap + (size_t)64 * K + k0, AsD + 64*32);
    gload16(Wp + k0, WsD);
    gload16(Wp + (size_t)64 * K + k0, WsD + 64*32);
    __syncthreads();                       // staging complete (vmcnt drained)
    short8 af[4], bf_[4];
#pragma unroll
    for (int mt = 0; mt < 4; ++mt)
      af[mt] = *(const short8*)&As[(wm + mt*16 + fr)*32 + fq*8];
#pragma unroll
    for (int nt = 0; nt < 4; ++nt)
      bf_[nt] = *(const short8*)&Ws[(wn + nt*16 + fr)*32 + fq*8];
#pragma unroll
    for (int mt = 0; mt < 4; ++mt)
#pragma unroll
      for (int nt = 0; nt < 4; ++nt)
        acc[mt][nt] = __builtin_amdgcn_mfma_f32_16x16x32_bf16(af[mt], bf_[nt], acc[mt][nt], 0, 0, 0);
  }
#pragma unroll
  for (int mt = 0; mt < 4; ++mt) {
#pragma unroll
    for (int reg = 0; reg < 4; ++reg) {
      const int row = bm + wm + mt*16 + fq*4 + reg;
#pragma unroll
      for (int nt = 0; nt < 4; ++nt) {
        const int col = bn + wn + nt*16 + fr;
        float v = acc[mt][nt][reg];
        if (ACT == 1) { v += bias[col]; v = v * sigm(v); }
        if (BF16OUT) ((ushort_t*)Cv)[(size_t)row * N + col] = f2bf(v);
        else         ((float*)Cv)[(size_t)row * N + col] = v;
      }
    }
  }
}

// ---- depthwise causal conv(k=4)+SiLU, vectorized 8/thread ------------------
__global__ __launch_bounds__(256) void conv_silu_kernel(const ushort_t* __restrict__ xin,
    const float* __restrict__ wc, ushort_t* __restrict__ outp)
{
  const size_t i8 = (size_t)blockIdx.x * 256 + threadIdx.x;  // over B*L*D/8
  const int d8 = (int)((i8 & 127) << 3);
  const int l  = (int)((i8 >> 7) & (LL - 1));
  const int b  = (int)(i8 >> 19);
  const ushort_t* xp = xin + i8 * 8;
  const uint4 z4 = (uint4){0u,0u,0u,0u};
  const uint4 v0 = *(const uint4*)xp;
  const uint4 v1 = (l >= 1) ? *(const uint4*)(xp - DD)   : z4;
  const uint4 v2 = (l >= 2) ? *(const uint4*)(xp - 2*DD) : z4;
  const uint4 v3 = (l >= 3) ? *(const uint4*)(xp - 3*DD) : z4;
  float x0[8], x1[8], x2[8], x3[8];
  unpack8(v0, x0); unpack8(v1, x1); unpack8(v2, x2); unpack8(v3, x3);
  unsigned pk[4];
#pragma unroll
  for (int p = 0; p < 4; ++p) {
    float o2[2];
#pragma unroll
    for (int q = 0; q < 2; ++q) {
      const int j = p*2 + q;
      const float4 w = *(const float4*)(wc + (d8 + j) * 4);
      float acc = w.w * x0[j];
      acc = fmaf(w.z, x1[j], acc);
      acc = fmaf(w.y, x2[j], acc);
      acc = fmaf(w.x, x3[j], acc);
      o2[q] = acc * sigm(acc);
    }
    pk[p] = pack2(o2[0], o2[1]);
  }
  const int h = d8 >> 8, dk = d8 & 255;
  *(uint4*)(outp + (((size_t)(b*HH + h))*LL + l)*DKk + dk) = *(uint4*)pk;
}

// ---- beta / g_s / g_l: 12 length-1024 dots per (b,l), x fp32 ---------------
__global__ __launch_bounds__(256) void small_proj_kernel(const float* __restrict__ x,
   const float* __restrict__ Wb, const float* __restrict__ Wds, const float* __restrict__ bds,
   const float* __restrict__ Wdl, const float* __restrict__ bdl,
   float* __restrict__ beta, float* __restrict__ gs, float* __restrict__ gl)
{
  const int bl = blockIdx.x;
  const int t = threadIdx.x, wave = t >> 6, lane = t & 63;
  __shared__ float res[12];
  const float* xr = x + (size_t)bl * DD + lane * 16;
  const float4 x0 = *(const float4*)(xr);
  const float4 x1 = *(const float4*)(xr + 4);
  const float4 x2 = *(const float4*)(xr + 8);
  const float4 x3 = *(const float4*)(xr + 12);
  for (int rr = 0; rr < 3; ++rr) {
    const int r = wave * 3 + rr;
    const int mat = r >> 2, h = r & 3;
    const float* Wr = (mat == 0 ? Wb : (mat == 1 ? Wds : Wdl)) + (size_t)h * DD + lane * 16;
    const float4 w0 = *(const float4*)(Wr);
    const float4 w1 = *(const float4*)(Wr + 4);
    const float4 w2 = *(const float4*)(Wr + 8);
    const float4 w3 = *(const float4*)(Wr + 12);
    float p = x0.x*w0.x + x0.y*w0.y + x0.z*w0.z + x0.w*w0.w
            + x1.x*w1.x + x1.y*w1.y + x1.z*w1.z + x1.w*w1.w
            + x2.x*w2.x + x2.y*w2.y + x2.z*w2.z + x2.w*w2.w
            + x3.x*w3.x + x3.y*w3.y + x3.z*w3.z + x3.w*w3.w;
#pragma unroll
    for (int o = 1; o < 64; o <<= 1) p += __shfl_xor(p, o);
    if (lane == 0) res[r] = p;
  }
  __syncthreads();
  if (t < 12) {
    const int mat = t >> 2, h = t & 3;
    float v = res[t];
    if (mat == 1) v += bds[h];
    if (mat == 2) v += bdl[h];
    v = sigm(v);
    const int b = bl >> 12, l = bl & (LL - 1);
    const size_t o = ((size_t)(b*HH + h))*LL + l;
    (mat == 0 ? beta : (mat == 1 ? gs : gl))[o] = v;
  }
}

// ---- hierarchical gate: z bf16, 24 length-512 dots + 2-way softmaxes -------
__global__ __launch_bounds__(256) void gate_kernel(const ushort_t* __restrict__ z,
  const float* __restrict__ Wc, const float* __restrict__ bc,
  const float* __restrict__ Wl, const float* __restrict__ bl_,
  const float* __restrict__ Wg, const float* __restrict__ bg,
  const float* __restrict__ ltc, const float* __restrict__ ltf,
  float* __restrict__ wgt)
{
  const int bl = blockIdx.x;
  const int t = threadIdx.x, wave = t >> 6, lane = t & 63;
  __shared__ float res[24];
  const uint4 zv = *(const uint4*)(z + (size_t)bl * HIDD + lane * 8);
  float zf[8]; unpack8(zv, zf);
  for (int rr = 0; rr < 6; ++rr) {
    const int r = wave * 6 + rr;
    const int mat = r >> 3, qi = r & 7;
    const float* Wr = (mat == 0 ? Wc : (mat == 1 ? Wl : Wg)) + (size_t)qi * HIDD + lane * 8;
    const float4 w0 = *(const float4*)(Wr);
    const float4 w1 = *(const float4*)(Wr + 4);
    float p = zf[0]*w0.x + zf[1]*w0.y + zf[2]*w0.z + zf[3]*w0.w
            + zf[4]*w1.x + zf[5]*w1.y + zf[6]*w1.z + zf[7]*w1.w;
#pragma unroll
    for (int o = 1; o < 64; o <<= 1) p += __shfl_xor(p, o);
    if (lane == 0) {
      const float* br = (mat == 0 ? bc : (mat == 1 ? bl_ : bg));
      res[r] = p + br[qi];
    }
  }
  __syncthreads();
  if (t < 4) {
    const float tc = logf(1.f + __expf(ltc[t])) + 1e-4f;
    const float tf = logf(1.f + __expf(ltf[t])) + 1e-4f;
    const float pg0 = sigm((res[2*t]     - res[2*t+1])     / tc);
    const float q0  = sigm((res[8+2*t]   - res[8+2*t+1])   / tf);
    const float r0  = sigm((res[16+2*t]  - res[16+2*t+1])  / tf);
    float* o = wgt + ((size_t)bl * HH + t) * 4;
    o[0] = pg0 * q0;         o[1] = pg0 * (1.f - q0);
    o[2] = (1.f - pg0) * r0; o[3] = (1.f - pg0) * (1.f - r0);
  }
}

// ---- chunk-local prep: vectorized l2norm, MFMA attn(hi/lo)+Lm, solves ------
#define QS 264
__global__ __launch_bounds__(256) void prep_kernel(ushort_t* __restrict__ q,
    ushort_t* __restrict__ k, const ushort_t* __restrict__ v,
    const float* __restrict__ beta,
    ushort_t* __restrict__ u, ushort_t* __restrict__ w,
    ushort_t* __restrict__ ah, ushort_t* __restrict__ al)
{
  __shared__ ushort_t qb[32*QS];
  __shared__ ushort_t kb[32*QS];
  __shared__ float Lm[32*32];
  __shared__ float betas[32];
  const int bid = blockIdx.x;
  const int ci = bid & (NC - 1);
  const int bh = bid >> 7;
  const int t = threadIdx.x;
  const size_t base = ((size_t)bh * LL + ci*32) * DKk;
  if (t < 32) betas[t] = beta[(size_t)bh * LL + ci*32 + t];
  for (int i4 = t; i4 < 1024; i4 += 256) {
    const int r = i4 >> 5, e = (i4 & 31) * 8;
    *(uint4*)&qb[r*QS + e] = *(const uint4*)(q + base + r*256 + e);
    *(uint4*)&kb[r*QS + e] = *(const uint4*)(k + base + r*256 + e);
  }
  __syncthreads();
  // l2norm: vectorized -- 8 uint4 reads, values kept in regs, 8 uint4 writes
  {
    const int r = t >> 3, g = t & 7;
    const int e0 = g * 32;
    float qf[32], kf[32];
#pragma unroll
    for (int j = 0; j < 4; ++j) {
      const uint4 qv = *(const uint4*)&qb[r*QS + e0 + j*8];
      const uint4 kv = *(const uint4*)&kb[r*QS + e0 + j*8];
      unpack8(qv, qf + j*8); unpack8(kv, kf + j*8);
    }
    float sq = 0.f, sk = 0.f;
#pragma unroll
    for (int j = 0; j < 32; ++j) {
      sq = fmaf(qf[j], qf[j], sq);
      sk = fmaf(kf[j], kf[j], sk);
    }
#pragma unroll
    for (int o = 1; o < 8; o <<= 1) { sq += __shfl_xor(sq, o); sk += __shfl_xor(sk, o); }
    const float rq = rsqrtf(sq + 1e-6f), rk = rsqrtf(sk + 1e-6f);
#pragma unroll
    for (int j = 0; j < 4; ++j) {
      uint4 qo, ko;
      qo.x = pack2(qf[j*8+0]*rq, qf[j*8+1]*rq);
      qo.y = pack2(qf[j*8+2]*rq, qf[j*8+3]*rq);
      qo.z = pack2(qf[j*8+4]*rq, qf[j*8+5]*rq);
      qo.w = pack2(qf[j*8+6]*rq, qf[j*8+7]*rq);
      ko.x = pack2(kf[j*8+0]*rk, kf[j*8+1]*rk);
      ko.y = pack2(kf[j*8+2]*rk, kf[j*8+3]*rk);
      ko.z = pack2(kf[j*8+4]*rk, kf[j*8+5]*rk);
      ko.w = pack2(kf[j*8+6]*rk, kf[j*8+7]*rk);
      *(uint4*)&qb[r*QS + e0 + j*8] = qo;
      *(uint4*)&kb[r*QS + e0 + j*8] = ko;
    }
  }
  __syncthreads();
  // write back normalized q (row-major, used as MFMA A-frags in scan)
  for (int i4 = t; i4 < 1024; i4 += 256) {
    const int r = i4 >> 5, e = (i4 & 31) * 8;
    *(uint4*)(q + base + r*256 + e) = *(const uint4*)&qb[r*QS + e];
  }
  // write kT (dk-major: [dk][cr]) into the k slab; thread t = dk
  {
    unsigned int pk[16];
#pragma unroll
    for (int j = 0; j < 16; ++j)
      pk[j] = (unsigned int)kb[(2*j)*QS + t] | ((unsigned int)kb[(2*j+1)*QS + t] << 16);
    uint4* kd = (uint4*)(k + base + (size_t)t*32);
#pragma unroll
    for (int j = 0; j < 4; ++j) kd[j] = ((const uint4*)pk)[j];
  }
  // attn = q@k^T (tril), Lm = beta_i * (k@k^T) (strict tril) -- via MFMA.
  {
    const int lane = t & 63, wv4 = t >> 6;
    const int fr = lane & 15, fq = lane >> 4;
    const int it = wv4 >> 1, jt = wv4 & 1;
    floatx4 dq = (floatx4){0.f,0.f,0.f,0.f};
    floatx4 dk2 = (floatx4){0.f,0.f,0.f,0.f};
#pragma unroll
    for (int ks = 0; ks < 8; ++ks) {
      const short8 bfk = *(const short8*)&kb[(jt*16+fr)*QS + ks*32 + fq*8];
      const short8 afq = *(const short8*)&qb[(it*16+fr)*QS + ks*32 + fq*8];
      const short8 afk = *(const short8*)&kb[(it*16+fr)*QS + ks*32 + fq*8];
      dq  = __builtin_amdgcn_mfma_f32_16x16x32_bf16(afq, bfk, dq, 0,0,0);
      dk2 = __builtin_amdgcn_mfma_f32_16x16x32_bf16(afk, bfk, dk2, 0,0,0);
    }
#pragma unroll
    for (int reg = 0; reg < 4; ++reg) {
      const int i = it*16 + fq*4 + reg;
      const int j = jt*16 + fr;
      const float av = (j <= i) ? dq[reg] : 0.f;
      const ushort_t hh = f2bf(av);
      const size_t aoff = ((size_t)bh*NC + ci)*1024 + (size_t)i*32 + j;
      ah[aoff] = hh;
      al[aoff] = f2bf(av - bf2f(hh));
      Lm[i*32 + j] = (j < i) ? betas[i] * dk2[reg] : 0.f;
    }
  }
  __syncthreads();
  {
    float cu[32], cw[32];
#pragma unroll
    for (int r = 0; r < 32; ++r) {
      cu[r] = bf2f(v[base + r*256 + t]) * betas[r];
      cw[r] = bf2f(kb[r*QS + t]) * betas[r];
    }
#pragma unroll
    for (int i = 1; i < 32; ++i) {
      float au = cu[i], aw = cw[i];
#pragma unroll
      for (int j = 0; j < i; ++j) {
        const float lm = Lm[i*32 + j];
        au = fmaf(-lm, cu[j], au);
        aw = fmaf(-lm, cw[j], aw);
      }
      cu[i] = au; cw[i] = aw;
    }
    // uT (dv-major: [dv][cr]); thread t = dv -> 64B contiguous
    {
      unsigned int pu[16];
#pragma unroll
      for (int j = 0; j < 16; ++j) pu[j] = pack2(cu[2*j], cu[2*j+1]);
      uint4* ud = (uint4*)(u + base + (size_t)t*32);
#pragma unroll
      for (int j = 0; j < 4; ++j) ud[j] = ((const uint4*)pu)[j];
    }
#pragma unroll
    for (int r = 0; r < 32; ++r) w[base + r*256 + t] = f2bf(cw[r]);
  }
}

// ---- MFMA sequential chunk scan: 256 blocks x 4 specialized waves ----------
// r6 structure + DEEP PREFETCH: per-chunk operand sets double-buffered
// (named ping-pong, no runtime indexing); BOTH next-chunk load sets issued at
// the top of the chunk body -> load-to-use distance ~ 1 full chunk, covering
// the ~900cy HBM first-touch latency that dominated r6's 4550 cy/chunk.
#define S16(dv,kk) (((dv)<<8) + ((kk) ^ (((dv)&7)<<3)))
#define U16(dv,cr) (((dv)<<5) + ((cr) ^ (((dv)&3)<<3)))

struct FragsK { short8 kf[4]; short8 afh, afl; };   // late-phase operands
struct FragsA { short8 aw[8]; uint2 uu; };          // phaseA operands

__global__ __launch_bounds__(256, 1) void scan_kernel(
    const ushort_t* __restrict__ qn, const ushort_t* __restrict__ kt,
    const ushort_t* __restrict__ ut, const ushort_t* __restrict__ w,
    const ushort_t* __restrict__ ah, const ushort_t* __restrict__ al,
    float* __restrict__ dout)
{
  __shared__ ushort_t STh[16*256];   // 8 KB [dv][dk] hi, swizzled
  __shared__ ushort_t STl[16*256];   // 8 KB lo
  __shared__ ushort_t Uh[16*32];     // 1 KB [dv][cr] hi, swizzled
  __shared__ ushort_t Ul[16*32];     // 1 KB lo
  const int bid = blockIdx.x;
  const int bh = bid & 15, vs = bid >> 4;  // bid%8==bh%8 -> bh pinned to XCD
  const int b = bh >> 2, h = bh & 3;
  const int t = threadIdx.x, lane = t & 63, wv = t >> 6;
  const int fr = lane & 15, fq = lane >> 4;
  const int mt = wv & 1;
  const bool isW = (wv < 2);

  for (int i = t; i < 512; i += 256) {
    ((uint4*)STh)[i] = (uint4){0u,0u,0u,0u};
    ((uint4*)STl)[i] = (uint4){0u,0u,0u,0u};
  }

  const size_t bhL = (size_t)bh * LL;
  const ushort_t* wqB = (isW ? w : qn) + bhL * DKk;  // phaseA A-operand source
  const ushort_t* kB  = kt + bhL * DKk;
  const ushort_t* uB  = ut + bhL * DVv;
  const ushort_t* ahB = ah + (size_t)bh * NC * 1024;
  const ushort_t* alB = al + (size_t)bh * NC * 1024;
  float* oB = dout + (size_t)b * LL * DD + h * DVv + vs * 16 + fr;

  floatx4 Sacc[4];   // dk slice [wv*64, wv*64+64) x dv16
#pragma unroll
  for (int i = 0; i < 4; ++i) Sacc[i] = (floatx4){0.f,0.f,0.f,0.f};

  auto loadK = [&](int ci, FragsK& f) {
    const ushort_t* kp = kB + (size_t)ci*8192 + (size_t)(wv*64 + fr)*32 + fq*8;
#pragma unroll
    for (int m = 0; m < 4; ++m) f.kf[m] = *(const short8*)(kp + m*512);
    if (!isW) {
      f.afh = *(const short8*)(ahB + (size_t)ci*1024 + (mt*16+fr)*32 + fq*8);
      f.afl = *(const short8*)(alB + (size_t)ci*1024 + (mt*16+fr)*32 + fq*8);
    }
  };
  auto loadA = [&](int ci, FragsA& f) {
    const ushort_t* ap = wqB + (size_t)(ci*32 + mt*16 + fr) * DKk + fq*8;
#pragma unroll
    for (int ks = 0; ks < 8; ++ks) f.aw[ks] = *(const short8*)(ap + ks*32);
    if (isW)
      f.uu = *(const uint2*)(uB + (size_t)ci*8192 + (size_t)(vs*16 + fr)*32 + mt*16 + fq*4);
  };

  FragsK k0, k1; FragsA a0, a1;
  loadK(0, k0);
  loadA(0, a0);
  __syncthreads();   // ST zero-init visible

  auto body = [&](int ci, FragsK& kc, FragsK& kn, FragsA& ac, FragsA& an) {
    // issue ALL next-chunk loads first: full-chunk load-to-use window
    if (ci + 1 < NC) { loadK(ci + 1, kn); loadA(ci + 1, an); }
    // phaseA (uses ac)
    floatx4 acc0, acc1;
    if (isW) {
      float u0,u1,u2,u3; unpack2(ac.uu.x,u0,u1); unpack2(ac.uu.y,u2,u3);
      acc0 = (floatx4){-u0,-u1,-u2,-u3};
      acc1 = (floatx4){0.f,0.f,0.f,0.f};
#pragma unroll
      for (int ks = 0; ks < 8; ++ks) {
        const short8 sh = *(const short8*)&STh[S16(fr, ks*32 + fq*8)];
        const short8 sl = *(const short8*)&STl[S16(fr, ks*32 + fq*8)];
        acc0 = __builtin_amdgcn_mfma_f32_16x16x32_bf16(ac.aw[ks], sh, acc0, 0,0,0);
        acc1 = __builtin_amdgcn_mfma_f32_16x16x32_bf16(ac.aw[ks], sl, acc1, 0,0,0);
      }
      const float v0 = -(acc0[0]+acc1[0]), v1 = -(acc0[1]+acc1[1]);
      const float v2 = -(acc0[2]+acc1[2]), v3 = -(acc0[3]+acc1[3]);
      unsigned ph0, pl0, ph1, pl1;
      split2t(v0, v1, ph0, pl0); split2t(v2, v3, ph1, pl1);
      *(uint2*)&Uh[U16(fr, mt*16 + fq*4)] = (uint2){ph0, ph1};
      *(uint2*)&Ul[U16(fr, mt*16 + fq*4)] = (uint2){pl0, pl1};
    } else {
      acc0 = (floatx4){0.f,0.f,0.f,0.f};
#pragma unroll
      for (int ks = 0; ks < 8; ++ks) {
        const short8 sh = *(const short8*)&STh[S16(fr, ks*32 + fq*8)];
        acc0 = __builtin_amdgcn_mfma_f32_16x16x32_bf16(ac.aw[ks], sh, acc0, 0,0,0);
      }
    }
    __syncthreads();   // BAR1: uhat ready; all ST reads of this chunk done
    const short8 uhh = *(const short8*)&Uh[U16(fr, fq*8)];
    const short8 uhl = *(const short8*)&Ul[U16(fr, fq*8)];
    if (!isW) {
      // o = q@Sh + attn@uhat; coalesced f32 stores (16 consecutive dv)
      acc0 = __builtin_amdgcn_mfma_f32_16x16x32_bf16(kc.afh, uhh, acc0, 0,0,0);
      acc0 = __builtin_amdgcn_mfma_f32_16x16x32_bf16(kc.afh, uhl, acc0, 0,0,0);
      acc0 = __builtin_amdgcn_mfma_f32_16x16x32_bf16(kc.afl, uhh, acc0, 0,0,0);
      float* op = oB + (size_t)(ci*32 + mt*16 + fq*4) * DD;
#pragma unroll
      for (int r = 0; r < 4; ++r) op[(size_t)r * DD] = acc0[r];
    }
    // S += kT @ (uhat_hi + uhat_lo): wave's own 4 dk tiles
#pragma unroll
    for (int m = 0; m < 4; ++m) {
      Sacc[m] = __builtin_amdgcn_mfma_f32_16x16x32_bf16(kc.kf[m], uhh, Sacc[m], 0,0,0);
      Sacc[m] = __builtin_amdgcn_mfma_f32_16x16x32_bf16(kc.kf[m], uhl, Sacc[m], 0,0,0);
    }
    // mirror S slice -> shared LDS image (hi/lo) for next chunk
#pragma unroll
    for (int m = 0; m < 4; ++m) {
      unsigned ph0, pl0, ph1, pl1;
      split2t(Sacc[m][0], Sacc[m][1], ph0, pl0);
      split2t(Sacc[m][2], Sacc[m][3], ph1, pl1);
      const int dk0 = wv*64 + m*16 + fq*4;
      *(uint2*)&STh[S16(fr, dk0)] = (uint2){ph0, ph1};
      *(uint2*)&STl[S16(fr, dk0)] = (uint2){pl0, pl1};
    }
    __syncthreads();   // BAR2: ST ready; Uh readers done
  };

  for (int c2 = 0; c2 < NC; c2 += 2) {
    body(c2,     k0, k1, a0, a1);
    body(c2 + 1, k1, k0, a1, a0);
  }
}

// ---- EMA pass 1: per-segment local scan ------------------------------------
__global__ __launch_bounds__(256) void ema_local_kernel(const ushort_t* __restrict__ v,
  const float* __restrict__ gs, const float* __restrict__ gl,
  ushort_t* __restrict__ es, ushort_t* __restrict__ el,
  float* __restrict__ Bs, float* __restrict__ Bl,
  float* __restrict__ As, float* __restrict__ Al,
  float* __restrict__ PfS, float* __restrict__ PfL)
{
  const int bid = blockIdx.x;
  const int seg = bid & (NSEG - 1), bh = bid >> 6;
  const int b = bh >> 2, h = bh & 3;
  const int dv = threadIdx.x;
  const int l0 = seg * SEG;
  const ushort_t* vp = v + ((size_t)bh*LL + l0) * DVv + dv;
  const float* gsp = gs + (size_t)bh*LL + l0;
  const float* glp = gl + (size_t)bh*LL + l0;
  ushort_t* esp = es + ((size_t)b*LL + l0)*DD + h*DVv + dv;
  ushort_t* elp = el + ((size_t)b*LL + l0)*DD + h*DVv + dv;
  float* pfs = PfS + (size_t)bh*LL + l0;
  float* pfl = PfL + (size_t)bh*LL + l0;
  float s1 = 0.f, s2 = 0.f, p1 = 1.f, p2 = 1.f;
  for (int j = 0; j < SEG; ++j) {
    const float vv = bf2f(vp[(size_t)j * DVv]);
    const float a = gsp[j], g2 = glp[j];
    s1 = fmaf(a,  s1, (1.f - a)  * vv);
    s2 = fmaf(g2, s2, (1.f - g2) * vv);
    p1 *= a; p2 *= g2;
    esp[(size_t)j * DD] = f2bf(s1);
    elp[(size_t)j * DD] = f2bf(s2);
    if (dv == 0) { pfs[j] = p1; pfl[j] = p2; }
  }
  const size_t o = (((size_t)bh*NSEG + seg) << 8) + dv;
  Bs[o] = s1; Bl[o] = s2;
  if (dv == 0) { As[bh*NSEG + seg] = p1; Al[bh*NSEG + seg] = p2; }
}

// ---- EMA pass 2: cross-segment carry (carry INTO each segment) -------------
__global__ __launch_bounds__(256) void ema_carry_kernel(
  const float* __restrict__ Bs, const float* __restrict__ Bl,
  const float* __restrict__ As, const float* __restrict__ Al,
  float* __restrict__ Cs, float* __restrict__ Cl)
{
  const int bh = blockIdx.x;
  const int dv = threadIdx.x;
  __shared__ float Ash[NSEG], Alh[NSEG];
  if (dv < NSEG) { Ash[dv] = As[bh*NSEG + dv]; Alh[dv] = Al[bh*NSEG + dv]; }
  __syncthreads();
  float c1 = 0.f, c2 = 0.f;
  for (int s = 0; s < NSEG; ++s) {
    const size_t o = (((size_t)bh*NSEG + s) << 8) + dv;
    Cs[o] = c1; Cl[o] = c2;
    c1 = fmaf(Ash[s], c1, Bs[o]);
    c2 = fmaf(Alh[s], c2, Bl[o]);
  }
}

// ---- combine + per-head RMSNorm; fuses EMA segment-carry correction --------
__global__ __launch_bounds__(64) void combine_kernel(const ushort_t* __restrict__ v,
  const ushort_t* __restrict__ es, const ushort_t* __restrict__ el,
  const float* __restrict__ dov, const float* __restrict__ wgt,
  const float* __restrict__ onw,
  const float* __restrict__ Cs, const float* __restrict__ Cl,
  const float* __restrict__ PfS, const float* __restrict__ PfL,
  ushort_t* __restrict__ outp)
{
  const int bid = blockIdx.x;
  const int h = bid & 3;
  const size_t bl = (size_t)(bid >> 2);
  const int lane = threadIdx.x;
  const size_t b = bl >> 12;
  const size_t l = bl & (LL - 1);
  const int bh = (int)(b * HH) + h;
  const int seg = (int)(l >> 6);
  const size_t vidx = (((b*HH + h) * (size_t)LL) + l) * DVv + lane*4;
  const size_t didx = bl * DD + h*DVv + lane*4;
  const uint2 vu = *(const uint2*)(v + vidx);
  const uint2 eu = *(const uint2*)(es + didx);
  const uint2 gu = *(const uint2*)(el + didx);
  const float4 d4 = *(const float4*)(dov + didx);
  const float pS = PfS[(size_t)bh*LL + l];
  const float pL = PfL[(size_t)bh*LL + l];
  const float4 cs4 = *(const float4*)(Cs + (((size_t)bh*NSEG + seg) << 8) + lane*4);
  const float4 cl4 = *(const float4*)(Cl + (((size_t)bh*NSEG + seg) << 8) + lane*4);
  float vf[4], ef[4], gf[4];
  unpack2(vu.x, vf[0], vf[1]); unpack2(vu.y, vf[2], vf[3]);
  unpack2(eu.x, ef[0], ef[1]); unpack2(eu.y, ef[2], ef[3]);
  unpack2(gu.x, gf[0], gf[1]); unpack2(gu.y, gf[2], gf[3]);
  ef[0] = fmaf(pS, cs4.x, ef[0]); ef[1] = fmaf(pS, cs4.y, ef[1]);
  ef[2] = fmaf(pS, cs4.z, ef[2]); ef[3] = fmaf(pS, cs4.w, ef[3]);
  gf[0] = fmaf(pL, cl4.x, gf[0]); gf[1] = fmaf(pL, cl4.y, gf[1]);
  gf[2] = fmaf(pL, cl4.z, gf[2]); gf[3] = fmaf(pL, cl4.w, gf[3]);
  const float* wp = wgt + (size_t)bid * 4;
  const float w0 = wp[0], w1 = wp[1], w2 = wp[2], w3 = wp[3];
  float o[4];
  const float df[4] = {d4.x, d4.y, d4.z, d4.w};
  float ss = 0.f;
#pragma unroll
  for (int i = 0; i < 4; ++i) {
    o[i] = w0*vf[i] + w1*ef[i] + w2*df[i] + w3*gf[i];
    ss = fmaf(o[i], o[i], ss);
  }
#pragma unroll
  for (int off = 1; off < 64; off <<= 1) ss += __shfl_xor(ss, off);
  const float sc = rsqrtf(ss * (1.f / DVv) + 1e-5f);
  const float4 nw = *(const float4*)(onw + lane*4);
  uint2 pk;
  pk.x = pack2(o[0]*sc*nw.x, o[1]*sc*nw.y);
  pk.y = pack2(o[2]*sc*nw.z, o[3]*sc*nw.w);
  *(uint2*)(outp + didx) = pk;
}

extern "C" void kernel_launch(void* const* d_in, const int* in_sizes, int n_in,
                              void* d_out, int out_size, void* d_ws, size_t ws_size,
                              hipStream_t stream)
{
  const float* x    = (const float*)d_in[0];
  const float* Wq   = (const float*)d_in[1];
  const float* Wk   = (const float*)d_in[2];
  const float* Wv   = (const float*)d_in[3];
  const float* cqw  = (const float*)d_in[4];
  const float* ckw  = (const float*)d_in[5];
  const float* cvw  = (const float*)d_in[6];
  const float* Wb   = (const float*)d_in[7];
  const float* Wds  = (const float*)d_in[8];
  const float* bds  = (const float*)d_in[9];
  const float* Wdl  = (const float*)d_in[10];
  const float* bdl  = (const float*)d_in[11];
  const float* Wtr  = (const float*)d_in[12];
  const float* btr  = (const float*)d_in[13];
  const float* Wc   = (const float*)d_in[14];
  const float* bc   = (const float*)d_in[15];
  const float* Wl   = (const float*)d_in[16];
  const float* blc  = (const float*)d_in[17];
  const float* Wg   = (const float*)d_in[18];
  const float* bg   = (const float*)d_in[19];
  const float* ltc  = (const float*)d_in[20];
  const float* ltf  = (const float*)d_in[21];
  const float* onw  = (const float*)d_in[22];
  const float* Wo   = (const float*)d_in[23];
  float* outp = (float*)d_out;

  const size_t BLD = (size_t)BB * LL * DD;
  unsigned char* w8 = (unsigned char*)d_ws;
  const size_t SL = BLD * 2;                        // 32 MB bf16 slab
  ushort_t* SA = (ushort_t*)(w8 + 0*SL);   // qraw -> kn -> kT -> opre
  ushort_t* SB = (ushort_t*)(w8 + 1*SL);   // kraw -> vv
  ushort_t* SC = (ushort_t*)(w8 + 2*SL);   // vraw -> uT
  ushort_t* SD = (ushort_t*)(w8 + 3*SL);   // xb -> qn -> el(local)
  ushort_t* SE = (ushort_t*)(w8 + 4*SL);   // w  -> es(local)
  ushort_t* zb   = (ushort_t*)(w8 + 5*SL);
  ushort_t* attn_hi = (ushort_t*)(w8 + 5*SL + BLD);
  ushort_t* attn_lo = attn_hi + (size_t)BB*HH*NC*1024;
  float*    beta = (float*)(attn_hi + 2*(size_t)BB*HH*NC*1024);
  float*    gs   = beta + (size_t)BB*HH*LL;
  float*    gl   = gs   + (size_t)BB*HH*LL;
  float*    wgt  = gl   + (size_t)BB*HH*LL;
  float*    Bs   = wgt  + (size_t)BB*LL*HH*4;
  float*    Bl   = Bs   + (size_t)BB*HH*NSEG*256;
  float*    Cs   = Bl   + (size_t)BB*HH*NSEG*256;
  float*    Cl   = Cs   + (size_t)BB*HH*NSEG*256;
  float*    As   = Cl   + (size_t)BB*HH*NSEG*256;
  float*    Al   = As   + (size_t)BB*HH*NSEG;
  float*    PfS  = Al   + (size_t)BB*HH*NSEG;
  float*    PfL  = PfS  + (size_t)BB*HH*LL;
  ushort_t* Wqb  = (ushort_t*)(PfL + (size_t)BB*HH*LL);
  ushort_t* Wkb  = Wqb + (size_t)DD*DD;
  ushort_t* Wvb  = Wkb + (size_t)DD*DD;
  ushort_t* Wob  = Wvb + (size_t)DD*DD;
  ushort_t* Wtrb = Wob + (size_t)DD*DD;
  ushort_t* xb   = SD;                     // bf16 x, consumed by the 4 x-GEMMs
  float*    dov  = outp;

  const int MBL = BB * LL;  // 16384
  dim3 blk256(256);

  {
    const int NTOT = (int)(BLD/8) + 4*(DD*DD/8) + HIDD*DD/8;
    cvt_all_kernel<<<dim3((NTOT + 255)/256), blk256, 0, stream>>>(
        x, Wq, Wk, Wv, Wo, Wtr, xb, Wqb, Wkb, Wvb, Wob, Wtrb);
  }

  gemm_bf16<0,1><<<dim3(DD/128, MBL/128), blk256, 0, stream>>>(xb, Wqb, nullptr, SA, MBL, DD, DD);
  gemm_bf16<0,1><<<dim3(DD/128, MBL/128), blk256, 0, stream>>>(xb, Wkb, nullptr, SB, MBL, DD, DD);
  gemm_bf16<0,1><<<dim3(DD/128, MBL/128), blk256, 0, stream>>>(xb, Wvb, nullptr, SC, MBL, DD, DD);
  gemm_bf16<1,1><<<dim3(HIDD/128, MBL/128), blk256, 0, stream>>>(xb, Wtrb, btr, zb, MBL, HIDD, DD);
  small_proj_kernel<<<dim3(MBL), blk256, 0, stream>>>(x, Wb, Wds, bds, Wdl, bdl, beta, gs, gl);
  gate_kernel<<<dim3(MBL), blk256, 0, stream>>>(zb, Wc, bc, Wl, blc, Wg, bg, ltc, ltf, wgt);
  conv_silu_kernel<<<dim3((unsigned)(BLD/8/256)), blk256, 0, stream>>>(SA, cqw, SD);  // qn=SD
  conv_silu_kernel<<<dim3((unsigned)(BLD/8/256)), blk256, 0, stream>>>(SB, ckw, SA);  // kn=SA
  conv_silu_kernel<<<dim3((unsigned)(BLD/8/256)), blk256, 0, stream>>>(SC, cvw, SB);  // vv=SB
  prep_kernel<<<dim3(BB*HH*NC), blk256, 0, stream>>>(SD, SA, SB, beta, SC, SE, attn_hi, attn_lo); // uT=SC w=SE kT=SA
  scan_kernel<<<dim3(256), blk256, 0, stream>>>(SD, SA, SC, SE, attn_hi, attn_lo, dov);
  ema_local_kernel<<<dim3(BB*HH*NSEG), blk256, 0, stream>>>(SB, gs, gl, SE, SD, Bs, Bl, As, Al, PfS, PfL); // es=SE el=SD
  ema_carry_kernel<<<dim3(BB*HH), blk256, 0, stream>>>(Bs, Bl, As, Al, Cs, Cl);
  combine_kernel<<<dim3(MBL*HH), dim3(64), 0, stream>>>(SB, SE, SD, dov, wgt, onw, Cs, Cl, PfS, PfL, SA); // opre=SA
  gemm_bf16<0,0><<<dim3(DD/128, MBL/128), blk256, 0, stream>>>(SA, Wob, nullptr, outp, MBL, DD, DD);
}

// Round 10
// 1016.253 us; speedup vs baseline: 1.1271x; 1.0173x over previous
//
#include <hip/hip_runtime.h>
#include <math.h>

#define BB 4
#define LL 4096
#define DD 1024
#define HH 4
#define DKk 256
#define DVv 256
#define HIDD 512
#define NC 128   // number of 32-chunks in L
#define NSEG 64  // EMA segments
#define SEG 64   // EMA segment length

typedef unsigned short ushort_t;
typedef __attribute__((ext_vector_type(8))) short short8;
typedef __attribute__((ext_vector_type(4))) float floatx4;

__device__ __forceinline__ float sigm(float x) { return 1.f / (1.f + __expf(-x)); }

__device__ __forceinline__ float bf2f(ushort_t u) {
  union { unsigned int i; float f; } c; c.i = ((unsigned int)u) << 16; return c.f;
}
__device__ __forceinline__ ushort_t f2bf(float f) {
  union { float f; unsigned int i; } c; c.f = f;
  unsigned int lsb = (c.i >> 16) & 1u;
  return (ushort_t)((c.i + 0x7fffu + lsb) >> 16);
}
__device__ __forceinline__ void unpack2(unsigned int u, float& a, float& b) {
  union { unsigned int i; float f; } c0, c1;
  c0.i = u << 16; c1.i = u & 0xffff0000u; a = c0.f; b = c1.f;
}
__device__ __forceinline__ unsigned int pack2(float a, float b) {
  return (unsigned int)f2bf(a) | ((unsigned int)f2bf(b) << 16);
}
__device__ __forceinline__ void unpack8(const uint4 v, float* o) {
  unpack2(v.x, o[0], o[1]); unpack2(v.y, o[2], o[3]);
  unpack2(v.z, o[4], o[5]); unpack2(v.w, o[6], o[7]);
}
__device__ __forceinline__ float ubits(unsigned u) {
  union { unsigned i; float f; } c; c.i = u; return c.f;
}
// exact truncate-split of two floats into packed bf16 hi and bf16 lo words
__device__ __forceinline__ void split2t(float a, float b, unsigned& hi, unsigned& lo) {
  union { float f; unsigned u; } ca, cb; ca.f = a; cb.f = b;
  const unsigned ha = ca.u & 0xffff0000u, hb = cb.u & 0xffff0000u;
  hi = (ha >> 16) | hb;
  union { float f; unsigned u; } la, lb;
  la.f = a - ubits(ha); lb.f = b - ubits(hb);
  lo = (la.u >> 16) | (lb.u & 0xffff0000u);
}
__device__ __forceinline__ void gload16(const ushort_t* g, ushort_t* l) {
  __builtin_amdgcn_global_load_lds(
      (const __attribute__((address_space(1))) void*)g,
      (__attribute__((address_space(3))) void*)l, 16, 0, 0);
}

// ---- fused f32 -> bf16 converts (x + 5 weight matrices), 8 elems/thread ----
// order: x, Wq, Wk, Wv, Wtr, Wo  (qkv+trunk contiguous for the fused GEMM)
__global__ __launch_bounds__(256) void cvt_all_kernel(
    const float* __restrict__ x,  const float* __restrict__ Wq,
    const float* __restrict__ Wk, const float* __restrict__ Wv,
    const float* __restrict__ Wtr, const float* __restrict__ Wo,
    ushort_t* __restrict__ xb,  ushort_t* __restrict__ Wqb,
    ushort_t* __restrict__ Wkb, ushort_t* __restrict__ Wvb,
    ushort_t* __restrict__ Wtrb, ushort_t* __restrict__ Wob)
{
  const int NX = (int)((size_t)BB*LL*DD/8), NW = DD*DD/8, NT = HIDD*DD/8;
  int i = blockIdx.x * 256 + threadIdx.x;
  const float* src; ushort_t* dst;
  if (i < NX) { src = x; dst = xb; }
  else {
    i -= NX;
    if (i < NW) { src = Wq; dst = Wqb; }
    else { i -= NW;
      if (i < NW) { src = Wk; dst = Wkb; }
      else { i -= NW;
        if (i < NW) { src = Wv; dst = Wvb; }
        else { i -= NW;
          if (i < NT) { src = Wtr; dst = Wtrb; }
          else { i -= NT; if (i >= NW) return; src = Wo; dst = Wob; }
        }
      }
    }
  }
  const float4 a = ((const float4*)src)[2*i];
  const float4 b = ((const float4*)src)[2*i + 1];
  uint4 p;
  p.x = pack2(a.x, a.y); p.y = pack2(a.z, a.w);
  p.z = pack2(b.x, b.y); p.w = pack2(b.z, b.w);
  ((uint4*)dst)[i] = p;
}

// ---- MFMA GEMM, bf16 A and W, global_load_lds staging ----------------------
// C(M,N) = A(M,K) @ W(N,K)^T.  ACT==1: +bias then SiLU. BF16OUT: bf16 else f32.
template<int ACT, int BF16OUT>
__global__ __launch_bounds__(256) void gemm_bf16(const ushort_t* __restrict__ A,
    const ushort_t* __restrict__ W, const float* __restrict__ bias,
    void* __restrict__ Cv, int M, int N, int K)
{
  __shared__ ushort_t As[128*32];
  __shared__ ushort_t Ws[128*32];
  const int tid = threadIdx.x;
  const int bm = blockIdx.y * 128, bn = blockIdx.x * 128;
  const int lane = tid & 63, wave = tid >> 6;
  const int wm = (wave >> 1) * 64, wn = (wave & 1) * 64;
  const int fr = lane & 15, fq = lane >> 4;
  const int srow = wave * 16 + (lane >> 2);
  const int scol = (lane & 3) * 8;
  const ushort_t* Ap = A + (size_t)(bm + srow) * K + scol;
  const ushort_t* Wp = W + (size_t)(bn + srow) * K + scol;
  ushort_t* AsD = &As[wave * 512];
  ushort_t* WsD = &Ws[wave * 512];
  floatx4 acc[4][4];
#pragma unroll
  for (int i = 0; i < 4; ++i)
#pragma unroll
    for (int j = 0; j < 4; ++j) acc[i][j] = (floatx4){0.f, 0.f, 0.f, 0.f};

  for (int k0 = 0; k0 < K; k0 += 32) {
    __syncthreads();                       // prev tile reads done
    gload16(Ap + k0, AsD);
    gload16(Ap + (size_t)64 * K + k0, AsD + 64*32);
    gload16(Wp + k0, WsD);
    gload16(Wp + (size_t)64 * K + k0, WsD + 64*32);
    __syncthreads();                       // staging complete (vmcnt drained)
    short8 af[4], bf_[4];
#pragma unroll
    for (int mt = 0; mt < 4; ++mt)
      af[mt] = *(const short8*)&As[(wm + mt*16 + fr)*32 + fq*8];
#pragma unroll
    for (int nt = 0; nt < 4; ++nt)
      bf_[nt] = *(const short8*)&Ws[(wn + nt*16 + fr)*32 + fq*8];
#pragma unroll
    for (int mt = 0; mt < 4; ++mt)
#pragma unroll
      for (int nt = 0; nt < 4; ++nt)
        acc[mt][nt] = __builtin_amdgcn_mfma_f32_16x16x32_bf16(af[mt], bf_[nt], acc[mt][nt], 0, 0, 0);
  }
#pragma unroll
  for (int mt = 0; mt < 4; ++mt) {
#pragma unroll
    for (int reg = 0; reg < 4; ++reg) {
      const int row = bm + wm + mt*16 + fq*4 + reg;
#pragma unroll
      for (int nt = 0; nt < 4; ++nt) {
        const int col = bn + wn + nt*16 + fr;
        float v = acc[mt][nt][reg];
        if (ACT == 1) { v += bias[col]; v = v * sigm(v); }
        if (BF16OUT) ((ushort_t*)Cv)[(size_t)row * N + col] = f2bf(v);
        else         ((float*)Cv)[(size_t)row * N + col] = v;
      }
    }
  }
}

// ---- fused q/k/v/trunk GEMM: Wcat = [Wq;Wk;Wv;Wtr] rows (3584 x 1024) ------
// cols [0,3072) -> Cq/Ck/Cv (N=1024 each, bf16); cols [3072,3584) -> trunk
// with bias+SiLU into Cz (N=512, bf16). bn is 128-aligned so dispatch is
// block-uniform.
__global__ __launch_bounds__(256) void gemm_qkvt(const ushort_t* __restrict__ A,
    const ushort_t* __restrict__ Wcat, const float* __restrict__ btr,
    ushort_t* __restrict__ Cq, ushort_t* __restrict__ Ck,
    ushort_t* __restrict__ Cvv, ushort_t* __restrict__ Cz, int M, int K)
{
  __shared__ ushort_t As[128*32];
  __shared__ ushort_t Ws[128*32];
  const int tid = threadIdx.x;
  const int bm = blockIdx.y * 128, bn = blockIdx.x * 128;
  const int lane = tid & 63, wave = tid >> 6;
  const int wm = (wave >> 1) * 64, wn = (wave & 1) * 64;
  const int fr = lane & 15, fq = lane >> 4;
  const int srow = wave * 16 + (lane >> 2);
  const int scol = (lane & 3) * 8;
  const ushort_t* Ap = A + (size_t)(bm + srow) * K + scol;
  const ushort_t* Wp = Wcat + (size_t)(bn + srow) * K + scol;
  ushort_t* AsD = &As[wave * 512];
  ushort_t* WsD = &Ws[wave * 512];
  floatx4 acc[4][4];
#pragma unroll
  for (int i = 0; i < 4; ++i)
#pragma unroll
    for (int j = 0; j < 4; ++j) acc[i][j] = (floatx4){0.f, 0.f, 0.f, 0.f};

  for (int k0 = 0; k0 < K; k0 += 32) {
    __syncthreads();
    gload16(Ap + k0, AsD);
    gload16(Ap + (size_t)64 * K + k0, AsD + 64*32);
    gload16(Wp + k0, WsD);
    gload16(Wp + (size_t)64 * K + k0, WsD + 64*32);
    __syncthreads();
    short8 af[4], bf_[4];
#pragma unroll
    for (int mt = 0; mt < 4; ++mt)
      af[mt] = *(const short8*)&As[(wm + mt*16 + fr)*32 + fq*8];
#pragma unroll
    for (int nt = 0; nt < 4; ++nt)
      bf_[nt] = *(const short8*)&Ws[(wn + nt*16 + fr)*32 + fq*8];
#pragma unroll
    for (int mt = 0; mt < 4; ++mt)
#pragma unroll
      for (int nt = 0; nt < 4; ++nt)
        acc[mt][nt] = __builtin_amdgcn_mfma_f32_16x16x32_bf16(af[mt], bf_[nt], acc[mt][nt], 0, 0, 0);
  }
  const bool trunk = (bn >= 3072);
  ushort_t* dst;
  int nloc, cbase;
  if (!trunk) {
    const int mat = bn >> 10;
    dst = (mat == 0 ? Cq : (mat == 1 ? Ck : Cvv));
    nloc = 1024; cbase = bn & 1023;
  } else {
    dst = Cz; nloc = 512; cbase = bn - 3072;
  }
#pragma unroll
  for (int mt = 0; mt < 4; ++mt) {
#pragma unroll
    for (int reg = 0; reg < 4; ++reg) {
      const int row = bm + wm + mt*16 + fq*4 + reg;
#pragma unroll
      for (int nt = 0; nt < 4; ++nt) {
        const int col = cbase + wn + nt*16 + fr;
        float v = acc[mt][nt][reg];
        if (trunk) { v += btr[col]; v = v * sigm(v); }
        dst[(size_t)row * nloc + col] = f2bf(v);
      }
    }
  }
}

// ---- depthwise causal conv(k=4)+SiLU, vectorized 8/thread ------------------
__global__ __launch_bounds__(256) void conv_silu_kernel(const ushort_t* __restrict__ xin,
    const float* __restrict__ wc, ushort_t* __restrict__ outp)
{
  const size_t i8 = (size_t)blockIdx.x * 256 + threadIdx.x;  // over B*L*D/8
  const int d8 = (int)((i8 & 127) << 3);
  const int l  = (int)((i8 >> 7) & (LL - 1));
  const int b  = (int)(i8 >> 19);
  const ushort_t* xp = xin + i8 * 8;
  const uint4 z4 = (uint4){0u,0u,0u,0u};
  const uint4 v0 = *(const uint4*)xp;
  const uint4 v1 = (l >= 1) ? *(const uint4*)(xp - DD)   : z4;
  const uint4 v2 = (l >= 2) ? *(const uint4*)(xp - 2*DD) : z4;
  const uint4 v3 = (l >= 3) ? *(const uint4*)(xp - 3*DD) : z4;
  float x0[8], x1[8], x2[8], x3[8];
  unpack8(v0, x0); unpack8(v1, x1); unpack8(v2, x2); unpack8(v3, x3);
  unsigned pk[4];
#pragma unroll
  for (int p = 0; p < 4; ++p) {
    float o2[2];
#pragma unroll
    for (int q = 0; q < 2; ++q) {
      const int j = p*2 + q;
      const float4 w = *(const float4*)(wc + (d8 + j) * 4);
      float acc = w.w * x0[j];
      acc = fmaf(w.z, x1[j], acc);
      acc = fmaf(w.y, x2[j], acc);
      acc = fmaf(w.x, x3[j], acc);
      o2[q] = acc * sigm(acc);
    }
    pk[p] = pack2(o2[0], o2[1]);
  }
  const int h = d8 >> 8, dk = d8 & 255;
  *(uint4*)(outp + (((size_t)(b*HH + h))*LL + l)*DKk + dk) = *(uint4*)pk;
}

// ---- beta / g_s / g_l: 12 length-1024 dots per (b,l), x fp32 ---------------
__global__ __launch_bounds__(256) void small_proj_kernel(const float* __restrict__ x,
   const float* __restrict__ Wb, const float* __restrict__ Wds, const float* __restrict__ bds,
   const float* __restrict__ Wdl, const float* __restrict__ bdl,
   float* __restrict__ beta, float* __restrict__ gs, float* __restrict__ gl)
{
  const int bl = blockIdx.x;
  const int t = threadIdx.x, wave = t >> 6, lane = t & 63;
  __shared__ float res[12];
  const float* xr = x + (size_t)bl * DD + lane * 16;
  const float4 x0 = *(const float4*)(xr);
  const float4 x1 = *(const float4*)(xr + 4);
  const float4 x2 = *(const float4*)(xr + 8);
  const float4 x3 = *(const float4*)(xr + 12);
  for (int rr = 0; rr < 3; ++rr) {
    const int r = wave * 3 + rr;
    const int mat = r >> 2, h = r & 3;
    const float* Wr = (mat == 0 ? Wb : (mat == 1 ? Wds : Wdl)) + (size_t)h * DD + lane * 16;
    const float4 w0 = *(const float4*)(Wr);
    const float4 w1 = *(const float4*)(Wr + 4);
    const float4 w2 = *(const float4*)(Wr + 8);
    const float4 w3 = *(const float4*)(Wr + 12);
    float p = x0.x*w0.x + x0.y*w0.y + x0.z*w0.z + x0.w*w0.w
            + x1.x*w1.x + x1.y*w1.y + x1.z*w1.z + x1.w*w1.w
            + x2.x*w2.x + x2.y*w2.y + x2.z*w2.z + x2.w*w2.w
            + x3.x*w3.x + x3.y*w3.y + x3.z*w3.z + x3.w*w3.w;
#pragma unroll
    for (int o = 1; o < 64; o <<= 1) p += __shfl_xor(p, o);
    if (lane == 0) res[r] = p;
  }
  __syncthreads();
  if (t < 12) {
    const int mat = t >> 2, h = t & 3;
    float v = res[t];
    if (mat == 1) v += bds[h];
    if (mat == 2) v += bdl[h];
    v = sigm(v);
    const int b = bl >> 12, l = bl & (LL - 1);
    const size_t o = ((size_t)(b*HH + h))*LL + l;
    (mat == 0 ? beta : (mat == 1 ? gs : gl))[o] = v;
  }
}

// ---- hierarchical gate: z bf16, 24 length-512 dots + 2-way softmaxes -------
__global__ __launch_bounds__(256) void gate_kernel(const ushort_t* __restrict__ z,
  const float* __restrict__ Wc, const float* __restrict__ bc,
  const float* __restrict__ Wl, const float* __restrict__ bl_,
  const float* __restrict__ Wg, const float* __restrict__ bg,
  const float* __restrict__ ltc, const float* __restrict__ ltf,
  float* __restrict__ wgt)
{
  const int bl = blockIdx.x;
  const int t = threadIdx.x, wave = t >> 6, lane = t & 63;
  __shared__ float res[24];
  const uint4 zv = *(const uint4*)(z + (size_t)bl * HIDD + lane * 8);
  float zf[8]; unpack8(zv, zf);
  for (int rr = 0; rr < 6; ++rr) {
    const int r = wave * 6 + rr;
    const int mat = r >> 3, qi = r & 7;
    const float* Wr = (mat == 0 ? Wc : (mat == 1 ? Wl : Wg)) + (size_t)qi * HIDD + lane * 8;
    const float4 w0 = *(const float4*)(Wr);
    const float4 w1 = *(const float4*)(Wr + 4);
    float p = zf[0]*w0.x + zf[1]*w0.y + zf[2]*w0.z + zf[3]*w0.w
            + zf[4]*w1.x + zf[5]*w1.y + zf[6]*w1.z + zf[7]*w1.w;
#pragma unroll
    for (int o = 1; o < 64; o <<= 1) p += __shfl_xor(p, o);
    if (lane == 0) {
      const float* br = (mat == 0 ? bc : (mat == 1 ? bl_ : bg));
      res[r] = p + br[qi];
    }
  }
  __syncthreads();
  if (t < 4) {
    const float tc = logf(1.f + __expf(ltc[t])) + 1e-4f;
    const float tf = logf(1.f + __expf(ltf[t])) + 1e-4f;
    const float pg0 = sigm((res[2*t]     - res[2*t+1])     / tc);
    const float q0  = sigm((res[8+2*t]   - res[8+2*t+1])   / tf);
    const float r0  = sigm((res[16+2*t]  - res[16+2*t+1])  / tf);
    float* o = wgt + ((size_t)bl * HH + t) * 4;
    o[0] = pg0 * q0;         o[1] = pg0 * (1.f - q0);
    o[2] = (1.f - pg0) * r0; o[3] = (1.f - pg0) * (1.f - r0);
  }
}

// ---- chunk-local prep: vectorized l2norm, MFMA attn(hi/lo)+Lm, solves ------
#define QS 264
__global__ __launch_bounds__(256) void prep_kernel(ushort_t* __restrict__ q,
    ushort_t* __restrict__ k, const ushort_t* __restrict__ v,
    const float* __restrict__ beta,
    ushort_t* __restrict__ u, ushort_t* __restrict__ w,
    ushort_t* __restrict__ ah, ushort_t* __restrict__ al)
{
  __shared__ ushort_t qb[32*QS];
  __shared__ ushort_t kb[32*QS];
  __shared__ float Lm[32*32];
  __shared__ float betas[32];
  const int bid = blockIdx.x;
  const int ci = bid & (NC - 1);
  const int bh = bid >> 7;
  const int t = threadIdx.x;
  const size_t base = ((size_t)bh * LL + ci*32) * DKk;
  if (t < 32) betas[t] = beta[(size_t)bh * LL + ci*32 + t];
  for (int i4 = t; i4 < 1024; i4 += 256) {
    const int r = i4 >> 5, e = (i4 & 31) * 8;
    *(uint4*)&qb[r*QS + e] = *(const uint4*)(q + base + r*256 + e);
    *(uint4*)&kb[r*QS + e] = *(const uint4*)(k + base + r*256 + e);
  }
  __syncthreads();
  // l2norm: vectorized -- 8 uint4 reads, values kept in regs, 8 uint4 writes
  {
    const int r = t >> 3, g = t & 7;
    const int e0 = g * 32;
    float qf[32], kf[32];
#pragma unroll
    for (int j = 0; j < 4; ++j) {
      const uint4 qv = *(const uint4*)&qb[r*QS + e0 + j*8];
      const uint4 kv = *(const uint4*)&kb[r*QS + e0 + j*8];
      unpack8(qv, qf + j*8); unpack8(kv, kf + j*8);
    }
    float sq = 0.f, sk = 0.f;
#pragma unroll
    for (int j = 0; j < 32; ++j) {
      sq = fmaf(qf[j], qf[j], sq);
      sk = fmaf(kf[j], kf[j], sk);
    }
#pragma unroll
    for (int o = 1; o < 8; o <<= 1) { sq += __shfl_xor(sq, o); sk += __shfl_xor(sk, o); }
    const float rq = rsqrtf(sq + 1e-6f), rk = rsqrtf(sk + 1e-6f);
#pragma unroll
    for (int j = 0; j < 4; ++j) {
      uint4 qo, ko;
      qo.x = pack2(qf[j*8+0]*rq, qf[j*8+1]*rq);
      qo.y = pack2(qf[j*8+2]*rq, qf[j*8+3]*rq);
      qo.z = pack2(qf[j*8+4]*rq, qf[j*8+5]*rq);
      qo.w = pack2(qf[j*8+6]*rq, qf[j*8+7]*rq);
      ko.x = pack2(kf[j*8+0]*rk, kf[j*8+1]*rk);
      ko.y = pack2(kf[j*8+2]*rk, kf[j*8+3]*rk);
      ko.z = pack2(kf[j*8+4]*rk, kf[j*8+5]*rk);
      ko.w = pack2(kf[j*8+6]*rk, kf[j*8+7]*rk);
      *(uint4*)&qb[r*QS + e0 + j*8] = qo;
      *(uint4*)&kb[r*QS + e0 + j*8] = ko;
    }
  }
  __syncthreads();
  // write back normalized q (row-major, used as MFMA A-frags in scan)
  for (int i4 = t; i4 < 1024; i4 += 256) {
    const int r = i4 >> 5, e = (i4 & 31) * 8;
    *(uint4*)(q + base + r*256 + e) = *(const uint4*)&qb[r*QS + e];
  }
  // write kT (dk-major: [dk][cr]) into the k slab; thread t = dk
  {
    unsigned int pk[16];
#pragma unroll
    for (int j = 0; j < 16; ++j)
      pk[j] = (unsigned int)kb[(2*j)*QS + t] | ((unsigned int)kb[(2*j+1)*QS + t] << 16);
    uint4* kd = (uint4*)(k + base + (size_t)t*32);
#pragma unroll
    for (int j = 0; j < 4; ++j) kd[j] = ((const uint4*)pk)[j];
  }
  // attn = q@k^T (tril), Lm = beta_i * (k@k^T) (strict tril) -- via MFMA.
  {
    const int lane = t & 63, wv4 = t >> 6;
    const int fr = lane & 15, fq = lane >> 4;
    const int it = wv4 >> 1, jt = wv4 & 1;
    floatx4 dq = (floatx4){0.f,0.f,0.f,0.f};
    floatx4 dk2 = (floatx4){0.f,0.f,0.f,0.f};
#pragma unroll
    for (int ks = 0; ks < 8; ++ks) {
      const short8 bfk = *(const short8*)&kb[(jt*16+fr)*QS + ks*32 + fq*8];
      const short8 afq = *(const short8*)&qb[(it*16+fr)*QS + ks*32 + fq*8];
      const short8 afk = *(const short8*)&kb[(it*16+fr)*QS + ks*32 + fq*8];
      dq  = __builtin_amdgcn_mfma_f32_16x16x32_bf16(afq, bfk, dq, 0,0,0);
      dk2 = __builtin_amdgcn_mfma_f32_16x16x32_bf16(afk, bfk, dk2, 0,0,0);
    }
#pragma unroll
    for (int reg = 0; reg < 4; ++reg) {
      const int i = it*16 + fq*4 + reg;
      const int j = jt*16 + fr;
      const float av = (j <= i) ? dq[reg] : 0.f;
      const ushort_t hh = f2bf(av);
      const size_t aoff = ((size_t)bh*NC + ci)*1024 + (size_t)i*32 + j;
      ah[aoff] = hh;
      al[aoff] = f2bf(av - bf2f(hh));
      Lm[i*32 + j] = (j < i) ? betas[i] * dk2[reg] : 0.f;
    }
  }
  __syncthreads();
  {
    float cu[32], cw[32];
#pragma unroll
    for (int r = 0; r < 32; ++r) {
      cu[r] = bf2f(v[base + r*256 + t]) * betas[r];
      cw[r] = bf2f(kb[r*QS + t]) * betas[r];
    }
    // forward substitution with float4 Lm row reads (same values/order)
#pragma unroll
    for (int i = 1; i < 32; ++i) {
      float au = cu[i], aw = cw[i];
#pragma unroll
      for (int jb = 0; jb < (i + 3) / 4; ++jb) {
        const float4 lr = *(const float4*)&Lm[i*32 + jb*4];
        const float lmv[4] = {lr.x, lr.y, lr.z, lr.w};
#pragma unroll
        for (int qv = 0; qv < 4; ++qv) {
          const int j = jb*4 + qv;
          if (j < i) {
            au = fmaf(-lmv[qv], cu[j], au);
            aw = fmaf(-lmv[qv], cw[j], aw);
          }
        }
      }
      cu[i] = au; cw[i] = aw;
    }
    // uT (dv-major: [dv][cr]); thread t = dv -> 64B contiguous
    {
      unsigned int pu[16];
#pragma unroll
      for (int j = 0; j < 16; ++j) pu[j] = pack2(cu[2*j], cu[2*j+1]);
      uint4* ud = (uint4*)(u + base + (size_t)t*32);
#pragma unroll
      for (int j = 0; j < 4; ++j) ud[j] = ((const uint4*)pu)[j];
    }
#pragma unroll
    for (int r = 0; r < 32; ++r) w[base + r*256 + t] = f2bf(cw[r]);
  }
}

// ---- MFMA sequential chunk scan: 256 blocks x 4 specialized waves ----------
// r9 structure (deep ping-pong prefetch, named buffers, 2 barriers/chunk).
#define S16(dv,kk) (((dv)<<8) + ((kk) ^ (((dv)&7)<<3)))
#define U16(dv,cr) (((dv)<<5) + ((cr) ^ (((dv)&3)<<3)))

struct FragsK { short8 kf[4]; short8 afh, afl; };   // late-phase operands
struct FragsA { short8 aw[8]; uint2 uu; };          // phaseA operands

__global__ __launch_bounds__(256, 1) void scan_kernel(
    const ushort_t* __restrict__ qn, const ushort_t* __restrict__ kt,
    const ushort_t* __restrict__ ut, const ushort_t* __restrict__ w,
    const ushort_t* __restrict__ ah, const ushort_t* __restrict__ al,
    float* __restrict__ dout)
{
  __shared__ ushort_t STh[16*256];   // 8 KB [dv][dk] hi, swizzled
  __shared__ ushort_t STl[16*256];   // 8 KB lo
  __shared__ ushort_t Uh[16*32];     // 1 KB [dv][cr] hi, swizzled
  __shared__ ushort_t Ul[16*32];     // 1 KB lo
  const int bid = blockIdx.x;
  const int bh = bid & 15, vs = bid >> 4;  // bid%8==bh%8 -> bh pinned to XCD
  const int b = bh >> 2, h = bh & 3;
  const int t = threadIdx.x, lane = t & 63, wv = t >> 6;
  const int fr = lane & 15, fq = lane >> 4;
  const int mt = wv & 1;
  const bool isW = (wv < 2);

  for (int i = t; i < 512; i += 256) {
    ((uint4*)STh)[i] = (uint4){0u,0u,0u,0u};
    ((uint4*)STl)[i] = (uint4){0u,0u,0u,0u};
  }

  const size_t bhL = (size_t)bh * LL;
  const ushort_t* wqB = (isW ? w : qn) + bhL * DKk;  // phaseA A-operand source
  const ushort_t* kB  = kt + bhL * DKk;
  const ushort_t* uB  = ut + bhL * DVv;
  const ushort_t* ahB = ah + (size_t)bh * NC * 1024;
  const ushort_t* alB = al + (size_t)bh * NC * 1024;
  float* oB = dout + (size_t)b * LL * DD + h * DVv + vs * 16 + fr;

  floatx4 Sacc[4];   // dk slice [wv*64, wv*64+64) x dv16
#pragma unroll
  for (int i = 0; i < 4; ++i) Sacc[i] = (floatx4){0.f,0.f,0.f,0.f};

  auto loadK = [&](int ci, FragsK& f) {
    const ushort_t* kp = kB + (size_t)ci*8192 + (size_t)(wv*64 + fr)*32 + fq*8;
#pragma unroll
    for (int m = 0; m < 4; ++m) f.kf[m] = *(const short8*)(kp + m*512);
    if (!isW) {
      f.afh = *(const short8*)(ahB + (size_t)ci*1024 + (mt*16+fr)*32 + fq*8);
      f.afl = *(const short8*)(alB + (size_t)ci*1024 + (mt*16+fr)*32 + fq*8);
    }
  };
  auto loadA = [&](int ci, FragsA& f) {
    const ushort_t* ap = wqB + (size_t)(ci*32 + mt*16 + fr) * DKk + fq*8;
#pragma unroll
    for (int ks = 0; ks < 8; ++ks) f.aw[ks] = *(const short8*)(ap + ks*32);
    if (isW)
      f.uu = *(const uint2*)(uB + (size_t)ci*8192 + (size_t)(vs*16 + fr)*32 + mt*16 + fq*4);
  };

  FragsK k0, k1; FragsA a0, a1;
  loadK(0, k0);
  loadA(0, a0);
  __syncthreads();   // ST zero-init visible

  auto body = [&](int ci, FragsK& kc, FragsK& kn, FragsA& ac, FragsA& an) {
    // issue ALL next-chunk loads first: full-chunk load-to-use window
    if (ci + 1 < NC) { loadK(ci + 1, kn); loadA(ci + 1, an); }
    // phaseA (uses ac)
    floatx4 acc0, acc1;
    if (isW) {
      float u0,u1,u2,u3; unpack2(ac.uu.x,u0,u1); unpack2(ac.uu.y,u2,u3);
      acc0 = (floatx4){-u0,-u1,-u2,-u3};
      acc1 = (floatx4){0.f,0.f,0.f,0.f};
#pragma unroll
      for (int ks = 0; ks < 8; ++ks) {
        const short8 sh = *(const short8*)&STh[S16(fr, ks*32 + fq*8)];
        const short8 sl = *(const short8*)&STl[S16(fr, ks*32 + fq*8)];
        acc0 = __builtin_amdgcn_mfma_f32_16x16x32_bf16(ac.aw[ks], sh, acc0, 0,0,0);
        acc1 = __builtin_amdgcn_mfma_f32_16x16x32_bf16(ac.aw[ks], sl, acc1, 0,0,0);
      }
      const float v0 = -(acc0[0]+acc1[0]), v1 = -(acc0[1]+acc1[1]);
      const float v2 = -(acc0[2]+acc1[2]), v3 = -(acc0[3]+acc1[3]);
      unsigned ph0, pl0, ph1, pl1;
      split2t(v0, v1, ph0, pl0); split2t(v2, v3, ph1, pl1);
      *(uint2*)&Uh[U16(fr, mt*16 + fq*4)] = (uint2){ph0, ph1};
      *(uint2*)&Ul[U16(fr, mt*16 + fq*4)] = (uint2){pl0, pl1};
    } else {
      acc0 = (floatx4){0.f,0.f,0.f,0.f};
#pragma unroll
      for (int ks = 0; ks < 8; ++ks) {
        const short8 sh = *(const short8*)&STh[S16(fr, ks*32 + fq*8)];
        acc0 = __builtin_amdgcn_mfma_f32_16x16x32_bf16(ac.aw[ks], sh, acc0, 0,0,0);
      }
    }
    __syncthreads();   // BAR1: uhat ready; all ST reads of this chunk done
    const short8 uhh = *(const short8*)&Uh[U16(fr, fq*8)];
    const short8 uhl = *(const short8*)&Ul[U16(fr, fq*8)];
    if (!isW) {
      // o = q@Sh + attn@uhat; coalesced f32 stores (16 consecutive dv)
      acc0 = __builtin_amdgcn_mfma_f32_16x16x32_bf16(kc.afh, uhh, acc0, 0,0,0);
      acc0 = __builtin_amdgcn_mfma_f32_16x16x32_bf16(kc.afh, uhl, acc0, 0,0,0);
      acc0 = __builtin_amdgcn_mfma_f32_16x16x32_bf16(kc.afl, uhh, acc0, 0,0,0);
      float* op = oB + (size_t)(ci*32 + mt*16 + fq*4) * DD;
#pragma unroll
      for (int r = 0; r < 4; ++r) op[(size_t)r * DD] = acc0[r];
    }
    // S += kT @ (uhat_hi + uhat_lo): wave's own 4 dk tiles
#pragma unroll
    for (int m = 0; m < 4; ++m) {
      Sacc[m] = __builtin_amdgcn_mfma_f32_16x16x32_bf16(kc.kf[m], uhh, Sacc[m], 0,0,0);
      Sacc[m] = __builtin_amdgcn_mfma_f32_16x16x32_bf16(kc.kf[m], uhl, Sacc[m], 0,0,0);
    }
    // mirror S slice -> shared LDS image (hi/lo) for next chunk
#pragma unroll
    for (int m = 0; m < 4; ++m) {
      unsigned ph0, pl0, ph1, pl1;
      split2t(Sacc[m][0], Sacc[m][1], ph0, pl0);
      split2t(Sacc[m][2], Sacc[m][3], ph1, pl1);
      const int dk0 = wv*64 + m*16 + fq*4;
      *(uint2*)&STh[S16(fr, dk0)] = (uint2){ph0, ph1};
      *(uint2*)&STl[S16(fr, dk0)] = (uint2){pl0, pl1};
    }
    __syncthreads();   // BAR2: ST ready; Uh readers done
  };

  for (int c2 = 0; c2 < NC; c2 += 2) {
    body(c2,     k0, k1, a0, a1);
    body(c2 + 1, k1, k0, a1, a0);
  }
}

// ---- EMA pass 1: per-segment local scan ------------------------------------
__global__ __launch_bounds__(256) void ema_local_kernel(const ushort_t* __restrict__ v,
  const float* __restrict__ gs, const float* __restrict__ gl,
  ushort_t* __restrict__ es, ushort_t* __restrict__ el,
  float* __restrict__ Bs, float* __restrict__ Bl,
  float* __restrict__ As, float* __restrict__ Al,
  float* __restrict__ PfS, float* __restrict__ PfL)
{
  const int bid = blockIdx.x;
  const int seg = bid & (NSEG - 1), bh = bid >> 6;
  const int b = bh >> 2, h = bh & 3;
  const int dv = threadIdx.x;
  const int l0 = seg * SEG;
  const ushort_t* vp = v + ((size_t)bh*LL + l0) * DVv + dv;
  const float* gsp = gs + (size_t)bh*LL + l0;
  const float* glp = gl + (size_t)bh*LL + l0;
  ushort_t* esp = es + ((size_t)b*LL + l0)*DD + h*DVv + dv;
  ushort_t* elp = el + ((size_t)b*LL + l0)*DD + h*DVv + dv;
  float* pfs = PfS + (size_t)bh*LL + l0;
  float* pfl = PfL + (size_t)bh*LL + l0;
  float s1 = 0.f, s2 = 0.f, p1 = 1.f, p2 = 1.f;
  for (int j = 0; j < SEG; ++j) {
    const float vv = bf2f(vp[(size_t)j * DVv]);
    const float a = gsp[j], g2 = glp[j];
    s1 = fmaf(a,  s1, (1.f - a)  * vv);
    s2 = fmaf(g2, s2, (1.f - g2) * vv);
    p1 *= a; p2 *= g2;
    esp[(size_t)j * DD] = f2bf(s1);
    elp[(size_t)j * DD] = f2bf(s2);
    if (dv == 0) { pfs[j] = p1; pfl[j] = p2; }
  }
  const size_t o = (((size_t)bh*NSEG + seg) << 8) + dv;
  Bs[o] = s1; Bl[o] = s2;
  if (dv == 0) { As[bh*NSEG + seg] = p1; Al[bh*NSEG + seg] = p2; }
}

// ---- EMA pass 2: cross-segment carry (carry INTO each segment) -------------
__global__ __launch_bounds__(256) void ema_carry_kernel(
  const float* __restrict__ Bs, const float* __restrict__ Bl,
  const float* __restrict__ As, const float* __restrict__ Al,
  float* __restrict__ Cs, float* __restrict__ Cl)
{
  const int bh = blockIdx.x;
  const int dv = threadIdx.x;
  __shared__ float Ash[NSEG], Alh[NSEG];
  if (dv < NSEG) { Ash[dv] = As[bh*NSEG + dv]; Alh[dv] = Al[bh*NSEG + dv]; }
  __syncthreads();
  float c1 = 0.f, c2 = 0.f;
  for (int s = 0; s < NSEG; ++s) {
    const size_t o = (((size_t)bh*NSEG + s) << 8) + dv;
    Cs[o] = c1; Cl[o] = c2;
    c1 = fmaf(Ash[s], c1, Bs[o]);
    c2 = fmaf(Alh[s], c2, Bl[o]);
  }
}

// ---- combine + per-head RMSNorm; 4 waves/block (one old 64-thread block
// per wave) to remove tiny-block scheduling overhead. ------------------------
__global__ __launch_bounds__(256) void combine_kernel(const ushort_t* __restrict__ v,
  const ushort_t* __restrict__ es, const ushort_t* __restrict__ el,
  const float* __restrict__ dov, const float* __restrict__ wgt,
  const float* __restrict__ onw,
  const float* __restrict__ Cs, const float* __restrict__ Cl,
  const float* __restrict__ PfS, const float* __restrict__ PfL,
  ushort_t* __restrict__ outp)
{
  const int bid = blockIdx.x * 4 + (threadIdx.x >> 6);
  const int h = bid & 3;
  const size_t bl = (size_t)(bid >> 2);
  const int lane = threadIdx.x & 63;
  const size_t b = bl >> 12;
  const size_t l = bl & (LL - 1);
  const int bh = (int)(b * HH) + h;
  const int seg = (int)(l >> 6);
  const size_t vidx = (((b*HH + h) * (size_t)LL) + l) * DVv + lane*4;
  const size_t didx = bl * DD + h*DVv + lane*4;
  const uint2 vu = *(const uint2*)(v + vidx);
  const uint2 eu = *(const uint2*)(es + didx);
  const uint2 gu = *(const uint2*)(el + didx);
  const float4 d4 = *(const float4*)(dov + didx);
  const float pS = PfS[(size_t)bh*LL + l];
  const float pL = PfL[(size_t)bh*LL + l];
  const float4 cs4 = *(const float4*)(Cs + (((size_t)bh*NSEG + seg) << 8) + lane*4);
  const float4 cl4 = *(const float4*)(Cl + (((size_t)bh*NSEG + seg) << 8) + lane*4);
  float vf[4], ef[4], gf[4];
  unpack2(vu.x, vf[0], vf[1]); unpack2(vu.y, vf[2], vf[3]);
  unpack2(eu.x, ef[0], ef[1]); unpack2(eu.y, ef[2], ef[3]);
  unpack2(gu.x, gf[0], gf[1]); unpack2(gu.y, gf[2], gf[3]);
  ef[0] = fmaf(pS, cs4.x, ef[0]); ef[1] = fmaf(pS, cs4.y, ef[1]);
  ef[2] = fmaf(pS, cs4.z, ef[2]); ef[3] = fmaf(pS, cs4.w, ef[3]);
  gf[0] = fmaf(pL, cl4.x, gf[0]); gf[1] = fmaf(pL, cl4.y, gf[1]);
  gf[2] = fmaf(pL, cl4.z, gf[2]); gf[3] = fmaf(pL, cl4.w, gf[3]);
  const float* wp = wgt + (size_t)bid * 4;
  const float w0 = wp[0], w1 = wp[1], w2 = wp[2], w3 = wp[3];
  float o[4];
  const float df[4] = {d4.x, d4.y, d4.z, d4.w};
  float ss = 0.f;
#pragma unroll
  for (int i = 0; i < 4; ++i) {
    o[i] = w0*vf[i] + w1*ef[i] + w2*df[i] + w3*gf[i];
    ss = fmaf(o[i], o[i], ss);
  }
#pragma unroll
  for (int off = 1; off < 64; off <<= 1) ss += __shfl_xor(ss, off);
  const float sc = rsqrtf(ss * (1.f / DVv) + 1e-5f);
  const float4 nw = *(const float4*)(onw + lane*4);
  uint2 pk;
  pk.x = pack2(o[0]*sc*nw.x, o[1]*sc*nw.y);
  pk.y = pack2(o[2]*sc*nw.z, o[3]*sc*nw.w);
  *(uint2*)(outp + didx) = pk;
}

extern "C" void kernel_launch(void* const* d_in, const int* in_sizes, int n_in,
                              void* d_out, int out_size, void* d_ws, size_t ws_size,
                              hipStream_t stream)
{
  const float* x    = (const float*)d_in[0];
  const float* Wq   = (const float*)d_in[1];
  const float* Wk   = (const float*)d_in[2];
  const float* Wv   = (const float*)d_in[3];
  const float* cqw  = (const float*)d_in[4];
  const float* ckw  = (const float*)d_in[5];
  const float* cvw  = (const float*)d_in[6];
  const float* Wb   = (const float*)d_in[7];
  const float* Wds  = (const float*)d_in[8];
  const float* bds  = (const float*)d_in[9];
  const float* Wdl  = (const float*)d_in[10];
  const float* bdl  = (const float*)d_in[11];
  const float* Wtr  = (const float*)d_in[12];
  const float* btr  = (const float*)d_in[13];
  const float* Wc   = (const float*)d_in[14];
  const float* bc   = (const float*)d_in[15];
  const float* Wl   = (const float*)d_in[16];
  const float* blc  = (const float*)d_in[17];
  const float* Wg   = (const float*)d_in[18];
  const float* bg   = (const float*)d_in[19];
  const float* ltc  = (const float*)d_in[20];
  const float* ltf  = (const float*)d_in[21];
  const float* onw  = (const float*)d_in[22];
  const float* Wo   = (const float*)d_in[23];
  float* outp = (float*)d_out;

  const size_t BLD = (size_t)BB * LL * DD;
  unsigned char* w8 = (unsigned char*)d_ws;
  const size_t SL = BLD * 2;                        // 32 MB bf16 slab
  ushort_t* SA = (ushort_t*)(w8 + 0*SL);   // qraw -> kn -> kT -> opre
  ushort_t* SB = (ushort_t*)(w8 + 1*SL);   // kraw -> vv
  ushort_t* SC = (ushort_t*)(w8 + 2*SL);   // vraw -> uT
  ushort_t* SD = (ushort_t*)(w8 + 3*SL);   // xb -> qn -> el(local)
  ushort_t* SE = (ushort_t*)(w8 + 4*SL);   // w  -> es(local)
  ushort_t* zb   = (ushort_t*)(w8 + 5*SL);
  ushort_t* attn_hi = (ushort_t*)(w8 + 5*SL + BLD);
  ushort_t* attn_lo = attn_hi + (size_t)BB*HH*NC*1024;
  float*    beta = (float*)(attn_hi + 2*(size_t)BB*HH*NC*1024);
  float*    gs   = beta + (size_t)BB*HH*LL;
  float*    gl   = gs   + (size_t)BB*HH*LL;
  float*    wgt  = gl   + (size_t)BB*HH*LL;
  float*    Bs   = wgt  + (size_t)BB*LL*HH*4;
  float*    Bl   = Bs   + (size_t)BB*HH*NSEG*256;
  float*    Cs   = Bl   + (size_t)BB*HH*NSEG*256;
  float*    Cl   = Cs   + (size_t)BB*HH*NSEG*256;
  float*    As   = Cl   + (size_t)BB*HH*NSEG*256;
  float*    Al   = As   + (size_t)BB*HH*NSEG;
  float*    PfS  = Al   + (size_t)BB*HH*NSEG;
  float*    PfL  = PfS  + (size_t)BB*HH*LL;
  // W slabs: Wq,Wk,Wv,Wtr contiguous (fused GEMM reads rows 0..3583), then Wo
  ushort_t* Wqb  = (ushort_t*)(PfL + (size_t)BB*HH*LL);
  ushort_t* Wkb  = Wqb + (size_t)DD*DD;
  ushort_t* Wvb  = Wkb + (size_t)DD*DD;
  ushort_t* Wtrb = Wvb + (size_t)DD*DD;
  ushort_t* Wob  = Wtrb + (size_t)HIDD*DD;
  ushort_t* xb   = SD;                     // bf16 x, consumed by the fused GEMM
  float*    dov  = outp;

  const int MBL = BB * LL;  // 16384
  dim3 blk256(256);

  {
    const int NTOT = (int)(BLD/8) + 4*(DD*DD/8) + HIDD*DD/8;
    cvt_all_kernel<<<dim3((NTOT + 255)/256), blk256, 0, stream>>>(
        x, Wq, Wk, Wv, Wtr, Wo, xb, Wqb, Wkb, Wvb, Wtrb, Wob);
  }

  gemm_qkvt<<<dim3(28, MBL/128), blk256, 0, stream>>>(xb, Wqb, btr, SA, SB, SC, zb, MBL, DD);
  small_proj_kernel<<<dim3(MBL), blk256, 0, stream>>>(x, Wb, Wds, bds, Wdl, bdl, beta, gs, gl);
  gate_kernel<<<dim3(MBL), blk256, 0, stream>>>(zb, Wc, bc, Wl, blc, Wg, bg, ltc, ltf, wgt);
  conv_silu_kernel<<<dim3((unsigned)(BLD/8/256)), blk256, 0, stream>>>(SA, cqw, SD);  // qn=SD
  conv_silu_kernel<<<dim3((unsigned)(BLD/8/256)), blk256, 0, stream>>>(SB, ckw, SA);  // kn=SA
  conv_silu_kernel<<<dim3((unsigned)(BLD/8/256)), blk256, 0, stream>>>(SC, cvw, SB);  // vv=SB
  prep_kernel<<<dim3(BB*HH*NC), blk256, 0, stream>>>(SD, SA, SB, beta, SC, SE, attn_hi, attn_lo); // uT=SC w=SE kT=SA
  scan_kernel<<<dim3(256), blk256, 0, stream>>>(SD, SA, SC, SE, attn_hi, attn_lo, dov);
  ema_local_kernel<<<dim3(BB*HH*NSEG), blk256, 0, stream>>>(SB, gs, gl, SE, SD, Bs, Bl, As, Al, PfS, PfL); // es=SE el=SD
  ema_carry_kernel<<<dim3(BB*HH), blk256, 0, stream>>>(Bs, Bl, As, Al, Cs, Cl);
  combine_kernel<<<dim3(MBL*HH/4), blk256, 0, stream>>>(SB, SE, SD, dov, wgt, onw, Cs, Cl, PfS, PfL, SA); // opre=SA
  gemm_bf16<0,0><<<dim3(DD/128, MBL/128), blk256, 0, stream>>>(SA, Wob, nullptr, outp, MBL, DD, DD);
}

// Round 11
// 1000.549 us; speedup vs baseline: 1.1448x; 1.0157x over previous
//
#include <hip/hip_runtime.h>
#include <math.h>

#define BB 4
#define LL 4096
#define DD 1024
#define HH 4
#define DKk 256
#define DVv 256
#define HIDD 512
#define NC 128   // number of 32-chunks in L
#define NSEG 64  // EMA segments
#define SEG 64   // EMA segment length

typedef unsigned short ushort_t;
typedef __attribute__((ext_vector_type(8))) short short8;
typedef __attribute__((ext_vector_type(4))) float floatx4;

__device__ __forceinline__ float sigm(float x) { return 1.f / (1.f + __expf(-x)); }

__device__ __forceinline__ float bf2f(ushort_t u) {
  union { unsigned int i; float f; } c; c.i = ((unsigned int)u) << 16; return c.f;
}
__device__ __forceinline__ ushort_t f2bf(float f) {
  union { float f; unsigned int i; } c; c.f = f;
  unsigned int lsb = (c.i >> 16) & 1u;
  return (ushort_t)((c.i + 0x7fffu + lsb) >> 16);
}
__device__ __forceinline__ void unpack2(unsigned int u, float& a, float& b) {
  union { unsigned int i; float f; } c0, c1;
  c0.i = u << 16; c1.i = u & 0xffff0000u; a = c0.f; b = c1.f;
}
__device__ __forceinline__ unsigned int pack2(float a, float b) {
  return (unsigned int)f2bf(a) | ((unsigned int)f2bf(b) << 16);
}
__device__ __forceinline__ void unpack8(const uint4 v, float* o) {
  unpack2(v.x, o[0], o[1]); unpack2(v.y, o[2], o[3]);
  unpack2(v.z, o[4], o[5]); unpack2(v.w, o[6], o[7]);
}
__device__ __forceinline__ float ubits(unsigned u) {
  union { unsigned i; float f; } c; c.i = u; return c.f;
}
// exact truncate-split of two floats into packed bf16 hi and bf16 lo words
__device__ __forceinline__ void split2t(float a, float b, unsigned& hi, unsigned& lo) {
  union { float f; unsigned u; } ca, cb; ca.f = a; cb.f = b;
  const unsigned ha = ca.u & 0xffff0000u, hb = cb.u & 0xffff0000u;
  hi = (ha >> 16) | hb;
  union { float f; unsigned u; } la, lb;
  la.f = a - ubits(ha); lb.f = b - ubits(hb);
  lo = (la.u >> 16) | (lb.u & 0xffff0000u);
}
__device__ __forceinline__ void gload16(const ushort_t* g, ushort_t* l) {
  __builtin_amdgcn_global_load_lds(
      (const __attribute__((address_space(1))) void*)g,
      (__attribute__((address_space(3))) void*)l, 16, 0, 0);
}

// ---- fused f32 -> bf16 converts (x + 5 weight matrices), 8 elems/thread ----
// order: x, Wq, Wk, Wv, Wtr, Wo  (qkv+trunk contiguous for the fused GEMM)
__global__ __launch_bounds__(256) void cvt_all_kernel(
    const float* __restrict__ x,  const float* __restrict__ Wq,
    const float* __restrict__ Wk, const float* __restrict__ Wv,
    const float* __restrict__ Wtr, const float* __restrict__ Wo,
    ushort_t* __restrict__ xb,  ushort_t* __restrict__ Wqb,
    ushort_t* __restrict__ Wkb, ushort_t* __restrict__ Wvb,
    ushort_t* __restrict__ Wtrb, ushort_t* __restrict__ Wob)
{
  const int NX = (int)((size_t)BB*LL*DD/8), NW = DD*DD/8, NT = HIDD*DD/8;
  int i = blockIdx.x * 256 + threadIdx.x;
  const float* src; ushort_t* dst;
  if (i < NX) { src = x; dst = xb; }
  else {
    i -= NX;
    if (i < NW) { src = Wq; dst = Wqb; }
    else { i -= NW;
      if (i < NW) { src = Wk; dst = Wkb; }
      else { i -= NW;
        if (i < NW) { src = Wv; dst = Wvb; }
        else { i -= NW;
          if (i < NT) { src = Wtr; dst = Wtrb; }
          else { i -= NT; if (i >= NW) return; src = Wo; dst = Wob; }
        }
      }
    }
  }
  const float4 a = ((const float4*)src)[2*i];
  const float4 b = ((const float4*)src)[2*i + 1];
  uint4 p;
  p.x = pack2(a.x, a.y); p.y = pack2(a.z, a.w);
  p.z = pack2(b.x, b.y); p.w = pack2(b.z, b.w);
  ((uint4*)dst)[i] = p;
}

// ---- MFMA GEMM, bf16 A and W, global_load_lds staging, 1D XCD-swizzled -----
// grid = (M/128)*(N/128) with M/128 == 128.  Panel y -> XCD y&7 so each
// A-row-panel lives on exactly ONE XCD's L2 (A traffic 8x lower).
// C(M,N) = A(M,K) @ W(N,K)^T.  BF16OUT: bf16 else f32.
template<int BF16OUT>
__global__ __launch_bounds__(256) void gemm_bf16(const ushort_t* __restrict__ A,
    const ushort_t* __restrict__ W, void* __restrict__ Cv, int M, int N, int K)
{
  __shared__ ushort_t As[128*32];
  __shared__ ushort_t Ws[128*32];
  const int bid = blockIdx.x;
  const int xcd = bid & 7;
  const int idx = bid >> 3;
  const int xB = idx >> 4;          // N panel
  const int yl = idx & 15;
  const int yB = xcd + (yl << 3);   // M panel -> XCD = yB&7
  const int tid = threadIdx.x;
  const int bm = yB * 128, bn = xB * 128;
  const int lane = tid & 63, wave = tid >> 6;
  const int wm = (wave >> 1) * 64, wn = (wave & 1) * 64;
  const int fr = lane & 15, fq = lane >> 4;
  const int srow = wave * 16 + (lane >> 2);
  const int scol = (lane & 3) * 8;
  const ushort_t* Ap = A + (size_t)(bm + srow) * K + scol;
  const ushort_t* Wp = W + (size_t)(bn + srow) * K + scol;
  ushort_t* AsD = &As[wave * 512];
  ushort_t* WsD = &Ws[wave * 512];
  floatx4 acc[4][4];
#pragma unroll
  for (int i = 0; i < 4; ++i)
#pragma unroll
    for (int j = 0; j < 4; ++j) acc[i][j] = (floatx4){0.f, 0.f, 0.f, 0.f};

  for (int k0 = 0; k0 < K; k0 += 32) {
    __syncthreads();
    gload16(Ap + k0, AsD);
    gload16(Ap + (size_t)64 * K + k0, AsD + 64*32);
    gload16(Wp + k0, WsD);
    gload16(Wp + (size_t)64 * K + k0, WsD + 64*32);
    __syncthreads();
    short8 af[4], bf_[4];
#pragma unroll
    for (int mt = 0; mt < 4; ++mt)
      af[mt] = *(const short8*)&As[(wm + mt*16 + fr)*32 + fq*8];
#pragma unroll
    for (int nt = 0; nt < 4; ++nt)
      bf_[nt] = *(const short8*)&Ws[(wn + nt*16 + fr)*32 + fq*8];
#pragma unroll
    for (int mt = 0; mt < 4; ++mt)
#pragma unroll
      for (int nt = 0; nt < 4; ++nt)
        acc[mt][nt] = __builtin_amdgcn_mfma_f32_16x16x32_bf16(af[mt], bf_[nt], acc[mt][nt], 0, 0, 0);
  }
#pragma unroll
  for (int mt = 0; mt < 4; ++mt) {
#pragma unroll
    for (int reg = 0; reg < 4; ++reg) {
      const int row = bm + wm + mt*16 + fq*4 + reg;
#pragma unroll
      for (int nt = 0; nt < 4; ++nt) {
        const int col = bn + wn + nt*16 + fr;
        const float v = acc[mt][nt][reg];
        if (BF16OUT) ((ushort_t*)Cv)[(size_t)row * N + col] = f2bf(v);
        else         ((float*)Cv)[(size_t)row * N + col] = v;
      }
    }
  }
}

// ---- fused q/k/v/trunk GEMM: Wcat = [Wq;Wk;Wv;Wtr] rows (3584 x 1024) ------
// 1D XCD-swizzled grid (3584 = 8 xcd x 16 yl x 28 x). cols [0,3072) ->
// Cq/Ck/Cv; cols [3072,3584) -> trunk bias+SiLU into Cz. Block-uniform dispatch.
__global__ __launch_bounds__(256) void gemm_qkvt(const ushort_t* __restrict__ A,
    const ushort_t* __restrict__ Wcat, const float* __restrict__ btr,
    ushort_t* __restrict__ Cq, ushort_t* __restrict__ Ck,
    ushort_t* __restrict__ Cvv, ushort_t* __restrict__ Cz, int M, int K)
{
  __shared__ ushort_t As[128*32];
  __shared__ ushort_t Ws[128*32];
  const int bid = blockIdx.x;
  const int xcd = bid & 7;
  const int idx = bid >> 3;
  const int xB = idx >> 4;          // 0..27
  const int yl = idx & 15;
  const int yB = xcd + (yl << 3);   // 0..127
  const int tid = threadIdx.x;
  const int bm = yB * 128, bn = xB * 128;
  const int lane = tid & 63, wave = tid >> 6;
  const int wm = (wave >> 1) * 64, wn = (wave & 1) * 64;
  const int fr = lane & 15, fq = lane >> 4;
  const int srow = wave * 16 + (lane >> 2);
  const int scol = (lane & 3) * 8;
  const ushort_t* Ap = A + (size_t)(bm + srow) * K + scol;
  const ushort_t* Wp = Wcat + (size_t)(bn + srow) * K + scol;
  ushort_t* AsD = &As[wave * 512];
  ushort_t* WsD = &Ws[wave * 512];
  floatx4 acc[4][4];
#pragma unroll
  for (int i = 0; i < 4; ++i)
#pragma unroll
    for (int j = 0; j < 4; ++j) acc[i][j] = (floatx4){0.f, 0.f, 0.f, 0.f};

  for (int k0 = 0; k0 < K; k0 += 32) {
    __syncthreads();
    gload16(Ap + k0, AsD);
    gload16(Ap + (size_t)64 * K + k0, AsD + 64*32);
    gload16(Wp + k0, WsD);
    gload16(Wp + (size_t)64 * K + k0, WsD + 64*32);
    __syncthreads();
    short8 af[4], bf_[4];
#pragma unroll
    for (int mt = 0; mt < 4; ++mt)
      af[mt] = *(const short8*)&As[(wm + mt*16 + fr)*32 + fq*8];
#pragma unroll
    for (int nt = 0; nt < 4; ++nt)
      bf_[nt] = *(const short8*)&Ws[(wn + nt*16 + fr)*32 + fq*8];
#pragma unroll
    for (int mt = 0; mt < 4; ++mt)
#pragma unroll
      for (int nt = 0; nt < 4; ++nt)
        acc[mt][nt] = __builtin_amdgcn_mfma_f32_16x16x32_bf16(af[mt], bf_[nt], acc[mt][nt], 0, 0, 0);
  }
  const bool trunk = (bn >= 3072);
  ushort_t* dst;
  int nloc, cbase;
  if (!trunk) {
    const int mat = bn >> 10;
    dst = (mat == 0 ? Cq : (mat == 1 ? Ck : Cvv));
    nloc = 1024; cbase = bn & 1023;
  } else {
    dst = Cz; nloc = 512; cbase = bn - 3072;
  }
#pragma unroll
  for (int mt = 0; mt < 4; ++mt) {
#pragma unroll
    for (int reg = 0; reg < 4; ++reg) {
      const int row = bm + wm + mt*16 + fq*4 + reg;
#pragma unroll
      for (int nt = 0; nt < 4; ++nt) {
        const int col = cbase + wn + nt*16 + fr;
        float v = acc[mt][nt][reg];
        if (trunk) { v += btr[col]; v = v * sigm(v); }
        dst[(size_t)row * nloc + col] = f2bf(v);
      }
    }
  }
}

// ---- depthwise causal conv(k=4)+SiLU, vectorized 8/thread ------------------
__global__ __launch_bounds__(256) void conv_silu_kernel(const ushort_t* __restrict__ xin,
    const float* __restrict__ wc, ushort_t* __restrict__ outp)
{
  const size_t i8 = (size_t)blockIdx.x * 256 + threadIdx.x;  // over B*L*D/8
  const int d8 = (int)((i8 & 127) << 3);
  const int l  = (int)((i8 >> 7) & (LL - 1));
  const int b  = (int)(i8 >> 19);
  const ushort_t* xp = xin + i8 * 8;
  const uint4 z4 = (uint4){0u,0u,0u,0u};
  const uint4 v0 = *(const uint4*)xp;
  const uint4 v1 = (l >= 1) ? *(const uint4*)(xp - DD)   : z4;
  const uint4 v2 = (l >= 2) ? *(const uint4*)(xp - 2*DD) : z4;
  const uint4 v3 = (l >= 3) ? *(const uint4*)(xp - 3*DD) : z4;
  float x0[8], x1[8], x2[8], x3[8];
  unpack8(v0, x0); unpack8(v1, x1); unpack8(v2, x2); unpack8(v3, x3);
  unsigned pk[4];
#pragma unroll
  for (int p = 0; p < 4; ++p) {
    float o2[2];
#pragma unroll
    for (int q = 0; q < 2; ++q) {
      const int j = p*2 + q;
      const float4 w = *(const float4*)(wc + (d8 + j) * 4);
      float acc = w.w * x0[j];
      acc = fmaf(w.z, x1[j], acc);
      acc = fmaf(w.y, x2[j], acc);
      acc = fmaf(w.x, x3[j], acc);
      o2[q] = acc * sigm(acc);
    }
    pk[p] = pack2(o2[0], o2[1]);
  }
  const int h = d8 >> 8, dk = d8 & 255;
  *(uint4*)(outp + (((size_t)(b*HH + h))*LL + l)*DKk + dk) = *(uint4*)pk;
}

// ---- beta / g_s / g_l: 12 length-1024 dots per (b,l), x fp32 ---------------
__global__ __launch_bounds__(256) void small_proj_kernel(const float* __restrict__ x,
   const float* __restrict__ Wb, const float* __restrict__ Wds, const float* __restrict__ bds,
   const float* __restrict__ Wdl, const float* __restrict__ bdl,
   float* __restrict__ beta, float* __restrict__ gs, float* __restrict__ gl)
{
  const int bl = blockIdx.x;
  const int t = threadIdx.x, wave = t >> 6, lane = t & 63;
  __shared__ float res[12];
  const float* xr = x + (size_t)bl * DD + lane * 16;
  const float4 x0 = *(const float4*)(xr);
  const float4 x1 = *(const float4*)(xr + 4);
  const float4 x2 = *(const float4*)(xr + 8);
  const float4 x3 = *(const float4*)(xr + 12);
  for (int rr = 0; rr < 3; ++rr) {
    const int r = wave * 3 + rr;
    const int mat = r >> 2, h = r & 3;
    const float* Wr = (mat == 0 ? Wb : (mat == 1 ? Wds : Wdl)) + (size_t)h * DD + lane * 16;
    const float4 w0 = *(const float4*)(Wr);
    const float4 w1 = *(const float4*)(Wr + 4);
    const float4 w2 = *(const float4*)(Wr + 8);
    const float4 w3 = *(const float4*)(Wr + 12);
    float p = x0.x*w0.x + x0.y*w0.y + x0.z*w0.z + x0.w*w0.w
            + x1.x*w1.x + x1.y*w1.y + x1.z*w1.z + x1.w*w1.w
            + x2.x*w2.x + x2.y*w2.y + x2.z*w2.z + x2.w*w2.w
            + x3.x*w3.x + x3.y*w3.y + x3.z*w3.z + x3.w*w3.w;
#pragma unroll
    for (int o = 1; o < 64; o <<= 1) p += __shfl_xor(p, o);
    if (lane == 0) res[r] = p;
  }
  __syncthreads();
  if (t < 12) {
    const int mat = t >> 2, h = t & 3;
    float v = res[t];
    if (mat == 1) v += bds[h];
    if (mat == 2) v += bdl[h];
    v = sigm(v);
    const int b = bl >> 12, l = bl & (LL - 1);
    const size_t o = ((size_t)(b*HH + h))*LL + l;
    (mat == 0 ? beta : (mat == 1 ? gs : gl))[o] = v;
  }
}

// ---- hierarchical gate: z bf16, 24 length-512 dots + 2-way softmaxes -------
__global__ __launch_bounds__(256) void gate_kernel(const ushort_t* __restrict__ z,
  const float* __restrict__ Wc, const float* __restrict__ bc,
  const float* __restrict__ Wl, const float* __restrict__ bl_,
  const float* __restrict__ Wg, const float* __restrict__ bg,
  const float* __restrict__ ltc, const float* __restrict__ ltf,
  float* __restrict__ wgt)
{
  const int bl = blockIdx.x;
  const int t = threadIdx.x, wave = t >> 6, lane = t & 63;
  __shared__ float res[24];
  const uint4 zv = *(const uint4*)(z + (size_t)bl * HIDD + lane * 8);
  float zf[8]; unpack8(zv, zf);
  for (int rr = 0; rr < 6; ++rr) {
    const int r = wave * 6 + rr;
    const int mat = r >> 3, qi = r & 7;
    const float* Wr = (mat == 0 ? Wc : (mat == 1 ? Wl : Wg)) + (size_t)qi * HIDD + lane * 8;
    const float4 w0 = *(const float4*)(Wr);
    const float4 w1 = *(const float4*)(Wr + 4);
    float p = zf[0]*w0.x + zf[1]*w0.y + zf[2]*w0.z + zf[3]*w0.w
            + zf[4]*w1.x + zf[5]*w1.y + zf[6]*w1.z + zf[7]*w1.w;
#pragma unroll
    for (int o = 1; o < 64; o <<= 1) p += __shfl_xor(p, o);
    if (lane == 0) {
      const float* br = (mat == 0 ? bc : (mat == 1 ? bl_ : bg));
      res[r] = p + br[qi];
    }
  }
  __syncthreads();
  if (t < 4) {
    const float tc = logf(1.f + __expf(ltc[t])) + 1e-4f;
    const float tf = logf(1.f + __expf(ltf[t])) + 1e-4f;
    const float pg0 = sigm((res[2*t]     - res[2*t+1])     / tc);
    const float q0  = sigm((res[8+2*t]   - res[8+2*t+1])   / tf);
    const float r0  = sigm((res[16+2*t]  - res[16+2*t+1])  / tf);
    float* o = wgt + ((size_t)bl * HH + t) * 4;
    o[0] = pg0 * q0;         o[1] = pg0 * (1.f - q0);
    o[2] = (1.f - pg0) * r0; o[3] = (1.f - pg0) * (1.f - r0);
  }
}

// ---- chunk-local prep: vectorized l2norm, MFMA attn(hi/lo)+Lm, solves ------
#define QS 264
__global__ __launch_bounds__(256) void prep_kernel(ushort_t* __restrict__ q,
    ushort_t* __restrict__ k, const ushort_t* __restrict__ v,
    const float* __restrict__ beta,
    ushort_t* __restrict__ u, ushort_t* __restrict__ w,
    ushort_t* __restrict__ ah, ushort_t* __restrict__ al)
{
  __shared__ ushort_t qb[32*QS];
  __shared__ ushort_t kb[32*QS];
  __shared__ float Lm[32*32];
  __shared__ float betas[32];
  const int bid = blockIdx.x;
  const int ci = bid & (NC - 1);
  const int bh = bid >> 7;
  const int t = threadIdx.x;
  const size_t base = ((size_t)bh * LL + ci*32) * DKk;
  if (t < 32) betas[t] = beta[(size_t)bh * LL + ci*32 + t];
  for (int i4 = t; i4 < 1024; i4 += 256) {
    const int r = i4 >> 5, e = (i4 & 31) * 8;
    *(uint4*)&qb[r*QS + e] = *(const uint4*)(q + base + r*256 + e);
    *(uint4*)&kb[r*QS + e] = *(const uint4*)(k + base + r*256 + e);
  }
  __syncthreads();
  // l2norm: vectorized -- 8 uint4 reads, values kept in regs, 8 uint4 writes
  {
    const int r = t >> 3, g = t & 7;
    const int e0 = g * 32;
    float qf[32], kf[32];
#pragma unroll
    for (int j = 0; j < 4; ++j) {
      const uint4 qv = *(const uint4*)&qb[r*QS + e0 + j*8];
      const uint4 kv = *(const uint4*)&kb[r*QS + e0 + j*8];
      unpack8(qv, qf + j*8); unpack8(kv, kf + j*8);
    }
    float sq = 0.f, sk = 0.f;
#pragma unroll
    for (int j = 0; j < 32; ++j) {
      sq = fmaf(qf[j], qf[j], sq);
      sk = fmaf(kf[j], kf[j], sk);
    }
#pragma unroll
    for (int o = 1; o < 8; o <<= 1) { sq += __shfl_xor(sq, o); sk += __shfl_xor(sk, o); }
    const float rq = rsqrtf(sq + 1e-6f), rk = rsqrtf(sk + 1e-6f);
#pragma unroll
    for (int j = 0; j < 4; ++j) {
      uint4 qo, ko;
      qo.x = pack2(qf[j*8+0]*rq, qf[j*8+1]*rq);
      qo.y = pack2(qf[j*8+2]*rq, qf[j*8+3]*rq);
      qo.z = pack2(qf[j*8+4]*rq, qf[j*8+5]*rq);
      qo.w = pack2(qf[j*8+6]*rq, qf[j*8+7]*rq);
      ko.x = pack2(kf[j*8+0]*rk, kf[j*8+1]*rk);
      ko.y = pack2(kf[j*8+2]*rk, kf[j*8+3]*rk);
      ko.z = pack2(kf[j*8+4]*rk, kf[j*8+5]*rk);
      ko.w = pack2(kf[j*8+6]*rk, kf[j*8+7]*rk);
      *(uint4*)&qb[r*QS + e0 + j*8] = qo;
      *(uint4*)&kb[r*QS + e0 + j*8] = ko;
    }
  }
  __syncthreads();
  // write back normalized q (row-major, used as MFMA A-frags in scan)
  for (int i4 = t; i4 < 1024; i4 += 256) {
    const int r = i4 >> 5, e = (i4 & 31) * 8;
    *(uint4*)(q + base + r*256 + e) = *(const uint4*)&qb[r*QS + e];
  }
  // write kT (dk-major: [dk][cr]) into the k slab; thread t = dk
  {
    unsigned int pk[16];
#pragma unroll
    for (int j = 0; j < 16; ++j)
      pk[j] = (unsigned int)kb[(2*j)*QS + t] | ((unsigned int)kb[(2*j+1)*QS + t] << 16);
    uint4* kd = (uint4*)(k + base + (size_t)t*32);
#pragma unroll
    for (int j = 0; j < 4; ++j) kd[j] = ((const uint4*)pk)[j];
  }
  // attn = q@k^T (tril), Lm = beta_i * (k@k^T) (strict tril) -- via MFMA.
  {
    const int lane = t & 63, wv4 = t >> 6;
    const int fr = lane & 15, fq = lane >> 4;
    const int it = wv4 >> 1, jt = wv4 & 1;
    floatx4 dq = (floatx4){0.f,0.f,0.f,0.f};
    floatx4 dk2 = (floatx4){0.f,0.f,0.f,0.f};
#pragma unroll
    for (int ks = 0; ks < 8; ++ks) {
      const short8 bfk = *(const short8*)&kb[(jt*16+fr)*QS + ks*32 + fq*8];
      const short8 afq = *(const short8*)&qb[(it*16+fr)*QS + ks*32 + fq*8];
      const short8 afk = *(const short8*)&kb[(it*16+fr)*QS + ks*32 + fq*8];
      dq  = __builtin_amdgcn_mfma_f32_16x16x32_bf16(afq, bfk, dq, 0,0,0);
      dk2 = __builtin_amdgcn_mfma_f32_16x16x32_bf16(afk, bfk, dk2, 0,0,0);
    }
#pragma unroll
    for (int reg = 0; reg < 4; ++reg) {
      const int i = it*16 + fq*4 + reg;
      const int j = jt*16 + fr;
      const float av = (j <= i) ? dq[reg] : 0.f;
      const ushort_t hh = f2bf(av);
      const size_t aoff = ((size_t)bh*NC + ci)*1024 + (size_t)i*32 + j;
      ah[aoff] = hh;
      al[aoff] = f2bf(av - bf2f(hh));
      Lm[i*32 + j] = (j < i) ? betas[i] * dk2[reg] : 0.f;
    }
  }
  __syncthreads();
  {
    float cu[32], cw[32];
#pragma unroll
    for (int r = 0; r < 32; ++r) {
      cu[r] = bf2f(v[base + r*256 + t]) * betas[r];
      cw[r] = bf2f(kb[r*QS + t]) * betas[r];
    }
    // forward substitution with float4 Lm row reads (same values/order)
#pragma unroll
    for (int i = 1; i < 32; ++i) {
      float au = cu[i], aw = cw[i];
#pragma unroll
      for (int jb = 0; jb < (i + 3) / 4; ++jb) {
        const float4 lr = *(const float4*)&Lm[i*32 + jb*4];
        const float lmv[4] = {lr.x, lr.y, lr.z, lr.w};
#pragma unroll
        for (int qv = 0; qv < 4; ++qv) {
          const int j = jb*4 + qv;
          if (j < i) {
            au = fmaf(-lmv[qv], cu[j], au);
            aw = fmaf(-lmv[qv], cw[j], aw);
          }
        }
      }
      cu[i] = au; cw[i] = aw;
    }
    // uT (dv-major: [dv][cr]); thread t = dv -> 64B contiguous
    {
      unsigned int pu[16];
#pragma unroll
      for (int j = 0; j < 16; ++j) pu[j] = pack2(cu[2*j], cu[2*j+1]);
      uint4* ud = (uint4*)(u + base + (size_t)t*32);
#pragma unroll
      for (int j = 0; j < 4; ++j) ud[j] = ((const uint4*)pu)[j];
    }
#pragma unroll
    for (int r = 0; r < 32; ++r) w[base + r*256 + t] = f2bf(cw[r]);
  }
}

// ---- MFMA sequential chunk scan: 256 blocks x 4 specialized waves ----------
// r9 structure (deep ping-pong prefetch). S16 XOR widened to (dv&15)<<3:
// phaseA ds_read conflict 8-way -> 4-way (writes stay 2-way). dout now bf16.
#define S16(dv,kk) (((dv)<<8) + ((kk) ^ (((dv)&15)<<3)))
#define U16(dv,cr) (((dv)<<5) + ((cr) ^ (((dv)&3)<<3)))

struct FragsK { short8 kf[4]; short8 afh, afl; };   // late-phase operands
struct FragsA { short8 aw[8]; uint2 uu; };          // phaseA operands

__global__ __launch_bounds__(256, 1) void scan_kernel(
    const ushort_t* __restrict__ qn, const ushort_t* __restrict__ kt,
    const ushort_t* __restrict__ ut, const ushort_t* __restrict__ w,
    const ushort_t* __restrict__ ah, const ushort_t* __restrict__ al,
    ushort_t* __restrict__ dout)
{
  __shared__ ushort_t STh[16*256];   // 8 KB [dv][dk] hi, swizzled
  __shared__ ushort_t STl[16*256];   // 8 KB lo
  __shared__ ushort_t Uh[16*32];     // 1 KB [dv][cr] hi, swizzled
  __shared__ ushort_t Ul[16*32];     // 1 KB lo
  const int bid = blockIdx.x;
  const int bh = bid & 15, vs = bid >> 4;  // bid%8==bh%8 -> bh pinned to XCD
  const int b = bh >> 2, h = bh & 3;
  const int t = threadIdx.x, lane = t & 63, wv = t >> 6;
  const int fr = lane & 15, fq = lane >> 4;
  const int mt = wv & 1;
  const bool isW = (wv < 2);

  for (int i = t; i < 512; i += 256) {
    ((uint4*)STh)[i] = (uint4){0u,0u,0u,0u};
    ((uint4*)STl)[i] = (uint4){0u,0u,0u,0u};
  }

  const size_t bhL = (size_t)bh * LL;
  const ushort_t* wqB = (isW ? w : qn) + bhL * DKk;  // phaseA A-operand source
  const ushort_t* kB  = kt + bhL * DKk;
  const ushort_t* uB  = ut + bhL * DVv;
  const ushort_t* ahB = ah + (size_t)bh * NC * 1024;
  const ushort_t* alB = al + (size_t)bh * NC * 1024;
  ushort_t* oB = dout + (size_t)b * LL * DD + h * DVv + vs * 16 + fr;

  floatx4 Sacc[4];   // dk slice [wv*64, wv*64+64) x dv16
#pragma unroll
  for (int i = 0; i < 4; ++i) Sacc[i] = (floatx4){0.f,0.f,0.f,0.f};

  auto loadK = [&](int ci, FragsK& f) {
    const ushort_t* kp = kB + (size_t)ci*8192 + (size_t)(wv*64 + fr)*32 + fq*8;
#pragma unroll
    for (int m = 0; m < 4; ++m) f.kf[m] = *(const short8*)(kp + m*512);
    if (!isW) {
      f.afh = *(const short8*)(ahB + (size_t)ci*1024 + (mt*16+fr)*32 + fq*8);
      f.afl = *(const short8*)(alB + (size_t)ci*1024 + (mt*16+fr)*32 + fq*8);
    }
  };
  auto loadA = [&](int ci, FragsA& f) {
    const ushort_t* ap = wqB + (size_t)(ci*32 + mt*16 + fr) * DKk + fq*8;
#pragma unroll
    for (int ks = 0; ks < 8; ++ks) f.aw[ks] = *(const short8*)(ap + ks*32);
    if (isW)
      f.uu = *(const uint2*)(uB + (size_t)ci*8192 + (size_t)(vs*16 + fr)*32 + mt*16 + fq*4);
  };

  FragsK k0, k1; FragsA a0, a1;
  loadK(0, k0);
  loadA(0, a0);
  __syncthreads();   // ST zero-init visible

  auto body = [&](int ci, FragsK& kc, FragsK& kn, FragsA& ac, FragsA& an) {
    // issue ALL next-chunk loads first: full-chunk load-to-use window
    if (ci + 1 < NC) { loadK(ci + 1, kn); loadA(ci + 1, an); }
    // phaseA (uses ac)
    floatx4 acc0, acc1;
    if (isW) {
      float u0,u1,u2,u3; unpack2(ac.uu.x,u0,u1); unpack2(ac.uu.y,u2,u3);
      acc0 = (floatx4){-u0,-u1,-u2,-u3};
      acc1 = (floatx4){0.f,0.f,0.f,0.f};
#pragma unroll
      for (int ks = 0; ks < 8; ++ks) {
        const short8 sh = *(const short8*)&STh[S16(fr, ks*32 + fq*8)];
        const short8 sl = *(const short8*)&STl[S16(fr, ks*32 + fq*8)];
        acc0 = __builtin_amdgcn_mfma_f32_16x16x32_bf16(ac.aw[ks], sh, acc0, 0,0,0);
        acc1 = __builtin_amdgcn_mfma_f32_16x16x32_bf16(ac.aw[ks], sl, acc1, 0,0,0);
      }
      const float v0 = -(acc0[0]+acc1[0]), v1 = -(acc0[1]+acc1[1]);
      const float v2 = -(acc0[2]+acc1[2]), v3 = -(acc0[3]+acc1[3]);
      unsigned ph0, pl0, ph1, pl1;
      split2t(v0, v1, ph0, pl0); split2t(v2, v3, ph1, pl1);
      *(uint2*)&Uh[U16(fr, mt*16 + fq*4)] = (uint2){ph0, ph1};
      *(uint2*)&Ul[U16(fr, mt*16 + fq*4)] = (uint2){pl0, pl1};
    } else {
      acc0 = (floatx4){0.f,0.f,0.f,0.f};
#pragma unroll
      for (int ks = 0; ks < 8; ++ks) {
        const short8 sh = *(const short8*)&STh[S16(fr, ks*32 + fq*8)];
        acc0 = __builtin_amdgcn_mfma_f32_16x16x32_bf16(ac.aw[ks], sh, acc0, 0,0,0);
      }
    }
    __syncthreads();   // BAR1: uhat ready; all ST reads of this chunk done
    const short8 uhh = *(const short8*)&Uh[U16(fr, fq*8)];
    const short8 uhl = *(const short8*)&Ul[U16(fr, fq*8)];
    if (!isW) {
      // o = q@Sh + attn@uhat; bf16 stores (16 consecutive dv per row)
      acc0 = __builtin_amdgcn_mfma_f32_16x16x32_bf16(kc.afh, uhh, acc0, 0,0,0);
      acc0 = __builtin_amdgcn_mfma_f32_16x16x32_bf16(kc.afh, uhl, acc0, 0,0,0);
      acc0 = __builtin_amdgcn_mfma_f32_16x16x32_bf16(kc.afl, uhh, acc0, 0,0,0);
      ushort_t* op = oB + (size_t)(ci*32 + mt*16 + fq*4) * DD;
#pragma unroll
      for (int r = 0; r < 4; ++r) op[(size_t)r * DD] = f2bf(acc0[r]);
    }
    // S += kT @ (uhat_hi + uhat_lo): wave's own 4 dk tiles
#pragma unroll
    for (int m = 0; m < 4; ++m) {
      Sacc[m] = __builtin_amdgcn_mfma_f32_16x16x32_bf16(kc.kf[m], uhh, Sacc[m], 0,0,0);
      Sacc[m] = __builtin_amdgcn_mfma_f32_16x16x32_bf16(kc.kf[m], uhl, Sacc[m], 0,0,0);
    }
    // mirror S slice -> shared LDS image (hi/lo) for next chunk
#pragma unroll
    for (int m = 0; m < 4; ++m) {
      unsigned ph0, pl0, ph1, pl1;
      split2t(Sacc[m][0], Sacc[m][1], ph0, pl0);
      split2t(Sacc[m][2], Sacc[m][3], ph1, pl1);
      const int dk0 = wv*64 + m*16 + fq*4;
      *(uint2*)&STh[S16(fr, dk0)] = (uint2){ph0, ph1};
      *(uint2*)&STl[S16(fr, dk0)] = (uint2){pl0, pl1};
    }
    __syncthreads();   // BAR2: ST ready; Uh readers done
  };

  for (int c2 = 0; c2 < NC; c2 += 2) {
    body(c2,     k0, k1, a0, a1);
    body(c2 + 1, k1, k0, a1, a0);
  }
}

// ---- EMA pass 1: per-segment local scan ------------------------------------
__global__ __launch_bounds__(256) void ema_local_kernel(const ushort_t* __restrict__ v,
  const float* __restrict__ gs, const float* __restrict__ gl,
  ushort_t* __restrict__ es, ushort_t* __restrict__ el,
  float* __restrict__ Bs, float* __restrict__ Bl,
  float* __restrict__ As, float* __restrict__ Al,
  float* __restrict__ PfS, float* __restrict__ PfL)
{
  const int bid = blockIdx.x;
  const int seg = bid & (NSEG - 1), bh = bid >> 6;
  const int b = bh >> 2, h = bh & 3;
  const int dv = threadIdx.x;
  const int l0 = seg * SEG;
  const ushort_t* vp = v + ((size_t)bh*LL + l0) * DVv + dv;
  const float* gsp = gs + (size_t)bh*LL + l0;
  const float* glp = gl + (size_t)bh*LL + l0;
  ushort_t* esp = es + ((size_t)b*LL + l0)*DD + h*DVv + dv;
  ushort_t* elp = el + ((size_t)b*LL + l0)*DD + h*DVv + dv;
  float* pfs = PfS + (size_t)bh*LL + l0;
  float* pfl = PfL + (size_t)bh*LL + l0;
  float s1 = 0.f, s2 = 0.f, p1 = 1.f, p2 = 1.f;
  for (int j = 0; j < SEG; ++j) {
    const float vv = bf2f(vp[(size_t)j * DVv]);
    const float a = gsp[j], g2 = glp[j];
    s1 = fmaf(a,  s1, (1.f - a)  * vv);
    s2 = fmaf(g2, s2, (1.f - g2) * vv);
    p1 *= a; p2 *= g2;
    esp[(size_t)j * DD] = f2bf(s1);
    elp[(size_t)j * DD] = f2bf(s2);
    if (dv == 0) { pfs[j] = p1; pfl[j] = p2; }
  }
  const size_t o = (((size_t)bh*NSEG + seg) << 8) + dv;
  Bs[o] = s1; Bl[o] = s2;
  if (dv == 0) { As[bh*NSEG + seg] = p1; Al[bh*NSEG + seg] = p2; }
}

// ---- EMA pass 2: cross-segment carry (carry INTO each segment) -------------
__global__ __launch_bounds__(256) void ema_carry_kernel(
  const float* __restrict__ Bs, const float* __restrict__ Bl,
  const float* __restrict__ As, const float* __restrict__ Al,
  float* __restrict__ Cs, float* __restrict__ Cl)
{
  const int bh = blockIdx.x;
  const int dv = threadIdx.x;
  __shared__ float Ash[NSEG], Alh[NSEG];
  if (dv < NSEG) { Ash[dv] = As[bh*NSEG + dv]; Alh[dv] = Al[bh*NSEG + dv]; }
  __syncthreads();
  float c1 = 0.f, c2 = 0.f;
  for (int s = 0; s < NSEG; ++s) {
    const size_t o = (((size_t)bh*NSEG + s) << 8) + dv;
    Cs[o] = c1; Cl[o] = c2;
    c1 = fmaf(Ash[s], c1, Bs[o]);
    c2 = fmaf(Alh[s], c2, Bl[o]);
  }
}

// ---- combine + per-head RMSNorm; 4 waves/block; delta_o now bf16 -----------
__global__ __launch_bounds__(256) void combine_kernel(const ushort_t* __restrict__ v,
  const ushort_t* __restrict__ es, const ushort_t* __restrict__ el,
  const ushort_t* __restrict__ dovb, const float* __restrict__ wgt,
  const float* __restrict__ onw,
  const float* __restrict__ Cs, const float* __restrict__ Cl,
  const float* __restrict__ PfS, const float* __restrict__ PfL,
  ushort_t* __restrict__ outp)
{
  const int bid = blockIdx.x * 4 + (threadIdx.x >> 6);
  const int h = bid & 3;
  const size_t bl = (size_t)(bid >> 2);
  const int lane = threadIdx.x & 63;
  const size_t b = bl >> 12;
  const size_t l = bl & (LL - 1);
  const int bh = (int)(b * HH) + h;
  const int seg = (int)(l >> 6);
  const size_t vidx = (((b*HH + h) * (size_t)LL) + l) * DVv + lane*4;
  const size_t didx = bl * DD + h*DVv + lane*4;
  const uint2 vu = *(const uint2*)(v + vidx);
  const uint2 eu = *(const uint2*)(es + didx);
  const uint2 gu = *(const uint2*)(el + didx);
  const uint2 du = *(const uint2*)(dovb + didx);
  const float pS = PfS[(size_t)bh*LL + l];
  const float pL = PfL[(size_t)bh*LL + l];
  const float4 cs4 = *(const float4*)(Cs + (((size_t)bh*NSEG + seg) << 8) + lane*4);
  const float4 cl4 = *(const float4*)(Cl + (((size_t)bh*NSEG + seg) << 8) + lane*4);
  float vf[4], ef[4], gf[4], df[4];
  unpack2(vu.x, vf[0], vf[1]); unpack2(vu.y, vf[2], vf[3]);
  unpack2(eu.x, ef[0], ef[1]); unpack2(eu.y, ef[2], ef[3]);
  unpack2(gu.x, gf[0], gf[1]); unpack2(gu.y, gf[2], gf[3]);
  unpack2(du.x, df[0], df[1]); unpack2(du.y, df[2], df[3]);
  ef[0] = fmaf(pS, cs4.x, ef[0]); ef[1] = fmaf(pS, cs4.y, ef[1]);
  ef[2] = fmaf(pS, cs4.z, ef[2]); ef[3] = fmaf(pS, cs4.w, ef[3]);
  gf[0] = fmaf(pL, cl4.x, gf[0]); gf[1] = fmaf(pL, cl4.y, gf[1]);
  gf[2] = fmaf(pL, cl4.z, gf[2]); gf[3] = fmaf(pL, cl4.w, gf[3]);
  const float* wp = wgt + (size_t)bid * 4;
  const float w0 = wp[0], w1 = wp[1], w2 = wp[2], w3 = wp[3];
  float o[4];
  float ss = 0.f;
#pragma unroll
  for (int i = 0; i < 4; ++i) {
    o[i] = w0*vf[i] + w1*ef[i] + w2*df[i] + w3*gf[i];
    ss = fmaf(o[i], o[i], ss);
  }
#pragma unroll
  for (int off = 1; off < 64; off <<= 1) ss += __shfl_xor(ss, off);
  const float sc = rsqrtf(ss * (1.f / DVv) + 1e-5f);
  const float4 nw = *(const float4*)(onw + lane*4);
  uint2 pk;
  pk.x = pack2(o[0]*sc*nw.x, o[1]*sc*nw.y);
  pk.y = pack2(o[2]*sc*nw.z, o[3]*sc*nw.w);
  *(uint2*)(outp + didx) = pk;
}

extern "C" void kernel_launch(void* const* d_in, const int* in_sizes, int n_in,
                              void* d_out, int out_size, void* d_ws, size_t ws_size,
                              hipStream_t stream)
{
  const float* x    = (const float*)d_in[0];
  const float* Wq   = (const float*)d_in[1];
  const float* Wk   = (const float*)d_in[2];
  const float* Wv   = (const float*)d_in[3];
  const float* cqw  = (const float*)d_in[4];
  const float* ckw  = (const float*)d_in[5];
  const float* cvw  = (const float*)d_in[6];
  const float* Wb   = (const float*)d_in[7];
  const float* Wds  = (const float*)d_in[8];
  const float* bds  = (const float*)d_in[9];
  const float* Wdl  = (const float*)d_in[10];
  const float* bdl  = (const float*)d_in[11];
  const float* Wtr  = (const float*)d_in[12];
  const float* btr  = (const float*)d_in[13];
  const float* Wc   = (const float*)d_in[14];
  const float* bc   = (const float*)d_in[15];
  const float* Wl   = (const float*)d_in[16];
  const float* blc  = (const float*)d_in[17];
  const float* Wg   = (const float*)d_in[18];
  const float* bg   = (const float*)d_in[19];
  const float* ltc  = (const float*)d_in[20];
  const float* ltf  = (const float*)d_in[21];
  const float* onw  = (const float*)d_in[22];
  const float* Wo   = (const float*)d_in[23];
  float* outp = (float*)d_out;

  const size_t BLD = (size_t)BB * LL * DD;
  unsigned char* w8 = (unsigned char*)d_ws;
  const size_t SL = BLD * 2;                        // 32 MB bf16 slab
  ushort_t* SA = (ushort_t*)(w8 + 0*SL);   // qraw -> kn -> kT -> opre
  ushort_t* SB = (ushort_t*)(w8 + 1*SL);   // kraw -> vv
  ushort_t* SC = (ushort_t*)(w8 + 2*SL);   // vraw -> uT
  ushort_t* SD = (ushort_t*)(w8 + 3*SL);   // xb -> qn -> el(local)
  ushort_t* SE = (ushort_t*)(w8 + 4*SL);   // w  -> es(local)
  ushort_t* zb   = (ushort_t*)(w8 + 5*SL);
  ushort_t* attn_hi = (ushort_t*)(w8 + 5*SL + BLD);
  ushort_t* attn_lo = attn_hi + (size_t)BB*HH*NC*1024;
  float*    beta = (float*)(attn_hi + 2*(size_t)BB*HH*NC*1024);
  float*    gs   = beta + (size_t)BB*HH*LL;
  float*    gl   = gs   + (size_t)BB*HH*LL;
  float*    wgt  = gl   + (size_t)BB*HH*LL;
  float*    Bs   = wgt  + (size_t)BB*LL*HH*4;
  float*    Bl   = Bs   + (size_t)BB*HH*NSEG*256;
  float*    Cs   = Bl   + (size_t)BB*HH*NSEG*256;
  float*    Cl   = Cs   + (size_t)BB*HH*NSEG*256;
  float*    As   = Cl   + (size_t)BB*HH*NSEG*256;
  float*    Al   = As   + (size_t)BB*HH*NSEG;
  float*    PfS  = Al   + (size_t)BB*HH*NSEG;
  float*    PfL  = PfS  + (size_t)BB*HH*LL;
  // W slabs: Wq,Wk,Wv,Wtr contiguous (fused GEMM reads rows 0..3583), then Wo
  ushort_t* Wqb  = (ushort_t*)(PfL + (size_t)BB*HH*LL);
  ushort_t* Wkb  = Wqb + (size_t)DD*DD;
  ushort_t* Wvb  = Wkb + (size_t)DD*DD;
  ushort_t* Wtrb = Wvb + (size_t)DD*DD;
  ushort_t* Wob  = Wtrb + (size_t)HIDD*DD;
  ushort_t* xb   = SD;                     // bf16 x, consumed by the fused GEMM
  ushort_t* dovb = (ushort_t*)outp;        // bf16 delta_o scratch in out buffer

  const int MBL = BB * LL;  // 16384
  dim3 blk256(256);

  {
    const int NTOT = (int)(BLD/8) + 4*(DD*DD/8) + HIDD*DD/8;
    cvt_all_kernel<<<dim3((NTOT + 255)/256), blk256, 0, stream>>>(
        x, Wq, Wk, Wv, Wtr, Wo, xb, Wqb, Wkb, Wvb, Wtrb, Wob);
  }

  gemm_qkvt<<<dim3(28*128), blk256, 0, stream>>>(xb, Wqb, btr, SA, SB, SC, zb, MBL, DD);
  small_proj_kernel<<<dim3(MBL), blk256, 0, stream>>>(x, Wb, Wds, bds, Wdl, bdl, beta, gs, gl);
  gate_kernel<<<dim3(MBL), blk256, 0, stream>>>(zb, Wc, bc, Wl, blc, Wg, bg, ltc, ltf, wgt);
  conv_silu_kernel<<<dim3((unsigned)(BLD/8/256)), blk256, 0, stream>>>(SA, cqw, SD);  // qn=SD
  conv_silu_kernel<<<dim3((unsigned)(BLD/8/256)), blk256, 0, stream>>>(SB, ckw, SA);  // kn=SA
  conv_silu_kernel<<<dim3((unsigned)(BLD/8/256)), blk256, 0, stream>>>(SC, cvw, SB);  // vv=SB
  prep_kernel<<<dim3(BB*HH*NC), blk256, 0, stream>>>(SD, SA, SB, beta, SC, SE, attn_hi, attn_lo); // uT=SC w=SE kT=SA
  scan_kernel<<<dim3(256), blk256, 0, stream>>>(SD, SA, SC, SE, attn_hi, attn_lo, dovb);
  ema_local_kernel<<<dim3(BB*HH*NSEG), blk256, 0, stream>>>(SB, gs, gl, SE, SD, Bs, Bl, As, Al, PfS, PfL); // es=SE el=SD
  ema_carry_kernel<<<dim3(BB*HH), blk256, 0, stream>>>(Bs, Bl, As, Al, Cs, Cl);
  combine_kernel<<<dim3(MBL*HH/4), blk256, 0, stream>>>(SB, SE, SD, dovb, wgt, onw, Cs, Cl, PfS, PfL, SA); // opre=SA
  gemm_bf16<0><<<dim3(8*128), blk256, 0, stream>>>(SA, Wob, outp, MBL, DD, DD);
}